// Round 11
// baseline (230.557 us; speedup 1.0000x reference)
//
#include <hip/hip_runtime.h>
#include <math.h>

#define IN_FEATS 128
#define OUT_FEATS 64
#define NEG_SLOPE 0.2f
#define MAXD 256
#define BSH 8                      // bucket = dst >> 8 (256 nodes/bucket)
#define BNODES (1 << BSH)
#define CHUNK 4096                 // edges per block in bucket passes
#define EPT 16                     // edges per thread (CHUNK/256)
#define EID_BITS 21                // n_edges < 2^21
#define LDP 132                    // padded LDS row stride (floats)

// bf16 helpers: packed pair in a uint (lo = even feat, hi = odd feat)
__device__ __forceinline__ float bf_lo(unsigned u) { return __uint_as_float(u << 16); }
__device__ __forceinline__ float bf_hi(unsigned u) { return __uint_as_float(u & 0xffff0000u); }
__device__ __forceinline__ unsigned short f2bf(float f) {
  unsigned x = __float_as_uint(f);
  x += 0x7fff + ((x >> 16) & 1);          // round to nearest even
  return (unsigned short)(x >> 16);
}
__device__ __forceinline__ unsigned packbf(float lo, float hi) {
  return (unsigned)f2bf(lo) | ((unsigned)f2bf(hi) << 16);
}

// ---------------------------------------------------------------------------
// K1: h16 = bf16(feat @ W^T), LDS-tiled (proven R9/R10).
// ---------------------------------------------------------------------------
__global__ __launch_bounds__(256)
void gemm_h_kernel(const float* __restrict__ feat,
                   const float* __restrict__ W,
                   unsigned short* __restrict__ h16, int n_nodes) {
  __shared__ float fs[64 * LDP];
  __shared__ float ws[64 * LDP];
  const int t  = threadIdx.x;
  const int n0 = blockIdx.x * 64;

  for (int i = t; i < 64 * 32; i += 256) {
    int r = i >> 5, c4 = i & 31;
    float4 v = *reinterpret_cast<const float4*>(W + r * IN_FEATS + c4 * 4);
    *reinterpret_cast<float4*>(&ws[r * LDP + c4 * 4]) = v;
  }
  for (int i = t; i < 64 * 32; i += 256) {
    int r = i >> 5, c4 = i & 31;
    int n = n0 + r;
    float4 v = {0.f, 0.f, 0.f, 0.f};
    if (n < n_nodes)
      v = *reinterpret_cast<const float4*>(feat + (size_t)n * IN_FEATS + c4 * 4);
    *reinterpret_cast<float4*>(&fs[r * LDP + c4 * 4]) = v;
  }
  __syncthreads();

  const int l  = t & 63, q = t >> 6;
  const int ob = (l & 15) * 4;            // output base (4 outputs)
  const int nb = q * 16 + (l >> 4) * 4;   // node base (4 nodes)

  float acc[4][4] = {{0.f}};
  for (int k4 = 0; k4 < 32; ++k4) {
    float4 fr[4], wr[4];
#pragma unroll
    for (int i = 0; i < 4; ++i)
      fr[i] = *reinterpret_cast<const float4*>(&fs[(nb + i) * LDP + k4 * 4]);
#pragma unroll
    for (int j = 0; j < 4; ++j)
      wr[j] = *reinterpret_cast<const float4*>(&ws[(ob + j) * LDP + k4 * 4]);
#pragma unroll
    for (int i = 0; i < 4; ++i) {
#pragma unroll
      for (int j = 0; j < 4; ++j) {
        acc[i][j] = fmaf(fr[i].x, wr[j].x, acc[i][j]);
        acc[i][j] = fmaf(fr[i].y, wr[j].y, acc[i][j]);
        acc[i][j] = fmaf(fr[i].z, wr[j].z, acc[i][j]);
        acc[i][j] = fmaf(fr[i].w, wr[j].w, acc[i][j]);
      }
    }
  }

#pragma unroll
  for (int i = 0; i < 4; ++i) {
    int node = n0 + nb + i;
    if (node < n_nodes) {
      ushort4 o;
      o.x = f2bf(acc[i][0]); o.y = f2bf(acc[i][1]);
      o.z = f2bf(acc[i][2]); o.w = f2bf(acc[i][3]);
      *reinterpret_cast<ushort4*>(h16 + (size_t)node * OUT_FEATS + ob) = o;
    }
  }
}

// ---------------------------------------------------------------------------
// Bucket sort pass A1: per-bucket edge counts
// ---------------------------------------------------------------------------
__global__ __launch_bounds__(256)
void bhist_kernel(const int* __restrict__ dst, int* __restrict__ bcount,
                  int n_edges, int nbuck) {
  __shared__ int hist[512];
  const int t = threadIdx.x;
  for (int i = t; i < nbuck; i += 256) hist[i] = 0;
  __syncthreads();
  const int base = blockIdx.x * CHUNK;
#pragma unroll
  for (int i = 0; i < EPT; ++i) {
    int e = base + t + i * 256;
    if (e < n_edges) atomicAdd(&hist[dst[e] >> BSH], 1);
  }
  __syncthreads();
  for (int i = t; i < nbuck; i += 256)
    if (hist[i]) atomicAdd(&bcount[i], hist[i]);
}

// ---------------------------------------------------------------------------
// A2: exclusive scan of bucket counts
// ---------------------------------------------------------------------------
__global__ void bscan_kernel(const int* __restrict__ bcount, int* __restrict__ bbase,
                             int* __restrict__ bcursor, int nbuck, int n_edges) {
  __shared__ int tmp[512];
  const int t = threadIdx.x;
  int v = (t < nbuck) ? bcount[t] : 0;
  tmp[t] = v;
  __syncthreads();
  for (int off = 1; off < 512; off <<= 1) {
    int x = (t >= off) ? tmp[t - off] : 0;
    __syncthreads();
    tmp[t] += x;
    __syncthreads();
  }
  if (t < nbuck) { int excl = tmp[t] - v; bbase[t] = excl; bcursor[t] = excl; }
  if (t == 0) bbase[nbuck] = n_edges;
}

// ---------------------------------------------------------------------------
// A3: scatter edges into bucket regions
// ---------------------------------------------------------------------------
__global__ __launch_bounds__(256)
void bscatter_kernel(const int* __restrict__ src, const int* __restrict__ dst,
                     int* __restrict__ bcursor, int2* __restrict__ tmpe,
                     int n_edges, int nbuck) {
  __shared__ int hist[512];
  __shared__ int basech[512];
  __shared__ int offs[512];
  const int t = threadIdx.x;
  const int base = blockIdx.x * CHUNK;
  for (int i = t; i < nbuck; i += 256) { hist[i] = 0; offs[i] = 0; }
  __syncthreads();
  int s16a[EPT], d16a[EPT];
#pragma unroll
  for (int i = 0; i < EPT; ++i) {
    int e = base + t + i * 256;
    if (e < n_edges) {
      s16a[i] = src[e];
      d16a[i] = dst[e];
      atomicAdd(&hist[d16a[i] >> BSH], 1);
    } else {
      d16a[i] = -1;
    }
  }
  __syncthreads();
  for (int i = t; i < nbuck; i += 256)
    if (hist[i]) basech[i] = atomicAdd(&bcursor[i], hist[i]);
  __syncthreads();
#pragma unroll
  for (int i = 0; i < EPT; ++i) {
    if (d16a[i] >= 0) {
      int e = base + t + i * 256;
      int b = d16a[i] >> BSH;
      int off = atomicAdd(&offs[b], 1);
      int2 v;
      v.x = s16a[i];
      v.y = ((d16a[i] & (BNODES - 1)) << EID_BITS) | e;
      tmpe[basech[b] + off] = v;
    }
  }
}

// ---------------------------------------------------------------------------
// B: one workgroup per bucket -> row_ptr + final CSR edata (src,eid).
// ---------------------------------------------------------------------------
__global__ __launch_bounds__(256)
void binB_kernel(const int2* __restrict__ tmpe, const int* __restrict__ bbase,
                 int2* __restrict__ edata, int* __restrict__ row_ptr,
                 int n_nodes, int n_edges) {
  __shared__ int cnt[BNODES];
  __shared__ int cur[BNODES];
  const int b = blockIdx.x;
  const int t = threadIdx.x;
  const int beg = bbase[b], end = bbase[b + 1];

  cnt[t] = 0;
  __syncthreads();
  for (int i = beg + t; i < end; i += 256)
    atomicAdd(&cnt[(tmpe[i].y >> EID_BITS) & (BNODES - 1)], 1);
  __syncthreads();

  int v = cnt[t];
  cur[t] = v;
  __syncthreads();
  for (int off = 1; off < BNODES; off <<= 1) {
    int x = (t >= off) ? cur[t - off] : 0;
    __syncthreads();
    cur[t] += x;
    __syncthreads();
  }
  int excl = cur[t] - v;
  int node = b * BNODES + t;
  if (node < n_nodes) row_ptr[node] = beg + excl;
  if (b == 0 && t == 0) row_ptr[n_nodes] = n_edges;
  __syncthreads();
  cur[t] = beg + excl;
  __syncthreads();

  for (int i = beg + t; i < end; i += 256) {
    int2 p = tmpe[i];
    int l = (p.y >> EID_BITS) & (BNODES - 1);
    int pos = atomicAdd(&cur[l], 1);
    int2 o;
    o.x = p.x;
    o.y = p.y & ((1 << EID_BITS) - 1);
    edata[pos] = o;
  }
}

// ---------------------------------------------------------------------------
// agg: wave per node, 8 edges in flight, bf16 gather, f32 accumulate.
// Epilogue (eo==0 lanes hold the full h_agg row): write h_agg (f32 output),
// a16 = bf16(h_agg), t16 = bf16(tanh(h_agg)) -- replaces the tanh kernel.
// ---------------------------------------------------------------------------
__global__ void agg_kernel(const unsigned* __restrict__ h16u,  // rows of 32 uints
                           const int* __restrict__ row_ptr,
                           const int2* __restrict__ edata, float* __restrict__ h_agg,
                           unsigned* __restrict__ a16u, unsigned* __restrict__ t16u,
                           int n_nodes) {
  int wid  = (blockIdx.x * blockDim.x + threadIdx.x) >> 6;
  int lane = threadIdx.x & 63;
  int eo = lane >> 3;   // edge slot in group of 8
  int fo = lane & 7;    // bf16x8 slot in row
  if (wid >= n_nodes) return;
  int beg = row_ptr[wid], end = row_ptr[wid + 1];
  float acc[8] = {0.f, 0.f, 0.f, 0.f, 0.f, 0.f, 0.f, 0.f};
  for (int i = beg + eo; i < end; i += 8) {
    int s = edata[i].x;
    uint4 v = *reinterpret_cast<const uint4*>(h16u + (unsigned)s * 32u + fo * 4);
    acc[0] += bf_lo(v.x); acc[1] += bf_hi(v.x);
    acc[2] += bf_lo(v.y); acc[3] += bf_hi(v.y);
    acc[4] += bf_lo(v.z); acc[5] += bf_hi(v.z);
    acc[6] += bf_lo(v.w); acc[7] += bf_hi(v.w);
  }
#pragma unroll
  for (int off = 8; off < 64; off <<= 1) {
#pragma unroll
    for (int j = 0; j < 8; ++j) acc[j] += __shfl_xor(acc[j], off, 64);
  }
  if (eo == 0) {
    float4 a, b;
    a.x = acc[0]; a.y = acc[1]; a.z = acc[2]; a.w = acc[3];
    b.x = acc[4]; b.y = acc[5]; b.z = acc[6]; b.w = acc[7];
    float* out = h_agg + (unsigned)wid * OUT_FEATS + fo * 8;
    *reinterpret_cast<float4*>(out) = a;
    *reinterpret_cast<float4*>(out + 4) = b;
    uint4 pa;
    pa.x = packbf(acc[0], acc[1]); pa.y = packbf(acc[2], acc[3]);
    pa.z = packbf(acc[4], acc[5]); pa.w = packbf(acc[6], acc[7]);
    *reinterpret_cast<uint4*>(a16u + (unsigned)wid * 32u + fo * 4) = pa;
    uint4 pt;
    pt.x = packbf(tanhf(acc[0]), tanhf(acc[1]));
    pt.y = packbf(tanhf(acc[2]), tanhf(acc[3]));
    pt.z = packbf(tanhf(acc[4]), tanhf(acc[5]));
    pt.w = packbf(tanhf(acc[6]), tanhf(acc[7]));
    *reinterpret_cast<uint4*>(t16u + (unsigned)wid * 32u + fo * 4) = pt;
  }
}

// ---------------------------------------------------------------------------
// fused per-node edge softmax, 8 edges in flight over bf16 rows.
// Tail gathers skipped (group-uniform guard); deg<=64 fast path keeps the
// max/exp/sum/write phases entirely in registers (one LDS read per lane).
// ---------------------------------------------------------------------------
__global__ __launch_bounds__(256)
void softmax_kernel(const unsigned* __restrict__ a16u, const unsigned* __restrict__ t16u,
                    const int* __restrict__ row_ptr, const int2* __restrict__ edata,
                    float* __restrict__ e_soft, int n_nodes) {
  __shared__ float ebuf[4][MAXD];
  int wid  = (blockIdx.x * blockDim.x + threadIdx.x) >> 6;
  int lane = threadIdx.x & 63;
  int lw   = threadIdx.x >> 6;
  int eo = lane >> 3;
  int fo = lane & 7;
  if (wid >= n_nodes) return;
  int beg = row_ptr[wid], end = row_ptr[wid + 1];
  int deg = end - beg;
  if (deg == 0) return;

  // this node's tanh slice (8 feats per lane; same across eo groups)
  uint4 tv = *reinterpret_cast<const uint4*>(t16u + (unsigned)wid * 32u + fo * 4);
  float tt[8];
  tt[0] = bf_lo(tv.x); tt[1] = bf_hi(tv.x);
  tt[2] = bf_lo(tv.y); tt[3] = bf_hi(tv.y);
  tt[4] = bf_lo(tv.z); tt[5] = bf_hi(tv.z);
  tt[6] = bf_lo(tv.w); tt[7] = bf_hi(tv.w);

  if (deg <= MAXD) {
    for (int i0 = 0; i0 < deg; i0 += 8) {
      int e = i0 + eo;
      if (e < deg) {                         // group-uniform guard: no dup gathers
        int s = edata[beg + e].x;
        uint4 av = *reinterpret_cast<const uint4*>(a16u + (unsigned)s * 32u + fo * 4);
        float d = tt[0] * bf_lo(av.x) + tt[1] * bf_hi(av.x)
                + tt[2] * bf_lo(av.y) + tt[3] * bf_hi(av.y)
                + tt[4] * bf_lo(av.z) + tt[5] * bf_hi(av.z)
                + tt[6] * bf_lo(av.w) + tt[7] * bf_hi(av.w);
#pragma unroll
        for (int off = 1; off < 8; off <<= 1) d += __shfl_xor(d, off, 64);
        if (fo == 0) {
          d = d > 0.f ? d : NEG_SLOPE * d;
          ebuf[lw][e] = d;
        }
      }
    }
    if (deg <= 64) {
      // register tail: lane i owns score i
      float sc = (lane < deg) ? ebuf[lw][lane] : -INFINITY;
      float mx = sc;
#pragma unroll
      for (int off = 32; off > 0; off >>= 1) mx = fmaxf(mx, __shfl_xor(mx, off, 64));
      float ex = (lane < deg) ? expf(sc - mx) : 0.f;
      float sum = ex;
#pragma unroll
      for (int off = 32; off > 0; off >>= 1) sum += __shfl_xor(sum, off, 64);
      float inv = 1.f / sum;
      if (lane < deg) e_soft[edata[beg + lane].y] = ex * inv;
    } else {
      float mx = -INFINITY;
      for (int i = lane; i < deg; i += 64) mx = fmaxf(mx, ebuf[lw][i]);
#pragma unroll
      for (int off = 32; off > 0; off >>= 1) mx = fmaxf(mx, __shfl_xor(mx, off, 64));
      float sum = 0.f;
      for (int i = lane; i < deg; i += 64) {
        float ex = expf(ebuf[lw][i] - mx);
        ebuf[lw][i] = ex;
        sum += ex;
      }
#pragma unroll
      for (int off = 32; off > 0; off >>= 1) sum += __shfl_xor(sum, off, 64);
      float inv = 1.f / sum;
      for (int i = lane; i < deg; i += 64) e_soft[edata[beg + i].y] = ebuf[lw][i] * inv;
    }
  } else {
    // recompute fallback (statistically never hit with Poisson(16) degrees)
    float mx = -INFINITY;
    for (int i0 = 0; i0 < deg; i0 += 8) {
      int e = i0 + eo;
      int idx = beg + (e < deg ? e : deg - 1);
      int s = edata[idx].x;
      uint4 av = *reinterpret_cast<const uint4*>(a16u + (unsigned)s * 32u + fo * 4);
      float d = tt[0] * bf_lo(av.x) + tt[1] * bf_hi(av.x)
              + tt[2] * bf_lo(av.y) + tt[3] * bf_hi(av.y)
              + tt[4] * bf_lo(av.z) + tt[5] * bf_hi(av.z)
              + tt[6] * bf_lo(av.w) + tt[7] * bf_hi(av.w);
#pragma unroll
      for (int off = 1; off < 8; off <<= 1) d += __shfl_xor(d, off, 64);
      d = d > 0.f ? d : NEG_SLOPE * d;
      if (e >= deg) d = -INFINITY;
#pragma unroll
      for (int off = 8; off < 64; off <<= 1) d = fmaxf(d, __shfl_xor(d, off, 64));
      mx = fmaxf(mx, d);
    }
    float sum = 0.f;
    for (int i0 = 0; i0 < deg; i0 += 8) {
      int e = i0 + eo;
      int idx = beg + (e < deg ? e : deg - 1);
      int s = edata[idx].x;
      uint4 av = *reinterpret_cast<const uint4*>(a16u + (unsigned)s * 32u + fo * 4);
      float d = tt[0] * bf_lo(av.x) + tt[1] * bf_hi(av.x)
              + tt[2] * bf_lo(av.y) + tt[3] * bf_hi(av.y)
              + tt[4] * bf_lo(av.z) + tt[5] * bf_hi(av.z)
              + tt[6] * bf_lo(av.w) + tt[7] * bf_hi(av.w);
#pragma unroll
      for (int off = 1; off < 8; off <<= 1) d += __shfl_xor(d, off, 64);
      d = d > 0.f ? d : NEG_SLOPE * d;
      float ex = (e < deg) ? expf(d - mx) : 0.f;
#pragma unroll
      for (int off = 8; off < 64; off <<= 1) ex += __shfl_xor(ex, off, 64);
      sum += ex;
    }
    float inv = 1.f / sum;
    for (int i0 = 0; i0 < deg; i0 += 8) {
      int e = i0 + eo;
      int idx = beg + (e < deg ? e : deg - 1);
      int s = edata[idx].x;
      uint4 av = *reinterpret_cast<const uint4*>(a16u + (unsigned)s * 32u + fo * 4);
      float d = tt[0] * bf_lo(av.x) + tt[1] * bf_hi(av.x)
              + tt[2] * bf_lo(av.y) + tt[3] * bf_hi(av.y)
              + tt[4] * bf_lo(av.z) + tt[5] * bf_hi(av.z)
              + tt[6] * bf_lo(av.w) + tt[7] * bf_hi(av.w);
#pragma unroll
      for (int off = 1; off < 8; off <<= 1) d += __shfl_xor(d, off, 64);
      d = d > 0.f ? d : NEG_SLOPE * d;
      if (fo == 0 && e < deg) e_soft[edata[idx].y] = expf(d - mx) * inv;
    }
  }
}

extern "C" void kernel_launch(void* const* d_in, const int* in_sizes, int n_in,
                              void* d_out, int out_size, void* d_ws, size_t ws_size,
                              hipStream_t stream) {
  const float* feat = (const float*)d_in[0];
  const float* W    = (const float*)d_in[1];
  const int*   src  = (const int*)d_in[2];
  const int*   dst  = (const int*)d_in[3];
  const int n_nodes = in_sizes[0] / IN_FEATS;
  const int n_edges = in_sizes[2];
  const int nbuck   = (n_nodes + BNODES - 1) >> BSH;   // <= 512

  // Output layout: [h_agg (N*64) | e_soft (E)]
  float* h_agg  = (float*)d_out;
  float* e_soft = (float*)d_out + (size_t)n_nodes * OUT_FEATS;

  // Workspace:
  // [h16 (N*64 bf16) | a16 (N*64 bf16) | bcount(513) | bbase(513)
  //  | bcursor(512) | row_ptr(N+1 pad) | tmpe (E int2) | edata (E int2)]
  // t16 aliases tmpe (dead after binB; agg runs after binB).
  unsigned short* h16 = (unsigned short*)d_ws;
  unsigned short* a16 = h16 + (size_t)n_nodes * OUT_FEATS;
  int* bcount   = (int*)(a16 + (size_t)n_nodes * OUT_FEATS);
  int* bbase    = bcount + 513;
  int* bcursor  = bbase + 513;
  int* row_ptr  = bcursor + 512;
  size_t rp_pad = ((size_t)n_nodes + 2) & ~(size_t)1;
  int2* tmpe    = (int2*)(row_ptr + rp_pad);
  int2* edata   = tmpe + n_edges;
  unsigned* t16 = (unsigned*)tmpe;          // N*32 uints <= E*2 ints: fits

  const int eb2 = (n_edges + CHUNK - 1) / CHUNK;
  const int wb  = (n_nodes * 64 + 255) / 256;

  hipMemsetAsync(bcount, 0, (size_t)nbuck * sizeof(int), stream);

  gemm_h_kernel<<<(n_nodes + 63) / 64, 256, 0, stream>>>(feat, W, h16, n_nodes);

  bhist_kernel<<<eb2, 256, 0, stream>>>(dst, bcount, n_edges, nbuck);
  bscan_kernel<<<1, 512, 0, stream>>>(bcount, bbase, bcursor, nbuck, n_edges);
  bscatter_kernel<<<eb2, 256, 0, stream>>>(src, dst, bcursor, tmpe, n_edges, nbuck);
  binB_kernel<<<nbuck, 256, 0, stream>>>(tmpe, bbase, edata, row_ptr, n_nodes, n_edges);

  agg_kernel<<<wb, 256, 0, stream>>>((const unsigned*)h16, row_ptr, edata,
                                     h_agg, (unsigned*)a16, t16, n_nodes);

  softmax_kernel<<<wb, 256, 0, stream>>>((const unsigned*)a16, (const unsigned*)t16,
                                         row_ptr, edata, e_soft, n_nodes);
}

// Round 12
// 223.900 us; speedup vs baseline: 1.0297x; 1.0297x over previous
//
#include <hip/hip_runtime.h>
#include <math.h>

#define IN_FEATS 128
#define OUT_FEATS 64
#define NEG_SLOPE 0.2f
#define MAXD 256
#define BSH 8                      // bucket = dst >> 8 (256 nodes/bucket)
#define BNODES (1 << BSH)
#define CHUNK 4096                 // edges per block in bucket passes
#define EPT 16                     // edges per thread (CHUNK/256)
#define EID_BITS 21                // n_edges < 2^21
#define LDP 132                    // padded LDS row stride (floats)

// bf16 helpers: packed pair in a uint (lo = even feat, hi = odd feat)
__device__ __forceinline__ float bf_lo(unsigned u) { return __uint_as_float(u << 16); }
__device__ __forceinline__ float bf_hi(unsigned u) { return __uint_as_float(u & 0xffff0000u); }
__device__ __forceinline__ unsigned short f2bf(float f) {
  unsigned x = __float_as_uint(f);
  x += 0x7fff + ((x >> 16) & 1);          // round to nearest even
  return (unsigned short)(x >> 16);
}
__device__ __forceinline__ unsigned packbf(float lo, float hi) {
  return (unsigned)f2bf(lo) | ((unsigned)f2bf(hi) << 16);
}

// ---------------------------------------------------------------------------
// K1: h16 = bf16(feat @ W^T), LDS-tiled (proven R9/R10).
// ---------------------------------------------------------------------------
__global__ __launch_bounds__(256)
void gemm_h_kernel(const float* __restrict__ feat,
                   const float* __restrict__ W,
                   unsigned short* __restrict__ h16, int n_nodes) {
  __shared__ float fs[64 * LDP];
  __shared__ float ws[64 * LDP];
  const int t  = threadIdx.x;
  const int n0 = blockIdx.x * 64;

  for (int i = t; i < 64 * 32; i += 256) {
    int r = i >> 5, c4 = i & 31;
    float4 v = *reinterpret_cast<const float4*>(W + r * IN_FEATS + c4 * 4);
    *reinterpret_cast<float4*>(&ws[r * LDP + c4 * 4]) = v;
  }
  for (int i = t; i < 64 * 32; i += 256) {
    int r = i >> 5, c4 = i & 31;
    int n = n0 + r;
    float4 v = {0.f, 0.f, 0.f, 0.f};
    if (n < n_nodes)
      v = *reinterpret_cast<const float4*>(feat + (size_t)n * IN_FEATS + c4 * 4);
    *reinterpret_cast<float4*>(&fs[r * LDP + c4 * 4]) = v;
  }
  __syncthreads();

  const int l  = t & 63, q = t >> 6;
  const int ob = (l & 15) * 4;            // output base (4 outputs)
  const int nb = q * 16 + (l >> 4) * 4;   // node base (4 nodes)

  float acc[4][4] = {{0.f}};
  for (int k4 = 0; k4 < 32; ++k4) {
    float4 fr[4], wr[4];
#pragma unroll
    for (int i = 0; i < 4; ++i)
      fr[i] = *reinterpret_cast<const float4*>(&fs[(nb + i) * LDP + k4 * 4]);
#pragma unroll
    for (int j = 0; j < 4; ++j)
      wr[j] = *reinterpret_cast<const float4*>(&ws[(ob + j) * LDP + k4 * 4]);
#pragma unroll
    for (int i = 0; i < 4; ++i) {
#pragma unroll
      for (int j = 0; j < 4; ++j) {
        acc[i][j] = fmaf(fr[i].x, wr[j].x, acc[i][j]);
        acc[i][j] = fmaf(fr[i].y, wr[j].y, acc[i][j]);
        acc[i][j] = fmaf(fr[i].z, wr[j].z, acc[i][j]);
        acc[i][j] = fmaf(fr[i].w, wr[j].w, acc[i][j]);
      }
    }
  }

#pragma unroll
  for (int i = 0; i < 4; ++i) {
    int node = n0 + nb + i;
    if (node < n_nodes) {
      ushort4 o;
      o.x = f2bf(acc[i][0]); o.y = f2bf(acc[i][1]);
      o.z = f2bf(acc[i][2]); o.w = f2bf(acc[i][3]);
      *reinterpret_cast<ushort4*>(h16 + (size_t)node * OUT_FEATS + ob) = o;
    }
  }
}

// ---------------------------------------------------------------------------
// Bucket sort pass A1: per-bucket edge counts
// ---------------------------------------------------------------------------
__global__ __launch_bounds__(256)
void bhist_kernel(const int* __restrict__ dst, int* __restrict__ bcount,
                  int n_edges, int nbuck) {
  __shared__ int hist[512];
  const int t = threadIdx.x;
  for (int i = t; i < nbuck; i += 256) hist[i] = 0;
  __syncthreads();
  const int base = blockIdx.x * CHUNK;
#pragma unroll
  for (int i = 0; i < EPT; ++i) {
    int e = base + t + i * 256;
    if (e < n_edges) atomicAdd(&hist[dst[e] >> BSH], 1);
  }
  __syncthreads();
  for (int i = t; i < nbuck; i += 256)
    if (hist[i]) atomicAdd(&bcount[i], hist[i]);
}

// ---------------------------------------------------------------------------
// A2: exclusive scan of bucket counts
// ---------------------------------------------------------------------------
__global__ void bscan_kernel(const int* __restrict__ bcount, int* __restrict__ bbase,
                             int* __restrict__ bcursor, int nbuck, int n_edges) {
  __shared__ int tmp[512];
  const int t = threadIdx.x;
  int v = (t < nbuck) ? bcount[t] : 0;
  tmp[t] = v;
  __syncthreads();
  for (int off = 1; off < 512; off <<= 1) {
    int x = (t >= off) ? tmp[t - off] : 0;
    __syncthreads();
    tmp[t] += x;
    __syncthreads();
  }
  if (t < nbuck) { int excl = tmp[t] - v; bbase[t] = excl; bcursor[t] = excl; }
  if (t == 0) bbase[nbuck] = n_edges;
}

// ---------------------------------------------------------------------------
// A3: scatter edges into bucket regions
// ---------------------------------------------------------------------------
__global__ __launch_bounds__(256)
void bscatter_kernel(const int* __restrict__ src, const int* __restrict__ dst,
                     int* __restrict__ bcursor, int2* __restrict__ tmpe,
                     int n_edges, int nbuck) {
  __shared__ int hist[512];
  __shared__ int basech[512];
  __shared__ int offs[512];
  const int t = threadIdx.x;
  const int base = blockIdx.x * CHUNK;
  for (int i = t; i < nbuck; i += 256) { hist[i] = 0; offs[i] = 0; }
  __syncthreads();
  int s16a[EPT], d16a[EPT];
#pragma unroll
  for (int i = 0; i < EPT; ++i) {
    int e = base + t + i * 256;
    if (e < n_edges) {
      s16a[i] = src[e];
      d16a[i] = dst[e];
      atomicAdd(&hist[d16a[i] >> BSH], 1);
    } else {
      d16a[i] = -1;
    }
  }
  __syncthreads();
  for (int i = t; i < nbuck; i += 256)
    if (hist[i]) basech[i] = atomicAdd(&bcursor[i], hist[i]);
  __syncthreads();
#pragma unroll
  for (int i = 0; i < EPT; ++i) {
    if (d16a[i] >= 0) {
      int e = base + t + i * 256;
      int b = d16a[i] >> BSH;
      int off = atomicAdd(&offs[b], 1);
      int2 v;
      v.x = s16a[i];
      v.y = ((d16a[i] & (BNODES - 1)) << EID_BITS) | e;
      tmpe[basech[b] + off] = v;
    }
  }
}

// ---------------------------------------------------------------------------
// B: one workgroup per bucket -> row_ptr + final CSR edata (src,eid).
// ---------------------------------------------------------------------------
__global__ __launch_bounds__(256)
void binB_kernel(const int2* __restrict__ tmpe, const int* __restrict__ bbase,
                 int2* __restrict__ edata, int* __restrict__ row_ptr,
                 int n_nodes, int n_edges) {
  __shared__ int cnt[BNODES];
  __shared__ int cur[BNODES];
  const int b = blockIdx.x;
  const int t = threadIdx.x;
  const int beg = bbase[b], end = bbase[b + 1];

  cnt[t] = 0;
  __syncthreads();
  for (int i = beg + t; i < end; i += 256)
    atomicAdd(&cnt[(tmpe[i].y >> EID_BITS) & (BNODES - 1)], 1);
  __syncthreads();

  int v = cnt[t];
  cur[t] = v;
  __syncthreads();
  for (int off = 1; off < BNODES; off <<= 1) {
    int x = (t >= off) ? cur[t - off] : 0;
    __syncthreads();
    cur[t] += x;
    __syncthreads();
  }
  int excl = cur[t] - v;
  int node = b * BNODES + t;
  if (node < n_nodes) row_ptr[node] = beg + excl;
  if (b == 0 && t == 0) row_ptr[n_nodes] = n_edges;
  __syncthreads();
  cur[t] = beg + excl;
  __syncthreads();

  for (int i = beg + t; i < end; i += 256) {
    int2 p = tmpe[i];
    int l = (p.y >> EID_BITS) & (BNODES - 1);
    int pos = atomicAdd(&cur[l], 1);
    int2 o;
    o.x = p.x;
    o.y = p.y & ((1 << EID_BITS) - 1);
    edata[pos] = o;
  }
}

// ---------------------------------------------------------------------------
// agg: 8 nodes per wave, 8 lanes per node, lane fo owns feats 8fo..8fo+7.
// Zero cross-lane ops: accumulate in registers, store directly. All 8 lanes
// of a group read the same edata[i] (L1 broadcast); consecutive nodes per
// wave keep edata/row_ptr reads near-contiguous.
// ---------------------------------------------------------------------------
__global__ void agg_kernel(const unsigned* __restrict__ h16u,  // rows of 32 uints
                           const int* __restrict__ row_ptr,
                           const int2* __restrict__ edata, float* __restrict__ h_agg,
                           int n_nodes) {
  int tid  = blockIdx.x * blockDim.x + threadIdx.x;
  int node = tid >> 3;
  int fo   = tid & 7;
  if (node >= n_nodes) return;
  int beg = row_ptr[node], end = row_ptr[node + 1];
  float acc[8] = {0.f, 0.f, 0.f, 0.f, 0.f, 0.f, 0.f, 0.f};
  for (int i = beg; i < end; ++i) {
    int s = edata[i].x;
    uint4 v = *reinterpret_cast<const uint4*>(h16u + (unsigned)s * 32u + fo * 4);
    acc[0] += bf_lo(v.x); acc[1] += bf_hi(v.x);
    acc[2] += bf_lo(v.y); acc[3] += bf_hi(v.y);
    acc[4] += bf_lo(v.z); acc[5] += bf_hi(v.z);
    acc[6] += bf_lo(v.w); acc[7] += bf_hi(v.w);
  }
  float4 a, b;
  a.x = acc[0]; a.y = acc[1]; a.z = acc[2]; a.w = acc[3];
  b.x = acc[4]; b.y = acc[5]; b.z = acc[6]; b.w = acc[7];
  float* out = h_agg + (size_t)node * OUT_FEATS + fo * 8;
  *reinterpret_cast<float4*>(out) = a;
  *reinterpret_cast<float4*>(out + 4) = b;
}

// ---------------------------------------------------------------------------
// t16 = bf16(tanh(h_agg)), a16 = bf16(h_agg) — streaming, all lanes active
// (folding this into agg's 8-active-lane epilogue 8x'd the tanh issue cost).
// ---------------------------------------------------------------------------
__global__ void tanh_kernel(const float4* __restrict__ h_agg,
                            ushort4* __restrict__ t16, ushort4* __restrict__ a16,
                            int n4) {
  int i = blockIdx.x * blockDim.x + threadIdx.x;
  if (i < n4) {
    float4 v = h_agg[i];
    ushort4 a;
    a.x = f2bf(v.x); a.y = f2bf(v.y); a.z = f2bf(v.z); a.w = f2bf(v.w);
    a16[i] = a;
    ushort4 o;
    o.x = f2bf(tanhf(v.x)); o.y = f2bf(tanhf(v.y));
    o.z = f2bf(tanhf(v.z)); o.w = f2bf(tanhf(v.w));
    t16[i] = o;
  }
}

// ---------------------------------------------------------------------------
// fused per-node edge softmax, 8 edges in flight over bf16 rows (R11 version:
// tail-gather skip + deg<=64 register path).
// ---------------------------------------------------------------------------
__global__ __launch_bounds__(256)
void softmax_kernel(const unsigned* __restrict__ a16u, const unsigned* __restrict__ t16u,
                    const int* __restrict__ row_ptr, const int2* __restrict__ edata,
                    float* __restrict__ e_soft, int n_nodes) {
  __shared__ float ebuf[4][MAXD];
  int wid  = (blockIdx.x * blockDim.x + threadIdx.x) >> 6;
  int lane = threadIdx.x & 63;
  int lw   = threadIdx.x >> 6;
  int eo = lane >> 3;
  int fo = lane & 7;
  if (wid >= n_nodes) return;
  int beg = row_ptr[wid], end = row_ptr[wid + 1];
  int deg = end - beg;
  if (deg == 0) return;

  uint4 tv = *reinterpret_cast<const uint4*>(t16u + (unsigned)wid * 32u + fo * 4);
  float tt[8];
  tt[0] = bf_lo(tv.x); tt[1] = bf_hi(tv.x);
  tt[2] = bf_lo(tv.y); tt[3] = bf_hi(tv.y);
  tt[4] = bf_lo(tv.z); tt[5] = bf_hi(tv.z);
  tt[6] = bf_lo(tv.w); tt[7] = bf_hi(tv.w);

  if (deg <= MAXD) {
    for (int i0 = 0; i0 < deg; i0 += 8) {
      int e = i0 + eo;
      if (e < deg) {
        int s = edata[beg + e].x;
        uint4 av = *reinterpret_cast<const uint4*>(a16u + (unsigned)s * 32u + fo * 4);
        float d = tt[0] * bf_lo(av.x) + tt[1] * bf_hi(av.x)
                + tt[2] * bf_lo(av.y) + tt[3] * bf_hi(av.y)
                + tt[4] * bf_lo(av.z) + tt[5] * bf_hi(av.z)
                + tt[6] * bf_lo(av.w) + tt[7] * bf_hi(av.w);
#pragma unroll
        for (int off = 1; off < 8; off <<= 1) d += __shfl_xor(d, off, 64);
        if (fo == 0) {
          d = d > 0.f ? d : NEG_SLOPE * d;
          ebuf[lw][e] = d;
        }
      }
    }
    if (deg <= 64) {
      float sc = (lane < deg) ? ebuf[lw][lane] : -INFINITY;
      float mx = sc;
#pragma unroll
      for (int off = 32; off > 0; off >>= 1) mx = fmaxf(mx, __shfl_xor(mx, off, 64));
      float ex = (lane < deg) ? expf(sc - mx) : 0.f;
      float sum = ex;
#pragma unroll
      for (int off = 32; off > 0; off >>= 1) sum += __shfl_xor(sum, off, 64);
      float inv = 1.f / sum;
      if (lane < deg) e_soft[edata[beg + lane].y] = ex * inv;
    } else {
      float mx = -INFINITY;
      for (int i = lane; i < deg; i += 64) mx = fmaxf(mx, ebuf[lw][i]);
#pragma unroll
      for (int off = 32; off > 0; off >>= 1) mx = fmaxf(mx, __shfl_xor(mx, off, 64));
      float sum = 0.f;
      for (int i = lane; i < deg; i += 64) {
        float ex = expf(ebuf[lw][i] - mx);
        ebuf[lw][i] = ex;
        sum += ex;
      }
#pragma unroll
      for (int off = 32; off > 0; off >>= 1) sum += __shfl_xor(sum, off, 64);
      float inv = 1.f / sum;
      for (int i = lane; i < deg; i += 64) e_soft[edata[beg + i].y] = ebuf[lw][i] * inv;
    }
  } else {
    // recompute fallback (statistically never hit with Poisson(16) degrees)
    float mx = -INFINITY;
    for (int i0 = 0; i0 < deg; i0 += 8) {
      int e = i0 + eo;
      int idx = beg + (e < deg ? e : deg - 1);
      int s = edata[idx].x;
      uint4 av = *reinterpret_cast<const uint4*>(a16u + (unsigned)s * 32u + fo * 4);
      float d = tt[0] * bf_lo(av.x) + tt[1] * bf_hi(av.x)
              + tt[2] * bf_lo(av.y) + tt[3] * bf_hi(av.y)
              + tt[4] * bf_lo(av.z) + tt[5] * bf_hi(av.z)
              + tt[6] * bf_lo(av.w) + tt[7] * bf_hi(av.w);
#pragma unroll
      for (int off = 1; off < 8; off <<= 1) d += __shfl_xor(d, off, 64);
      d = d > 0.f ? d : NEG_SLOPE * d;
      if (e >= deg) d = -INFINITY;
#pragma unroll
      for (int off = 8; off < 64; off <<= 1) d = fmaxf(d, __shfl_xor(d, off, 64));
      mx = fmaxf(mx, d);
    }
    float sum = 0.f;
    for (int i0 = 0; i0 < deg; i0 += 8) {
      int e = i0 + eo;
      int idx = beg + (e < deg ? e : deg - 1);
      int s = edata[idx].x;
      uint4 av = *reinterpret_cast<const uint4*>(a16u + (unsigned)s * 32u + fo * 4);
      float d = tt[0] * bf_lo(av.x) + tt[1] * bf_hi(av.x)
              + tt[2] * bf_lo(av.y) + tt[3] * bf_hi(av.y)
              + tt[4] * bf_lo(av.z) + tt[5] * bf_hi(av.z)
              + tt[6] * bf_lo(av.w) + tt[7] * bf_hi(av.w);
#pragma unroll
      for (int off = 1; off < 8; off <<= 1) d += __shfl_xor(d, off, 64);
      d = d > 0.f ? d : NEG_SLOPE * d;
      float ex = (e < deg) ? expf(d - mx) : 0.f;
#pragma unroll
      for (int off = 8; off < 64; off <<= 1) ex += __shfl_xor(ex, off, 64);
      sum += ex;
    }
    float inv = 1.f / sum;
    for (int i0 = 0; i0 < deg; i0 += 8) {
      int e = i0 + eo;
      int idx = beg + (e < deg ? e : deg - 1);
      int s = edata[idx].x;
      uint4 av = *reinterpret_cast<const uint4*>(a16u + (unsigned)s * 32u + fo * 4);
      float d = tt[0] * bf_lo(av.x) + tt[1] * bf_hi(av.x)
              + tt[2] * bf_lo(av.y) + tt[3] * bf_hi(av.y)
              + tt[4] * bf_lo(av.z) + tt[5] * bf_hi(av.z)
              + tt[6] * bf_lo(av.w) + tt[7] * bf_hi(av.w);
#pragma unroll
      for (int off = 1; off < 8; off <<= 1) d += __shfl_xor(d, off, 64);
      d = d > 0.f ? d : NEG_SLOPE * d;
      if (fo == 0 && e < deg) e_soft[edata[idx].y] = expf(d - mx) * inv;
    }
  }
}

extern "C" void kernel_launch(void* const* d_in, const int* in_sizes, int n_in,
                              void* d_out, int out_size, void* d_ws, size_t ws_size,
                              hipStream_t stream) {
  const float* feat = (const float*)d_in[0];
  const float* W    = (const float*)d_in[1];
  const int*   src  = (const int*)d_in[2];
  const int*   dst  = (const int*)d_in[3];
  const int n_nodes = in_sizes[0] / IN_FEATS;
  const int n_edges = in_sizes[2];
  const int nbuck   = (n_nodes + BNODES - 1) >> BSH;   // <= 512

  // Output layout: [h_agg (N*64) | e_soft (E)]
  float* h_agg  = (float*)d_out;
  float* e_soft = (float*)d_out + (size_t)n_nodes * OUT_FEATS;

  // Workspace:
  // [h16 (N*64 bf16) | a16 (N*64 bf16) | bcount(513) | bbase(513)
  //  | bcursor(512) | row_ptr(N+1 pad) | tmpe (E int2) | edata (E int2)]
  // t16 reuses h16 (dead after agg).
  unsigned short* h16 = (unsigned short*)d_ws;
  unsigned short* a16 = h16 + (size_t)n_nodes * OUT_FEATS;
  int* bcount   = (int*)(a16 + (size_t)n_nodes * OUT_FEATS);
  int* bbase    = bcount + 513;
  int* bcursor  = bbase + 513;
  int* row_ptr  = bcursor + 512;
  size_t rp_pad = ((size_t)n_nodes + 2) & ~(size_t)1;
  int2* tmpe    = (int2*)(row_ptr + rp_pad);
  int2* edata   = tmpe + n_edges;

  const int eb2 = (n_edges + CHUNK - 1) / CHUNK;
  const int wb  = (n_nodes * 64 + 255) / 256;   // wave-per-node grid (softmax)
  const int ab  = (n_nodes * 8 + 255) / 256;    // 8-lane-per-node grid (agg)

  hipMemsetAsync(bcount, 0, (size_t)nbuck * sizeof(int), stream);

  gemm_h_kernel<<<(n_nodes + 63) / 64, 256, 0, stream>>>(feat, W, h16, n_nodes);

  bhist_kernel<<<eb2, 256, 0, stream>>>(dst, bcount, n_edges, nbuck);
  bscan_kernel<<<1, 512, 0, stream>>>(bcount, bbase, bcursor, nbuck, n_edges);
  bscatter_kernel<<<eb2, 256, 0, stream>>>(src, dst, bcursor, tmpe, n_edges, nbuck);
  binB_kernel<<<nbuck, 256, 0, stream>>>(tmpe, bbase, edata, row_ptr, n_nodes, n_edges);

  agg_kernel<<<ab, 256, 0, stream>>>((const unsigned*)h16, row_ptr, edata,
                                     h_agg, n_nodes);

  // h16 dead -> reuse as t16
  unsigned short* t16 = h16;
  int n4 = n_nodes * OUT_FEATS / 4;
  tanh_kernel<<<(n4 + 255) / 256, 256, 0, stream>>>((const float4*)h_agg,
                                                    (ushort4*)t16, (ushort4*)a16, n4);

  softmax_kernel<<<wb, 256, 0, stream>>>((const unsigned*)a16, (const unsigned*)t16,
                                         row_ptr, edata, e_soft, n_nodes);
}

// Round 14
// 213.367 us; speedup vs baseline: 1.0806x; 1.0494x over previous
//
#include <hip/hip_runtime.h>
#include <math.h>

#define IN_FEATS 128
#define OUT_FEATS 64
#define NEG_SLOPE 0.2f
#define MAXD 256
#define BSH 8                      // bucket = dst >> 8 (256 nodes/bucket)
#define BNODES (1 << BSH)
#define CHUNK 4096                 // edges per block in bucket passes
#define EPT 16                     // edges per thread (CHUNK/256)
#define EID_BITS 21                // n_edges < 2^21
#define LDP 132                    // padded LDS row stride (floats)

typedef _Float16 half2_t __attribute__((ext_vector_type(2)));

// bf16 helpers (h16 stays bf16 for agg's accumulation path)
__device__ __forceinline__ float bf_lo(unsigned u) { return __uint_as_float(u << 16); }
__device__ __forceinline__ float bf_hi(unsigned u) { return __uint_as_float(u & 0xffff0000u); }
__device__ __forceinline__ unsigned short f2bf(float f) {
  unsigned x = __float_as_uint(f);
  x += 0x7fff + ((x >> 16) & 1);          // round to nearest even
  return (unsigned short)(x >> 16);
}
// bit-cast any 4-byte vector (cvt_pkrtz returns __fp16x2, fdot2 takes _Float16x2)
template <typename T>
__device__ __forceinline__ unsigned h2u(T h) {
  union { T h; unsigned u; } c; c.h = h; return c.u;
}

// ---------------------------------------------------------------------------
// K1: h16 = bf16(feat @ W^T), LDS-tiled (proven R9-R12).
// ---------------------------------------------------------------------------
__global__ __launch_bounds__(256)
void gemm_h_kernel(const float* __restrict__ feat,
                   const float* __restrict__ W,
                   unsigned short* __restrict__ h16, int n_nodes) {
  __shared__ float fs[64 * LDP];
  __shared__ float ws[64 * LDP];
  const int t  = threadIdx.x;
  const int n0 = blockIdx.x * 64;

  for (int i = t; i < 64 * 32; i += 256) {
    int r = i >> 5, c4 = i & 31;
    float4 v = *reinterpret_cast<const float4*>(W + r * IN_FEATS + c4 * 4);
    *reinterpret_cast<float4*>(&ws[r * LDP + c4 * 4]) = v;
  }
  for (int i = t; i < 64 * 32; i += 256) {
    int r = i >> 5, c4 = i & 31;
    int n = n0 + r;
    float4 v = {0.f, 0.f, 0.f, 0.f};
    if (n < n_nodes)
      v = *reinterpret_cast<const float4*>(feat + (size_t)n * IN_FEATS + c4 * 4);
    *reinterpret_cast<float4*>(&fs[r * LDP + c4 * 4]) = v;
  }
  __syncthreads();

  const int l  = t & 63, q = t >> 6;
  const int ob = (l & 15) * 4;            // output base (4 outputs)
  const int nb = q * 16 + (l >> 4) * 4;   // node base (4 nodes)

  float acc[4][4] = {{0.f}};
  for (int k4 = 0; k4 < 32; ++k4) {
    float4 fr[4], wr[4];
#pragma unroll
    for (int i = 0; i < 4; ++i)
      fr[i] = *reinterpret_cast<const float4*>(&fs[(nb + i) * LDP + k4 * 4]);
#pragma unroll
    for (int j = 0; j < 4; ++j)
      wr[j] = *reinterpret_cast<const float4*>(&ws[(ob + j) * LDP + k4 * 4]);
#pragma unroll
    for (int i = 0; i < 4; ++i) {
#pragma unroll
      for (int j = 0; j < 4; ++j) {
        acc[i][j] = fmaf(fr[i].x, wr[j].x, acc[i][j]);
        acc[i][j] = fmaf(fr[i].y, wr[j].y, acc[i][j]);
        acc[i][j] = fmaf(fr[i].z, wr[j].z, acc[i][j]);
        acc[i][j] = fmaf(fr[i].w, wr[j].w, acc[i][j]);
      }
    }
  }

#pragma unroll
  for (int i = 0; i < 4; ++i) {
    int node = n0 + nb + i;
    if (node < n_nodes) {
      ushort4 o;
      o.x = f2bf(acc[i][0]); o.y = f2bf(acc[i][1]);
      o.z = f2bf(acc[i][2]); o.w = f2bf(acc[i][3]);
      *reinterpret_cast<ushort4*>(h16 + (size_t)node * OUT_FEATS + ob) = o;
    }
  }
}

// ---------------------------------------------------------------------------
// Bucket sort pass A1: per-bucket edge counts
// ---------------------------------------------------------------------------
__global__ __launch_bounds__(256)
void bhist_kernel(const int* __restrict__ dst, int* __restrict__ bcount,
                  int n_edges, int nbuck) {
  __shared__ int hist[512];
  const int t = threadIdx.x;
  for (int i = t; i < nbuck; i += 256) hist[i] = 0;
  __syncthreads();
  const int base = blockIdx.x * CHUNK;
#pragma unroll
  for (int i = 0; i < EPT; ++i) {
    int e = base + t + i * 256;
    if (e < n_edges) atomicAdd(&hist[dst[e] >> BSH], 1);
  }
  __syncthreads();
  for (int i = t; i < nbuck; i += 256)
    if (hist[i]) atomicAdd(&bcount[i], hist[i]);
}

// ---------------------------------------------------------------------------
// A2: exclusive scan of bucket counts
// ---------------------------------------------------------------------------
__global__ void bscan_kernel(const int* __restrict__ bcount, int* __restrict__ bbase,
                             int* __restrict__ bcursor, int nbuck, int n_edges) {
  __shared__ int tmp[512];
  const int t = threadIdx.x;
  int v = (t < nbuck) ? bcount[t] : 0;
  tmp[t] = v;
  __syncthreads();
  for (int off = 1; off < 512; off <<= 1) {
    int x = (t >= off) ? tmp[t - off] : 0;
    __syncthreads();
    tmp[t] += x;
    __syncthreads();
  }
  if (t < nbuck) { int excl = tmp[t] - v; bbase[t] = excl; bcursor[t] = excl; }
  if (t == 0) bbase[nbuck] = n_edges;
}

// ---------------------------------------------------------------------------
// A3: scatter edges into bucket regions
// ---------------------------------------------------------------------------
__global__ __launch_bounds__(256)
void bscatter_kernel(const int* __restrict__ src, const int* __restrict__ dst,
                     int* __restrict__ bcursor, int2* __restrict__ tmpe,
                     int n_edges, int nbuck) {
  __shared__ int hist[512];
  __shared__ int basech[512];
  __shared__ int offs[512];
  const int t = threadIdx.x;
  const int base = blockIdx.x * CHUNK;
  for (int i = t; i < nbuck; i += 256) { hist[i] = 0; offs[i] = 0; }
  __syncthreads();
  int s16a[EPT], d16a[EPT];
#pragma unroll
  for (int i = 0; i < EPT; ++i) {
    int e = base + t + i * 256;
    if (e < n_edges) {
      s16a[i] = src[e];
      d16a[i] = dst[e];
      atomicAdd(&hist[d16a[i] >> BSH], 1);
    } else {
      d16a[i] = -1;
    }
  }
  __syncthreads();
  for (int i = t; i < nbuck; i += 256)
    if (hist[i]) basech[i] = atomicAdd(&bcursor[i], hist[i]);
  __syncthreads();
#pragma unroll
  for (int i = 0; i < EPT; ++i) {
    if (d16a[i] >= 0) {
      int e = base + t + i * 256;
      int b = d16a[i] >> BSH;
      int off = atomicAdd(&offs[b], 1);
      int2 v;
      v.x = s16a[i];
      v.y = ((d16a[i] & (BNODES - 1)) << EID_BITS) | e;
      tmpe[basech[b] + off] = v;
    }
  }
}

// ---------------------------------------------------------------------------
// B: one workgroup per bucket -> row_ptr + final CSR edata (src,eid).
// ---------------------------------------------------------------------------
__global__ __launch_bounds__(256)
void binB_kernel(const int2* __restrict__ tmpe, const int* __restrict__ bbase,
                 int2* __restrict__ edata, int* __restrict__ row_ptr,
                 int n_nodes, int n_edges) {
  __shared__ int cnt[BNODES];
  __shared__ int cur[BNODES];
  const int b = blockIdx.x;
  const int t = threadIdx.x;
  const int beg = bbase[b], end = bbase[b + 1];

  cnt[t] = 0;
  __syncthreads();
  for (int i = beg + t; i < end; i += 256)
    atomicAdd(&cnt[(tmpe[i].y >> EID_BITS) & (BNODES - 1)], 1);
  __syncthreads();

  int v = cnt[t];
  cur[t] = v;
  __syncthreads();
  for (int off = 1; off < BNODES; off <<= 1) {
    int x = (t >= off) ? cur[t - off] : 0;
    __syncthreads();
    cur[t] += x;
    __syncthreads();
  }
  int excl = cur[t] - v;
  int node = b * BNODES + t;
  if (node < n_nodes) row_ptr[node] = beg + excl;
  if (b == 0 && t == 0) row_ptr[n_nodes] = n_edges;
  __syncthreads();
  cur[t] = beg + excl;
  __syncthreads();

  for (int i = beg + t; i < end; i += 256) {
    int2 p = tmpe[i];
    int l = (p.y >> EID_BITS) & (BNODES - 1);
    int pos = atomicAdd(&cur[l], 1);
    int2 o;
    o.x = p.x;
    o.y = p.y & ((1 << EID_BITS) - 1);
    edata[pos] = o;
  }
}

// ---------------------------------------------------------------------------
// agg: 8 nodes per wave, 8 lanes per node, lane fo owns feats 8fo..8fo+7.
// Zero cross-lane ops. Epilogue: every lane owns 8 distinct feats, so
// emitting a16 = f16(acc) and t16 = f16(tanh(acc)) here has NO lane
// redundancy (unlike R11's eo==0 version) and kills the tanh pass.
// ---------------------------------------------------------------------------
__global__ void agg_kernel(const unsigned* __restrict__ h16u,  // rows of 32 uints
                           const int* __restrict__ row_ptr,
                           const int2* __restrict__ edata, float* __restrict__ h_agg,
                           unsigned* __restrict__ a16u, unsigned* __restrict__ t16u,
                           int n_nodes) {
  int tid  = blockIdx.x * blockDim.x + threadIdx.x;
  int node = tid >> 3;
  int fo   = tid & 7;
  if (node >= n_nodes) return;
  int beg = row_ptr[node], end = row_ptr[node + 1];
  float acc[8] = {0.f, 0.f, 0.f, 0.f, 0.f, 0.f, 0.f, 0.f};
  for (int i = beg; i < end; ++i) {
    int s = edata[i].x;
    uint4 v = *reinterpret_cast<const uint4*>(h16u + (unsigned)s * 32u + fo * 4);
    acc[0] += bf_lo(v.x); acc[1] += bf_hi(v.x);
    acc[2] += bf_lo(v.y); acc[3] += bf_hi(v.y);
    acc[4] += bf_lo(v.z); acc[5] += bf_hi(v.z);
    acc[6] += bf_lo(v.w); acc[7] += bf_hi(v.w);
  }
  float4 a, b;
  a.x = acc[0]; a.y = acc[1]; a.z = acc[2]; a.w = acc[3];
  b.x = acc[4]; b.y = acc[5]; b.z = acc[6]; b.w = acc[7];
  float* out = h_agg + (size_t)node * OUT_FEATS + fo * 8;
  *reinterpret_cast<float4*>(out) = a;
  *reinterpret_cast<float4*>(out + 4) = b;

  uint4 pa;
  pa.x = h2u(__builtin_amdgcn_cvt_pkrtz(acc[0], acc[1]));
  pa.y = h2u(__builtin_amdgcn_cvt_pkrtz(acc[2], acc[3]));
  pa.z = h2u(__builtin_amdgcn_cvt_pkrtz(acc[4], acc[5]));
  pa.w = h2u(__builtin_amdgcn_cvt_pkrtz(acc[6], acc[7]));
  *reinterpret_cast<uint4*>(a16u + (unsigned)node * 32u + fo * 4) = pa;

  uint4 pt;
  pt.x = h2u(__builtin_amdgcn_cvt_pkrtz(tanhf(acc[0]), tanhf(acc[1])));
  pt.y = h2u(__builtin_amdgcn_cvt_pkrtz(tanhf(acc[2]), tanhf(acc[3])));
  pt.z = h2u(__builtin_amdgcn_cvt_pkrtz(tanhf(acc[4]), tanhf(acc[5])));
  pt.w = h2u(__builtin_amdgcn_cvt_pkrtz(tanhf(acc[6]), tanhf(acc[7])));
  *reinterpret_cast<uint4*>(t16u + (unsigned)node * 32u + fo * 4) = pt;
}

// ---------------------------------------------------------------------------
// fused per-node edge softmax, 8 edges in flight over f16 rows.
// Dot = 4x v_dot2_f32_f16 per lane (2 MACs/instr, no unpack) vs the old
// 16 FMA + 16 bf16 unpack ops.
// ---------------------------------------------------------------------------
__global__ __launch_bounds__(256)
void softmax_kernel(const unsigned* __restrict__ a16u, const unsigned* __restrict__ t16u,
                    const int* __restrict__ row_ptr, const int2* __restrict__ edata,
                    float* __restrict__ e_soft, int n_nodes) {
  __shared__ float ebuf[4][MAXD];
  int wid  = (blockIdx.x * blockDim.x + threadIdx.x) >> 6;
  int lane = threadIdx.x & 63;
  int lw   = threadIdx.x >> 6;
  int eo = lane >> 3;
  int fo = lane & 7;
  if (wid >= n_nodes) return;
  int beg = row_ptr[wid], end = row_ptr[wid + 1];
  int deg = end - beg;
  if (deg == 0) return;

  union { uint4 u; half2_t h[4]; } tc;
  tc.u = *reinterpret_cast<const uint4*>(t16u + (unsigned)wid * 32u + fo * 4);

  if (deg <= MAXD) {
    for (int i0 = 0; i0 < deg; i0 += 8) {
      int e = i0 + eo;
      if (e < deg) {                         // group-uniform guard: no dup gathers
        int s = edata[beg + e].x;
        union { uint4 u; half2_t h[4]; } ac;
        ac.u = *reinterpret_cast<const uint4*>(a16u + (unsigned)s * 32u + fo * 4);
        float d = 0.f;
        d = __builtin_amdgcn_fdot2(ac.h[0], tc.h[0], d, false);
        d = __builtin_amdgcn_fdot2(ac.h[1], tc.h[1], d, false);
        d = __builtin_amdgcn_fdot2(ac.h[2], tc.h[2], d, false);
        d = __builtin_amdgcn_fdot2(ac.h[3], tc.h[3], d, false);
#pragma unroll
        for (int off = 1; off < 8; off <<= 1) d += __shfl_xor(d, off, 64);
        if (fo == 0) {
          d = d > 0.f ? d : NEG_SLOPE * d;
          ebuf[lw][e] = d;
        }
      }
    }
    if (deg <= 64) {
      // register tail: lane i owns score i
      float sc = (lane < deg) ? ebuf[lw][lane] : -INFINITY;
      float mx = sc;
#pragma unroll
      for (int off = 32; off > 0; off >>= 1) mx = fmaxf(mx, __shfl_xor(mx, off, 64));
      float ex = (lane < deg) ? expf(sc - mx) : 0.f;
      float sum = ex;
#pragma unroll
      for (int off = 32; off > 0; off >>= 1) sum += __shfl_xor(sum, off, 64);
      float inv = 1.f / sum;
      if (lane < deg) e_soft[edata[beg + lane].y] = ex * inv;
    } else {
      float mx = -INFINITY;
      for (int i = lane; i < deg; i += 64) mx = fmaxf(mx, ebuf[lw][i]);
#pragma unroll
      for (int off = 32; off > 0; off >>= 1) mx = fmaxf(mx, __shfl_xor(mx, off, 64));
      float sum = 0.f;
      for (int i = lane; i < deg; i += 64) {
        float ex = expf(ebuf[lw][i] - mx);
        ebuf[lw][i] = ex;
        sum += ex;
      }
#pragma unroll
      for (int off = 32; off > 0; off >>= 1) sum += __shfl_xor(sum, off, 64);
      float inv = 1.f / sum;
      for (int i = lane; i < deg; i += 64) e_soft[edata[beg + i].y] = ebuf[lw][i] * inv;
    }
  } else {
    // recompute fallback (statistically never hit with Poisson(16) degrees)
    float mx = -INFINITY;
    for (int i0 = 0; i0 < deg; i0 += 8) {
      int e = i0 + eo;
      int idx = beg + (e < deg ? e : deg - 1);
      int s = edata[idx].x;
      union { uint4 u; half2_t h[4]; } ac;
      ac.u = *reinterpret_cast<const uint4*>(a16u + (unsigned)s * 32u + fo * 4);
      float d = 0.f;
      d = __builtin_amdgcn_fdot2(ac.h[0], tc.h[0], d, false);
      d = __builtin_amdgcn_fdot2(ac.h[1], tc.h[1], d, false);
      d = __builtin_amdgcn_fdot2(ac.h[2], tc.h[2], d, false);
      d = __builtin_amdgcn_fdot2(ac.h[3], tc.h[3], d, false);
#pragma unroll
      for (int off = 1; off < 8; off <<= 1) d += __shfl_xor(d, off, 64);
      d = d > 0.f ? d : NEG_SLOPE * d;
      if (e >= deg) d = -INFINITY;
#pragma unroll
      for (int off = 8; off < 64; off <<= 1) d = fmaxf(d, __shfl_xor(d, off, 64));
      mx = fmaxf(mx, d);
    }
    float sum = 0.f;
    for (int i0 = 0; i0 < deg; i0 += 8) {
      int e = i0 + eo;
      int idx = beg + (e < deg ? e : deg - 1);
      int s = edata[idx].x;
      union { uint4 u; half2_t h[4]; } ac;
      ac.u = *reinterpret_cast<const uint4*>(a16u + (unsigned)s * 32u + fo * 4);
      float d = 0.f;
      d = __builtin_amdgcn_fdot2(ac.h[0], tc.h[0], d, false);
      d = __builtin_amdgcn_fdot2(ac.h[1], tc.h[1], d, false);
      d = __builtin_amdgcn_fdot2(ac.h[2], tc.h[2], d, false);
      d = __builtin_amdgcn_fdot2(ac.h[3], tc.h[3], d, false);
#pragma unroll
      for (int off = 1; off < 8; off <<= 1) d += __shfl_xor(d, off, 64);
      d = d > 0.f ? d : NEG_SLOPE * d;
      float ex = (e < deg) ? expf(d - mx) : 0.f;
#pragma unroll
      for (int off = 8; off < 64; off <<= 1) ex += __shfl_xor(ex, off, 64);
      sum += ex;
    }
    float inv = 1.f / sum;
    for (int i0 = 0; i0 < deg; i0 += 8) {
      int e = i0 + eo;
      int idx = beg + (e < deg ? e : deg - 1);
      int s = edata[idx].x;
      union { uint4 u; half2_t h[4]; } ac;
      ac.u = *reinterpret_cast<const uint4*>(a16u + (unsigned)s * 32u + fo * 4);
      float d = 0.f;
      d = __builtin_amdgcn_fdot2(ac.h[0], tc.h[0], d, false);
      d = __builtin_amdgcn_fdot2(ac.h[1], tc.h[1], d, false);
      d = __builtin_amdgcn_fdot2(ac.h[2], tc.h[2], d, false);
      d = __builtin_amdgcn_fdot2(ac.h[3], tc.h[3], d, false);
#pragma unroll
      for (int off = 1; off < 8; off <<= 1) d += __shfl_xor(d, off, 64);
      d = d > 0.f ? d : NEG_SLOPE * d;
      if (fo == 0 && e < deg) e_soft[edata[idx].y] = expf(d - mx) * inv;
    }
  }
}

extern "C" void kernel_launch(void* const* d_in, const int* in_sizes, int n_in,
                              void* d_out, int out_size, void* d_ws, size_t ws_size,
                              hipStream_t stream) {
  const float* feat = (const float*)d_in[0];
  const float* W    = (const float*)d_in[1];
  const int*   src  = (const int*)d_in[2];
  const int*   dst  = (const int*)d_in[3];
  const int n_nodes = in_sizes[0] / IN_FEATS;
  const int n_edges = in_sizes[2];
  const int nbuck   = (n_nodes + BNODES - 1) >> BSH;   // <= 512

  // Output layout: [h_agg (N*64) | e_soft (E)]
  float* h_agg  = (float*)d_out;
  float* e_soft = (float*)d_out + (size_t)n_nodes * OUT_FEATS;

  // Workspace:
  // [h16 (N*64 bf16) | a16 (N*64 f16) | bcount(513) | bbase(513)
  //  | bcursor(512) | row_ptr(N+1 pad) | tmpe (E int2) | edata (E int2)]
  // t16 aliases tmpe (dead after binB; agg runs after binB and must NOT
  // alias h16, which it reads).
  unsigned short* h16 = (unsigned short*)d_ws;
  unsigned short* a16 = h16 + (size_t)n_nodes * OUT_FEATS;
  int* bcount   = (int*)(a16 + (size_t)n_nodes * OUT_FEATS);
  int* bbase    = bcount + 513;
  int* bcursor  = bbase + 513;
  int* row_ptr  = bcursor + 512;
  size_t rp_pad = ((size_t)n_nodes + 2) & ~(size_t)1;
  int2* tmpe    = (int2*)(row_ptr + rp_pad);
  int2* edata   = tmpe + n_edges;
  unsigned* t16 = (unsigned*)tmpe;          // N*32 uints <= E*2 ints: fits

  const int eb2 = (n_edges + CHUNK - 1) / CHUNK;
  const int wb  = (n_nodes * 64 + 255) / 256;   // wave-per-node grid (softmax)
  const int ab  = (n_nodes * 8 + 255) / 256;    // 8-lane-per-node grid (agg)

  hipMemsetAsync(bcount, 0, (size_t)nbuck * sizeof(int), stream);

  gemm_h_kernel<<<(n_nodes + 63) / 64, 256, 0, stream>>>(feat, W, h16, n_nodes);

  bhist_kernel<<<eb2, 256, 0, stream>>>(dst, bcount, n_edges, nbuck);
  bscan_kernel<<<1, 512, 0, stream>>>(bcount, bbase, bcursor, nbuck, n_edges);
  bscatter_kernel<<<eb2, 256, 0, stream>>>(src, dst, bcursor, tmpe, n_edges, nbuck);
  binB_kernel<<<nbuck, 256, 0, stream>>>(tmpe, bbase, edata, row_ptr, n_nodes, n_edges);

  agg_kernel<<<ab, 256, 0, stream>>>((const unsigned*)h16, row_ptr, edata,
                                     h_agg, (unsigned*)a16, t16, n_nodes);

  softmax_kernel<<<wb, 256, 0, stream>>>((const unsigned*)a16, (const unsigned*)t16,
                                         row_ptr, edata, e_soft, n_nodes);
}

// Round 15
// 210.369 us; speedup vs baseline: 1.0960x; 1.0142x over previous
//
#include <hip/hip_runtime.h>
#include <math.h>

#define IN_FEATS 128
#define OUT_FEATS 64
#define NEG_SLOPE 0.2f
#define MAXD 256
#define BSH 8                      // bucket = dst >> 8 (256 nodes/bucket)
#define BNODES (1 << BSH)
#define CHUNK 4096                 // edges per block in bucket passes
#define EPT 16                     // edges per thread (CHUNK/256)
#define EID_BITS 21                // n_edges < 2^21
#define LDP 132                    // padded LDS row stride (floats)

typedef _Float16 half2_t __attribute__((ext_vector_type(2)));

// bf16 helpers (h16 stays bf16 for agg's accumulation path)
__device__ __forceinline__ float bf_lo(unsigned u) { return __uint_as_float(u << 16); }
__device__ __forceinline__ float bf_hi(unsigned u) { return __uint_as_float(u & 0xffff0000u); }
__device__ __forceinline__ unsigned short f2bf(float f) {
  unsigned x = __float_as_uint(f);
  x += 0x7fff + ((x >> 16) & 1);          // round to nearest even
  return (unsigned short)(x >> 16);
}
// bit-cast any 4-byte vector (cvt_pkrtz returns __fp16x2, fdot2 takes _Float16x2)
template <typename T>
__device__ __forceinline__ unsigned h2u(T h) {
  union { T h; unsigned u; } c; c.h = h; return c.u;
}

// ---------------------------------------------------------------------------
// K1: h16 = bf16(feat @ W^T), LDS-tiled (proven R9-R14).
// ---------------------------------------------------------------------------
__global__ __launch_bounds__(256)
void gemm_h_kernel(const float* __restrict__ feat,
                   const float* __restrict__ W,
                   unsigned short* __restrict__ h16, int n_nodes) {
  __shared__ float fs[64 * LDP];
  __shared__ float ws[64 * LDP];
  const int t  = threadIdx.x;
  const int n0 = blockIdx.x * 64;

  for (int i = t; i < 64 * 32; i += 256) {
    int r = i >> 5, c4 = i & 31;
    float4 v = *reinterpret_cast<const float4*>(W + r * IN_FEATS + c4 * 4);
    *reinterpret_cast<float4*>(&ws[r * LDP + c4 * 4]) = v;
  }
  for (int i = t; i < 64 * 32; i += 256) {
    int r = i >> 5, c4 = i & 31;
    int n = n0 + r;
    float4 v = {0.f, 0.f, 0.f, 0.f};
    if (n < n_nodes)
      v = *reinterpret_cast<const float4*>(feat + (size_t)n * IN_FEATS + c4 * 4);
    *reinterpret_cast<float4*>(&fs[r * LDP + c4 * 4]) = v;
  }
  __syncthreads();

  const int l  = t & 63, q = t >> 6;
  const int ob = (l & 15) * 4;            // output base (4 outputs)
  const int nb = q * 16 + (l >> 4) * 4;   // node base (4 nodes)

  float acc[4][4] = {{0.f}};
  for (int k4 = 0; k4 < 32; ++k4) {
    float4 fr[4], wr[4];
#pragma unroll
    for (int i = 0; i < 4; ++i)
      fr[i] = *reinterpret_cast<const float4*>(&fs[(nb + i) * LDP + k4 * 4]);
#pragma unroll
    for (int j = 0; j < 4; ++j)
      wr[j] = *reinterpret_cast<const float4*>(&ws[(ob + j) * LDP + k4 * 4]);
#pragma unroll
    for (int i = 0; i < 4; ++i) {
#pragma unroll
      for (int j = 0; j < 4; ++j) {
        acc[i][j] = fmaf(fr[i].x, wr[j].x, acc[i][j]);
        acc[i][j] = fmaf(fr[i].y, wr[j].y, acc[i][j]);
        acc[i][j] = fmaf(fr[i].z, wr[j].z, acc[i][j]);
        acc[i][j] = fmaf(fr[i].w, wr[j].w, acc[i][j]);
      }
    }
  }

#pragma unroll
  for (int i = 0; i < 4; ++i) {
    int node = n0 + nb + i;
    if (node < n_nodes) {
      ushort4 o;
      o.x = f2bf(acc[i][0]); o.y = f2bf(acc[i][1]);
      o.z = f2bf(acc[i][2]); o.w = f2bf(acc[i][3]);
      *reinterpret_cast<ushort4*>(h16 + (size_t)node * OUT_FEATS + ob) = o;
    }
  }
}

// ---------------------------------------------------------------------------
// Bucket sort pass A1: per-bucket edge counts
// ---------------------------------------------------------------------------
__global__ __launch_bounds__(256)
void bhist_kernel(const int* __restrict__ dst, int* __restrict__ bcount,
                  int n_edges, int nbuck) {
  __shared__ int hist[512];
  const int t = threadIdx.x;
  for (int i = t; i < nbuck; i += 256) hist[i] = 0;
  __syncthreads();
  const int base = blockIdx.x * CHUNK;
#pragma unroll
  for (int i = 0; i < EPT; ++i) {
    int e = base + t + i * 256;
    if (e < n_edges) atomicAdd(&hist[dst[e] >> BSH], 1);
  }
  __syncthreads();
  for (int i = t; i < nbuck; i += 256)
    if (hist[i]) atomicAdd(&bcount[i], hist[i]);
}

// ---------------------------------------------------------------------------
// A2: exclusive scan of bucket counts
// ---------------------------------------------------------------------------
__global__ void bscan_kernel(const int* __restrict__ bcount, int* __restrict__ bbase,
                             int* __restrict__ bcursor, int nbuck, int n_edges) {
  __shared__ int tmp[512];
  const int t = threadIdx.x;
  int v = (t < nbuck) ? bcount[t] : 0;
  tmp[t] = v;
  __syncthreads();
  for (int off = 1; off < 512; off <<= 1) {
    int x = (t >= off) ? tmp[t - off] : 0;
    __syncthreads();
    tmp[t] += x;
    __syncthreads();
  }
  if (t < nbuck) { int excl = tmp[t] - v; bbase[t] = excl; bcursor[t] = excl; }
  if (t == 0) bbase[nbuck] = n_edges;
}

// ---------------------------------------------------------------------------
// A3: scatter edges into bucket regions
// ---------------------------------------------------------------------------
__global__ __launch_bounds__(256)
void bscatter_kernel(const int* __restrict__ src, const int* __restrict__ dst,
                     int* __restrict__ bcursor, int2* __restrict__ tmpe,
                     int n_edges, int nbuck) {
  __shared__ int hist[512];
  __shared__ int basech[512];
  __shared__ int offs[512];
  const int t = threadIdx.x;
  const int base = blockIdx.x * CHUNK;
  for (int i = t; i < nbuck; i += 256) { hist[i] = 0; offs[i] = 0; }
  __syncthreads();
  int s16a[EPT], d16a[EPT];
#pragma unroll
  for (int i = 0; i < EPT; ++i) {
    int e = base + t + i * 256;
    if (e < n_edges) {
      s16a[i] = src[e];
      d16a[i] = dst[e];
      atomicAdd(&hist[d16a[i] >> BSH], 1);
    } else {
      d16a[i] = -1;
    }
  }
  __syncthreads();
  for (int i = t; i < nbuck; i += 256)
    if (hist[i]) basech[i] = atomicAdd(&bcursor[i], hist[i]);
  __syncthreads();
#pragma unroll
  for (int i = 0; i < EPT; ++i) {
    if (d16a[i] >= 0) {
      int e = base + t + i * 256;
      int b = d16a[i] >> BSH;
      int off = atomicAdd(&offs[b], 1);
      int2 v;
      v.x = s16a[i];
      v.y = ((d16a[i] & (BNODES - 1)) << EID_BITS) | e;
      tmpe[basech[b] + off] = v;
    }
  }
}

// ---------------------------------------------------------------------------
// B: one workgroup per bucket -> row_ptr + final CSR edata (src,eid).
// ---------------------------------------------------------------------------
__global__ __launch_bounds__(256)
void binB_kernel(const int2* __restrict__ tmpe, const int* __restrict__ bbase,
                 int2* __restrict__ edata, int* __restrict__ row_ptr,
                 int n_nodes, int n_edges) {
  __shared__ int cnt[BNODES];
  __shared__ int cur[BNODES];
  const int b = blockIdx.x;
  const int t = threadIdx.x;
  const int beg = bbase[b], end = bbase[b + 1];

  cnt[t] = 0;
  __syncthreads();
  for (int i = beg + t; i < end; i += 256)
    atomicAdd(&cnt[(tmpe[i].y >> EID_BITS) & (BNODES - 1)], 1);
  __syncthreads();

  int v = cnt[t];
  cur[t] = v;
  __syncthreads();
  for (int off = 1; off < BNODES; off <<= 1) {
    int x = (t >= off) ? cur[t - off] : 0;
    __syncthreads();
    cur[t] += x;
    __syncthreads();
  }
  int excl = cur[t] - v;
  int node = b * BNODES + t;
  if (node < n_nodes) row_ptr[node] = beg + excl;
  if (b == 0 && t == 0) row_ptr[n_nodes] = n_edges;
  __syncthreads();
  cur[t] = beg + excl;
  __syncthreads();

  for (int i = beg + t; i < end; i += 256) {
    int2 p = tmpe[i];
    int l = (p.y >> EID_BITS) & (BNODES - 1);
    int pos = atomicAdd(&cur[l], 1);
    int2 o;
    o.x = p.x;
    o.y = p.y & ((1 << EID_BITS) - 1);
    edata[pos] = o;
  }
}

// ---------------------------------------------------------------------------
// agg: 8 nodes per wave, 8 lanes per node. Software-pipelined: gather i+1
// issued before accumulating i -> 2 loads in flight per lane.
// Epilogue emits a16/t16 (f16) with full lane utilization.
// ---------------------------------------------------------------------------
__global__ void agg_kernel(const unsigned* __restrict__ h16u,  // rows of 32 uints
                           const int* __restrict__ row_ptr,
                           const int2* __restrict__ edata, float* __restrict__ h_agg,
                           unsigned* __restrict__ a16u, unsigned* __restrict__ t16u,
                           int n_nodes) {
  int tid  = blockIdx.x * blockDim.x + threadIdx.x;
  int node = tid >> 3;
  int fo   = tid & 7;
  if (node >= n_nodes) return;
  int beg = row_ptr[node], end = row_ptr[node + 1];
  float acc[8] = {0.f, 0.f, 0.f, 0.f, 0.f, 0.f, 0.f, 0.f};
  if (beg < end) {
    uint4 v = *reinterpret_cast<const uint4*>(
        h16u + (unsigned)edata[beg].x * 32u + fo * 4);
    for (int i = beg + 1; i < end; ++i) {
      uint4 vn = *reinterpret_cast<const uint4*>(
          h16u + (unsigned)edata[i].x * 32u + fo * 4);   // next gather in flight
      acc[0] += bf_lo(v.x); acc[1] += bf_hi(v.x);
      acc[2] += bf_lo(v.y); acc[3] += bf_hi(v.y);
      acc[4] += bf_lo(v.z); acc[5] += bf_hi(v.z);
      acc[6] += bf_lo(v.w); acc[7] += bf_hi(v.w);
      v = vn;
    }
    acc[0] += bf_lo(v.x); acc[1] += bf_hi(v.x);
    acc[2] += bf_lo(v.y); acc[3] += bf_hi(v.y);
    acc[4] += bf_lo(v.z); acc[5] += bf_hi(v.z);
    acc[6] += bf_lo(v.w); acc[7] += bf_hi(v.w);
  }
  float4 a, b;
  a.x = acc[0]; a.y = acc[1]; a.z = acc[2]; a.w = acc[3];
  b.x = acc[4]; b.y = acc[5]; b.z = acc[6]; b.w = acc[7];
  float* out = h_agg + (size_t)node * OUT_FEATS + fo * 8;
  *reinterpret_cast<float4*>(out) = a;
  *reinterpret_cast<float4*>(out + 4) = b;

  uint4 pa;
  pa.x = h2u(__builtin_amdgcn_cvt_pkrtz(acc[0], acc[1]));
  pa.y = h2u(__builtin_amdgcn_cvt_pkrtz(acc[2], acc[3]));
  pa.z = h2u(__builtin_amdgcn_cvt_pkrtz(acc[4], acc[5]));
  pa.w = h2u(__builtin_amdgcn_cvt_pkrtz(acc[6], acc[7]));
  *reinterpret_cast<uint4*>(a16u + (unsigned)node * 32u + fo * 4) = pa;

  uint4 pt;
  pt.x = h2u(__builtin_amdgcn_cvt_pkrtz(tanhf(acc[0]), tanhf(acc[1])));
  pt.y = h2u(__builtin_amdgcn_cvt_pkrtz(tanhf(acc[2]), tanhf(acc[3])));
  pt.z = h2u(__builtin_amdgcn_cvt_pkrtz(tanhf(acc[4]), tanhf(acc[5])));
  pt.w = h2u(__builtin_amdgcn_cvt_pkrtz(tanhf(acc[6]), tanhf(acc[7])));
  *reinterpret_cast<uint4*>(t16u + (unsigned)node * 32u + fo * 4) = pt;
}

// ---------------------------------------------------------------------------
// fused per-node edge softmax over f16 rows.
// deg<=32 (99.98% of Poisson-16 nodes): 4 unrolled 8-edge chunks, scores in
// registers, all 4 gathers in flight, no LDS round trip; max/sum = 3 reg ops
// + 3 eo-stride shuffles. Dead chunks (group-uniform guard) skip via execz.
// 32<deg<=256: LDS path. deg>256: recompute fallback.
// ---------------------------------------------------------------------------
__global__ __launch_bounds__(256)
void softmax_kernel(const unsigned* __restrict__ a16u, const unsigned* __restrict__ t16u,
                    const int* __restrict__ row_ptr, const int2* __restrict__ edata,
                    float* __restrict__ e_soft, int n_nodes) {
  __shared__ float ebuf[4][MAXD];
  int wid  = (blockIdx.x * blockDim.x + threadIdx.x) >> 6;
  int lane = threadIdx.x & 63;
  int lw   = threadIdx.x >> 6;
  int eo = lane >> 3;
  int fo = lane & 7;
  if (wid >= n_nodes) return;
  int beg = row_ptr[wid], end = row_ptr[wid + 1];
  int deg = end - beg;
  if (deg == 0) return;

  union { uint4 u; half2_t h[4]; } tc;
  tc.u = *reinterpret_cast<const uint4*>(t16u + (unsigned)wid * 32u + fo * 4);

  if (deg <= 32) {
    float s[4];
#pragma unroll
    for (int k = 0; k < 4; ++k) {
      int e = k * 8 + eo;
      float d = -INFINITY;
      if (e < deg) {
        int sidx = edata[beg + e].x;
        union { uint4 u; half2_t h[4]; } ac;
        ac.u = *reinterpret_cast<const uint4*>(a16u + (unsigned)sidx * 32u + fo * 4);
        d = 0.f;
        d = __builtin_amdgcn_fdot2(ac.h[0], tc.h[0], d, false);
        d = __builtin_amdgcn_fdot2(ac.h[1], tc.h[1], d, false);
        d = __builtin_amdgcn_fdot2(ac.h[2], tc.h[2], d, false);
        d = __builtin_amdgcn_fdot2(ac.h[3], tc.h[3], d, false);
#pragma unroll
        for (int off = 1; off < 8; off <<= 1) d += __shfl_xor(d, off, 64);
        d = d > 0.f ? d : NEG_SLOPE * d;
      }
      s[k] = d;
    }
    float mx = fmaxf(fmaxf(s[0], s[1]), fmaxf(s[2], s[3]));
#pragma unroll
    for (int off = 8; off < 64; off <<= 1) mx = fmaxf(mx, __shfl_xor(mx, off, 64));
    float x[4], sum = 0.f;
#pragma unroll
    for (int k = 0; k < 4; ++k) {
      x[k] = (k * 8 + eo < deg) ? expf(s[k] - mx) : 0.f;
      sum += x[k];
    }
#pragma unroll
    for (int off = 8; off < 64; off <<= 1) sum += __shfl_xor(sum, off, 64);
    float inv = 1.f / sum;
    if (fo == 0) {
#pragma unroll
      for (int k = 0; k < 4; ++k) {
        int e = k * 8 + eo;
        if (e < deg) e_soft[edata[beg + e].y] = x[k] * inv;
      }
    }
  } else if (deg <= MAXD) {
    for (int i0 = 0; i0 < deg; i0 += 8) {
      int e = i0 + eo;
      if (e < deg) {
        int sidx = edata[beg + e].x;
        union { uint4 u; half2_t h[4]; } ac;
        ac.u = *reinterpret_cast<const uint4*>(a16u + (unsigned)sidx * 32u + fo * 4);
        float d = 0.f;
        d = __builtin_amdgcn_fdot2(ac.h[0], tc.h[0], d, false);
        d = __builtin_amdgcn_fdot2(ac.h[1], tc.h[1], d, false);
        d = __builtin_amdgcn_fdot2(ac.h[2], tc.h[2], d, false);
        d = __builtin_amdgcn_fdot2(ac.h[3], tc.h[3], d, false);
#pragma unroll
        for (int off = 1; off < 8; off <<= 1) d += __shfl_xor(d, off, 64);
        if (fo == 0) {
          d = d > 0.f ? d : NEG_SLOPE * d;
          ebuf[lw][e] = d;
        }
      }
    }
    float mx = -INFINITY;
    for (int i = lane; i < deg; i += 64) mx = fmaxf(mx, ebuf[lw][i]);
#pragma unroll
    for (int off = 32; off > 0; off >>= 1) mx = fmaxf(mx, __shfl_xor(mx, off, 64));
    float sum = 0.f;
    for (int i = lane; i < deg; i += 64) {
      float ex = expf(ebuf[lw][i] - mx);
      ebuf[lw][i] = ex;
      sum += ex;
    }
#pragma unroll
    for (int off = 32; off > 0; off >>= 1) sum += __shfl_xor(sum, off, 64);
    float inv = 1.f / sum;
    for (int i = lane; i < deg; i += 64) e_soft[edata[beg + i].y] = ebuf[lw][i] * inv;
  } else {
    // recompute fallback (statistically never hit with Poisson(16) degrees)
    float mx = -INFINITY;
    for (int i0 = 0; i0 < deg; i0 += 8) {
      int e = i0 + eo;
      int idx = beg + (e < deg ? e : deg - 1);
      int sidx = edata[idx].x;
      union { uint4 u; half2_t h[4]; } ac;
      ac.u = *reinterpret_cast<const uint4*>(a16u + (unsigned)sidx * 32u + fo * 4);
      float d = 0.f;
      d = __builtin_amdgcn_fdot2(ac.h[0], tc.h[0], d, false);
      d = __builtin_amdgcn_fdot2(ac.h[1], tc.h[1], d, false);
      d = __builtin_amdgcn_fdot2(ac.h[2], tc.h[2], d, false);
      d = __builtin_amdgcn_fdot2(ac.h[3], tc.h[3], d, false);
#pragma unroll
      for (int off = 1; off < 8; off <<= 1) d += __shfl_xor(d, off, 64);
      d = d > 0.f ? d : NEG_SLOPE * d;
      if (e >= deg) d = -INFINITY;
#pragma unroll
      for (int off = 8; off < 64; off <<= 1) d = fmaxf(d, __shfl_xor(d, off, 64));
      mx = fmaxf(mx, d);
    }
    float sum = 0.f;
    for (int i0 = 0; i0 < deg; i0 += 8) {
      int e = i0 + eo;
      int idx = beg + (e < deg ? e : deg - 1);
      int sidx = edata[idx].x;
      union { uint4 u; half2_t h[4]; } ac;
      ac.u = *reinterpret_cast<const uint4*>(a16u + (unsigned)sidx * 32u + fo * 4);
      float d = 0.f;
      d = __builtin_amdgcn_fdot2(ac.h[0], tc.h[0], d, false);
      d = __builtin_amdgcn_fdot2(ac.h[1], tc.h[1], d, false);
      d = __builtin_amdgcn_fdot2(ac.h[2], tc.h[2], d, false);
      d = __builtin_amdgcn_fdot2(ac.h[3], tc.h[3], d, false);
#pragma unroll
      for (int off = 1; off < 8; off <<= 1) d += __shfl_xor(d, off, 64);
      d = d > 0.f ? d : NEG_SLOPE * d;
      float ex = (e < deg) ? expf(d - mx) : 0.f;
#pragma unroll
      for (int off = 8; off < 64; off <<= 1) ex += __shfl_xor(ex, off, 64);
      sum += ex;
    }
    float inv = 1.f / sum;
    for (int i0 = 0; i0 < deg; i0 += 8) {
      int e = i0 + eo;
      int idx = beg + (e < deg ? e : deg - 1);
      int sidx = edata[idx].x;
      union { uint4 u; half2_t h[4]; } ac;
      ac.u = *reinterpret_cast<const uint4*>(a16u + (unsigned)sidx * 32u + fo * 4);
      float d = 0.f;
      d = __builtin_amdgcn_fdot2(ac.h[0], tc.h[0], d, false);
      d = __builtin_amdgcn_fdot2(ac.h[1], tc.h[1], d, false);
      d = __builtin_amdgcn_fdot2(ac.h[2], tc.h[2], d, false);
      d = __builtin_amdgcn_fdot2(ac.h[3], tc.h[3], d, false);
#pragma unroll
      for (int off = 1; off < 8; off <<= 1) d += __shfl_xor(d, off, 64);
      d = d > 0.f ? d : NEG_SLOPE * d;
      if (fo == 0 && e < deg) e_soft[edata[idx].y] = expf(d - mx) * inv;
    }
  }
}

extern "C" void kernel_launch(void* const* d_in, const int* in_sizes, int n_in,
                              void* d_out, int out_size, void* d_ws, size_t ws_size,
                              hipStream_t stream) {
  const float* feat = (const float*)d_in[0];
  const float* W    = (const float*)d_in[1];
  const int*   src  = (const int*)d_in[2];
  const int*   dst  = (const int*)d_in[3];
  const int n_nodes = in_sizes[0] / IN_FEATS;
  const int n_edges = in_sizes[2];
  const int nbuck   = (n_nodes + BNODES - 1) >> BSH;   // <= 512

  // Output layout: [h_agg (N*64) | e_soft (E)]
  float* h_agg  = (float*)d_out;
  float* e_soft = (float*)d_out + (size_t)n_nodes * OUT_FEATS;

  // Workspace:
  // [h16 (N*64 bf16) | a16 (N*64 f16) | bcount(513) | bbase(513)
  //  | bcursor(512) | row_ptr(N+1 pad) | tmpe (E int2) | edata (E int2)]
  // t16 aliases tmpe (dead after binB; agg runs after binB and must NOT
  // alias h16, which it reads).
  unsigned short* h16 = (unsigned short*)d_ws;
  unsigned short* a16 = h16 + (size_t)n_nodes * OUT_FEATS;
  int* bcount   = (int*)(a16 + (size_t)n_nodes * OUT_FEATS);
  int* bbase    = bcount + 513;
  int* bcursor  = bbase + 513;
  int* row_ptr  = bcursor + 512;
  size_t rp_pad = ((size_t)n_nodes + 2) & ~(size_t)1;
  int2* tmpe    = (int2*)(row_ptr + rp_pad);
  int2* edata   = tmpe + n_edges;
  unsigned* t16 = (unsigned*)tmpe;          // N*32 uints <= E*2 ints: fits

  const int eb2 = (n_edges + CHUNK - 1) / CHUNK;
  const int wb  = (n_nodes * 64 + 255) / 256;   // wave-per-node grid (softmax)
  const int ab  = (n_nodes * 8 + 255) / 256;    // 8-lane-per-node grid (agg)

  hipMemsetAsync(bcount, 0, (size_t)nbuck * sizeof(int), stream);

  gemm_h_kernel<<<(n_nodes + 63) / 64, 256, 0, stream>>>(feat, W, h16, n_nodes);

  bhist_kernel<<<eb2, 256, 0, stream>>>(dst, bcount, n_edges, nbuck);
  bscan_kernel<<<1, 512, 0, stream>>>(bcount, bbase, bcursor, nbuck, n_edges);
  bscatter_kernel<<<eb2, 256, 0, stream>>>(src, dst, bcursor, tmpe, n_edges, nbuck);
  binB_kernel<<<nbuck, 256, 0, stream>>>(tmpe, bbase, edata, row_ptr, n_nodes, n_edges);

  agg_kernel<<<ab, 256, 0, stream>>>((const unsigned*)h16, row_ptr, edata,
                                     h_agg, (unsigned*)a16, t16, n_nodes);

  softmax_kernel<<<wb, 256, 0, stream>>>((const unsigned*)a16, (const unsigned*)t16,
                                         row_ptr, edata, e_soft, n_nodes);
}

// Round 16
// 180.266 us; speedup vs baseline: 1.2790x; 1.1670x over previous
//
#include <hip/hip_runtime.h>
#include <math.h>

#define IN_FEATS 128
#define OUT_FEATS 64
#define NEG_SLOPE 0.2f
#define MAXD 256
#define BSH 8                      // bucket = dst >> 8 (256 nodes/bucket)
#define BNODES (1 << BSH)
#define CHUNK 4096                 // edges per block in bucket passes
#define EPT 16                     // edges per thread (CHUNK/256)
#define EID_BITS 21                // n_edges < 2^21
#define LDP 132                    // padded LDS row stride (floats)

typedef _Float16 half2_t __attribute__((ext_vector_type(2)));
typedef short bf16x8 __attribute__((ext_vector_type(8)));   // 8 bf16 = 4 VGPRs
typedef float f32x4 __attribute__((ext_vector_type(4)));    // MFMA acc

// bf16 helpers (h16 stays bf16 for agg's accumulation path)
__device__ __forceinline__ float bf_lo(unsigned u) { return __uint_as_float(u << 16); }
__device__ __forceinline__ float bf_hi(unsigned u) { return __uint_as_float(u & 0xffff0000u); }
__device__ __forceinline__ unsigned short f2bf(float f) {
  unsigned x = __float_as_uint(f);
  x += 0x7fff + ((x >> 16) & 1);          // round to nearest even
  return (unsigned short)(x >> 16);
}
// bit-cast any 4-byte vector (cvt_pkrtz returns __fp16x2, fdot2 takes _Float16x2)
template <typename T>
__device__ __forceinline__ unsigned h2u(T h) {
  union { T h; unsigned u; } c; c.h = h; return c.u;
}

// ---------------------------------------------------------------------------
// K1: h16 = bf16(feat @ W^T) via MFMA 16x16x32 bf16.
// Wave = 16-node tile (grid-stride). W converted f32->bf16 once per wave into
// 16 B-fragments (64 VGPRs, L1-hot loads); feat rows loaded f32 (the 51 MB
// floor) and packed to A-frags in-register. 16 MFMA per tile. No LDS.
// Layouts (m89-verified C/D; standard A/B): A: row=l&15, k=(l>>4)*8+j;
// B: col=l&15, k=(l>>4)*8+j; D: col=l&15, row=(l>>4)*4+reg.
// ---------------------------------------------------------------------------
__global__ __launch_bounds__(256)
void gemm_h_kernel(const float* __restrict__ feat,
                   const float* __restrict__ W,
                   unsigned short* __restrict__ h16, int n_nodes) {
  const int wid    = (blockIdx.x * blockDim.x + threadIdx.x) >> 6;
  const int lane   = threadIdx.x & 63;
  const int nwaves = (gridDim.x * blockDim.x) >> 6;
  const int r16 = lane & 15;          // row (A) / col (B,D)
  const int kb  = lane >> 4;          // k-block 0..3

  // B fragments: wf[ot][kc] covers outs ot*16..+15, k kc*32..+31
  bf16x8 wf[4][4];
#pragma unroll
  for (int ot = 0; ot < 4; ++ot) {
#pragma unroll
    for (int kc = 0; kc < 4; ++kc) {
      const float* wp = W + (size_t)(ot * 16 + r16) * IN_FEATS + kc * 32 + kb * 8;
      float4 w0 = *reinterpret_cast<const float4*>(wp);
      float4 w1 = *reinterpret_cast<const float4*>(wp + 4);
      bf16x8 f;
      f[0] = (short)f2bf(w0.x); f[1] = (short)f2bf(w0.y);
      f[2] = (short)f2bf(w0.z); f[3] = (short)f2bf(w0.w);
      f[4] = (short)f2bf(w1.x); f[5] = (short)f2bf(w1.y);
      f[6] = (short)f2bf(w1.z); f[7] = (short)f2bf(w1.w);
      wf[ot][kc] = f;
    }
  }

  const int ntiles = (n_nodes + 15) >> 4;
  for (int t = wid; t < ntiles; t += nwaves) {
    const int n0 = t * 16;
    int row = n0 + r16;
    if (row >= n_nodes) row = n_nodes - 1;   // clamp loads; stores guarded
    const float* fp = feat + (size_t)row * IN_FEATS + kb * 8;

    bf16x8 af[4];
#pragma unroll
    for (int kc = 0; kc < 4; ++kc) {
      float4 a0 = *reinterpret_cast<const float4*>(fp + kc * 32);
      float4 a1 = *reinterpret_cast<const float4*>(fp + kc * 32 + 4);
      bf16x8 f;
      f[0] = (short)f2bf(a0.x); f[1] = (short)f2bf(a0.y);
      f[2] = (short)f2bf(a0.z); f[3] = (short)f2bf(a0.w);
      f[4] = (short)f2bf(a1.x); f[5] = (short)f2bf(a1.y);
      f[6] = (short)f2bf(a1.z); f[7] = (short)f2bf(a1.w);
      af[kc] = f;
    }

    f32x4 acc[4];
#pragma unroll
    for (int ot = 0; ot < 4; ++ot) acc[ot] = (f32x4){0.f, 0.f, 0.f, 0.f};
#pragma unroll
    for (int ot = 0; ot < 4; ++ot) {
#pragma unroll
      for (int kc = 0; kc < 4; ++kc) {
        acc[ot] = __builtin_amdgcn_mfma_f32_16x16x32_bf16(af[kc], wf[ot][kc],
                                                          acc[ot], 0, 0, 0);
      }
    }

#pragma unroll
    for (int ot = 0; ot < 4; ++ot) {
#pragma unroll
      for (int reg = 0; reg < 4; ++reg) {
        int node = n0 + (lane >> 4) * 4 + reg;
        if (node < n_nodes)
          h16[(size_t)node * OUT_FEATS + ot * 16 + r16] = f2bf(acc[ot][reg]);
      }
    }
  }
}

// ---------------------------------------------------------------------------
// Bucket sort pass A1: per-bucket edge counts
// ---------------------------------------------------------------------------
__global__ __launch_bounds__(256)
void bhist_kernel(const int* __restrict__ dst, int* __restrict__ bcount,
                  int n_edges, int nbuck) {
  __shared__ int hist[512];
  const int t = threadIdx.x;
  for (int i = t; i < nbuck; i += 256) hist[i] = 0;
  __syncthreads();
  const int base = blockIdx.x * CHUNK;
#pragma unroll
  for (int i = 0; i < EPT; ++i) {
    int e = base + t + i * 256;
    if (e < n_edges) atomicAdd(&hist[dst[e] >> BSH], 1);
  }
  __syncthreads();
  for (int i = t; i < nbuck; i += 256)
    if (hist[i]) atomicAdd(&bcount[i], hist[i]);
}

// ---------------------------------------------------------------------------
// A2: exclusive scan of bucket counts
// ---------------------------------------------------------------------------
__global__ void bscan_kernel(const int* __restrict__ bcount, int* __restrict__ bbase,
                             int* __restrict__ bcursor, int nbuck, int n_edges) {
  __shared__ int tmp[512];
  const int t = threadIdx.x;
  int v = (t < nbuck) ? bcount[t] : 0;
  tmp[t] = v;
  __syncthreads();
  for (int off = 1; off < 512; off <<= 1) {
    int x = (t >= off) ? tmp[t - off] : 0;
    __syncthreads();
    tmp[t] += x;
    __syncthreads();
  }
  if (t < nbuck) { int excl = tmp[t] - v; bbase[t] = excl; bcursor[t] = excl; }
  if (t == 0) bbase[nbuck] = n_edges;
}

// ---------------------------------------------------------------------------
// A3: scatter edges into bucket regions
// ---------------------------------------------------------------------------
__global__ __launch_bounds__(256)
void bscatter_kernel(const int* __restrict__ src, const int* __restrict__ dst,
                     int* __restrict__ bcursor, int2* __restrict__ tmpe,
                     int n_edges, int nbuck) {
  __shared__ int hist[512];
  __shared__ int basech[512];
  __shared__ int offs[512];
  const int t = threadIdx.x;
  const int base = blockIdx.x * CHUNK;
  for (int i = t; i < nbuck; i += 256) { hist[i] = 0; offs[i] = 0; }
  __syncthreads();
  int s16a[EPT], d16a[EPT];
#pragma unroll
  for (int i = 0; i < EPT; ++i) {
    int e = base + t + i * 256;
    if (e < n_edges) {
      s16a[i] = src[e];
      d16a[i] = dst[e];
      atomicAdd(&hist[d16a[i] >> BSH], 1);
    } else {
      d16a[i] = -1;
    }
  }
  __syncthreads();
  for (int i = t; i < nbuck; i += 256)
    if (hist[i]) basech[i] = atomicAdd(&bcursor[i], hist[i]);
  __syncthreads();
#pragma unroll
  for (int i = 0; i < EPT; ++i) {
    if (d16a[i] >= 0) {
      int e = base + t + i * 256;
      int b = d16a[i] >> BSH;
      int off = atomicAdd(&offs[b], 1);
      int2 v;
      v.x = s16a[i];
      v.y = ((d16a[i] & (BNODES - 1)) << EID_BITS) | e;
      tmpe[basech[b] + off] = v;
    }
  }
}

// ---------------------------------------------------------------------------
// B: one workgroup per bucket -> row_ptr + final CSR edata (src,eid).
// ---------------------------------------------------------------------------
__global__ __launch_bounds__(256)
void binB_kernel(const int2* __restrict__ tmpe, const int* __restrict__ bbase,
                 int2* __restrict__ edata, int* __restrict__ row_ptr,
                 int n_nodes, int n_edges) {
  __shared__ int cnt[BNODES];
  __shared__ int cur[BNODES];
  const int b = blockIdx.x;
  const int t = threadIdx.x;
  const int beg = bbase[b], end = bbase[b + 1];

  cnt[t] = 0;
  __syncthreads();
  for (int i = beg + t; i < end; i += 256)
    atomicAdd(&cnt[(tmpe[i].y >> EID_BITS) & (BNODES - 1)], 1);
  __syncthreads();

  int v = cnt[t];
  cur[t] = v;
  __syncthreads();
  for (int off = 1; off < BNODES; off <<= 1) {
    int x = (t >= off) ? cur[t - off] : 0;
    __syncthreads();
    cur[t] += x;
    __syncthreads();
  }
  int excl = cur[t] - v;
  int node = b * BNODES + t;
  if (node < n_nodes) row_ptr[node] = beg + excl;
  if (b == 0 && t == 0) row_ptr[n_nodes] = n_edges;
  __syncthreads();
  cur[t] = beg + excl;
  __syncthreads();

  for (int i = beg + t; i < end; i += 256) {
    int2 p = tmpe[i];
    int l = (p.y >> EID_BITS) & (BNODES - 1);
    int pos = atomicAdd(&cur[l], 1);
    int2 o;
    o.x = p.x;
    o.y = p.y & ((1 << EID_BITS) - 1);
    edata[pos] = o;
  }
}

// ---------------------------------------------------------------------------
// agg: 8 nodes per wave, 8 lanes per node. Software-pipelined: gather i+1
// issued before accumulating i -> 2 loads in flight per lane.
// Epilogue emits a16/t16 (f16) with full lane utilization.
// ---------------------------------------------------------------------------
__global__ void agg_kernel(const unsigned* __restrict__ h16u,  // rows of 32 uints
                           const int* __restrict__ row_ptr,
                           const int2* __restrict__ edata, float* __restrict__ h_agg,
                           unsigned* __restrict__ a16u, unsigned* __restrict__ t16u,
                           int n_nodes) {
  int tid  = blockIdx.x * blockDim.x + threadIdx.x;
  int node = tid >> 3;
  int fo   = tid & 7;
  if (node >= n_nodes) return;
  int beg = row_ptr[node], end = row_ptr[node + 1];
  float acc[8] = {0.f, 0.f, 0.f, 0.f, 0.f, 0.f, 0.f, 0.f};
  if (beg < end) {
    uint4 v = *reinterpret_cast<const uint4*>(
        h16u + (unsigned)edata[beg].x * 32u + fo * 4);
    for (int i = beg + 1; i < end; ++i) {
      uint4 vn = *reinterpret_cast<const uint4*>(
          h16u + (unsigned)edata[i].x * 32u + fo * 4);   // next gather in flight
      acc[0] += bf_lo(v.x); acc[1] += bf_hi(v.x);
      acc[2] += bf_lo(v.y); acc[3] += bf_hi(v.y);
      acc[4] += bf_lo(v.z); acc[5] += bf_hi(v.z);
      acc[6] += bf_lo(v.w); acc[7] += bf_hi(v.w);
      v = vn;
    }
    acc[0] += bf_lo(v.x); acc[1] += bf_hi(v.x);
    acc[2] += bf_lo(v.y); acc[3] += bf_hi(v.y);
    acc[4] += bf_lo(v.z); acc[5] += bf_hi(v.z);
    acc[6] += bf_lo(v.w); acc[7] += bf_hi(v.w);
  }
  float4 a, b;
  a.x = acc[0]; a.y = acc[1]; a.z = acc[2]; a.w = acc[3];
  b.x = acc[4]; b.y = acc[5]; b.z = acc[6]; b.w = acc[7];
  float* out = h_agg + (size_t)node * OUT_FEATS + fo * 8;
  *reinterpret_cast<float4*>(out) = a;
  *reinterpret_cast<float4*>(out + 4) = b;

  uint4 pa;
  pa.x = h2u(__builtin_amdgcn_cvt_pkrtz(acc[0], acc[1]));
  pa.y = h2u(__builtin_amdgcn_cvt_pkrtz(acc[2], acc[3]));
  pa.z = h2u(__builtin_amdgcn_cvt_pkrtz(acc[4], acc[5]));
  pa.w = h2u(__builtin_amdgcn_cvt_pkrtz(acc[6], acc[7]));
  *reinterpret_cast<uint4*>(a16u + (unsigned)node * 32u + fo * 4) = pa;

  uint4 pt;
  pt.x = h2u(__builtin_amdgcn_cvt_pkrtz(tanhf(acc[0]), tanhf(acc[1])));
  pt.y = h2u(__builtin_amdgcn_cvt_pkrtz(tanhf(acc[2]), tanhf(acc[3])));
  pt.z = h2u(__builtin_amdgcn_cvt_pkrtz(tanhf(acc[4]), tanhf(acc[5])));
  pt.w = h2u(__builtin_amdgcn_cvt_pkrtz(tanhf(acc[6]), tanhf(acc[7])));
  *reinterpret_cast<uint4*>(t16u + (unsigned)node * 32u + fo * 4) = pt;
}

// ---------------------------------------------------------------------------
// fused per-node edge softmax over f16 rows (R14-proven loop structure).
// ---------------------------------------------------------------------------
__global__ __launch_bounds__(256)
void softmax_kernel(const unsigned* __restrict__ a16u, const unsigned* __restrict__ t16u,
                    const int* __restrict__ row_ptr, const int2* __restrict__ edata,
                    float* __restrict__ e_soft, int n_nodes) {
  __shared__ float ebuf[4][MAXD];
  int wid  = (blockIdx.x * blockDim.x + threadIdx.x) >> 6;
  int lane = threadIdx.x & 63;
  int lw   = threadIdx.x >> 6;
  int eo = lane >> 3;
  int fo = lane & 7;
  if (wid >= n_nodes) return;
  int beg = row_ptr[wid], end = row_ptr[wid + 1];
  int deg = end - beg;
  if (deg == 0) return;

  union { uint4 u; half2_t h[4]; } tc;
  tc.u = *reinterpret_cast<const uint4*>(t16u + (unsigned)wid * 32u + fo * 4);

  if (deg <= MAXD) {
    for (int i0 = 0; i0 < deg; i0 += 8) {
      int e = i0 + eo;
      if (e < deg) {                         // group-uniform guard: no dup gathers
        int s = edata[beg + e].x;
        union { uint4 u; half2_t h[4]; } ac;
        ac.u = *reinterpret_cast<const uint4*>(a16u + (unsigned)s * 32u + fo * 4);
        float d = 0.f;
        d = __builtin_amdgcn_fdot2(ac.h[0], tc.h[0], d, false);
        d = __builtin_amdgcn_fdot2(ac.h[1], tc.h[1], d, false);
        d = __builtin_amdgcn_fdot2(ac.h[2], tc.h[2], d, false);
        d = __builtin_amdgcn_fdot2(ac.h[3], tc.h[3], d, false);
#pragma unroll
        for (int off = 1; off < 8; off <<= 1) d += __shfl_xor(d, off, 64);
        if (fo == 0) {
          d = d > 0.f ? d : NEG_SLOPE * d;
          ebuf[lw][e] = d;
        }
      }
    }
    if (deg <= 64) {
      // register tail: lane i owns score i
      float sc = (lane < deg) ? ebuf[lw][lane] : -INFINITY;
      float mx = sc;
#pragma unroll
      for (int off = 32; off > 0; off >>= 1) mx = fmaxf(mx, __shfl_xor(mx, off, 64));
      float ex = (lane < deg) ? expf(sc - mx) : 0.f;
      float sum = ex;
#pragma unroll
      for (int off = 32; off > 0; off >>= 1) sum += __shfl_xor(sum, off, 64);
      float inv = 1.f / sum;
      if (lane < deg) e_soft[edata[beg + lane].y] = ex * inv;
    } else {
      float mx = -INFINITY;
      for (int i = lane; i < deg; i += 64) mx = fmaxf(mx, ebuf[lw][i]);
#pragma unroll
      for (int off = 32; off > 0; off >>= 1) mx = fmaxf(mx, __shfl_xor(mx, off, 64));
      float sum = 0.f;
      for (int i = lane; i < deg; i += 64) {
        float ex = expf(ebuf[lw][i] - mx);
        ebuf[lw][i] = ex;
        sum += ex;
      }
#pragma unroll
      for (int off = 32; off > 0; off >>= 1) sum += __shfl_xor(sum, off, 64);
      float inv = 1.f / sum;
      for (int i = lane; i < deg; i += 64) e_soft[edata[beg + i].y] = ebuf[lw][i] * inv;
    }
  } else {
    // recompute fallback (statistically never hit with Poisson(16) degrees)
    float mx = -INFINITY;
    for (int i0 = 0; i0 < deg; i0 += 8) {
      int e = i0 + eo;
      int idx = beg + (e < deg ? e : deg - 1);
      int s = edata[idx].x;
      union { uint4 u; half2_t h[4]; } ac;
      ac.u = *reinterpret_cast<const uint4*>(a16u + (unsigned)s * 32u + fo * 4);
      float d = 0.f;
      d = __builtin_amdgcn_fdot2(ac.h[0], tc.h[0], d, false);
      d = __builtin_amdgcn_fdot2(ac.h[1], tc.h[1], d, false);
      d = __builtin_amdgcn_fdot2(ac.h[2], tc.h[2], d, false);
      d = __builtin_amdgcn_fdot2(ac.h[3], tc.h[3], d, false);
#pragma unroll
      for (int off = 1; off < 8; off <<= 1) d += __shfl_xor(d, off, 64);
      d = d > 0.f ? d : NEG_SLOPE * d;
      if (e >= deg) d = -INFINITY;
#pragma unroll
      for (int off = 8; off < 64; off <<= 1) d = fmaxf(d, __shfl_xor(d, off, 64));
      mx = fmaxf(mx, d);
    }
    float sum = 0.f;
    for (int i0 = 0; i0 < deg; i0 += 8) {
      int e = i0 + eo;
      int idx = beg + (e < deg ? e : deg - 1);
      int s = edata[idx].x;
      union { uint4 u; half2_t h[4]; } ac;
      ac.u = *reinterpret_cast<const uint4*>(a16u + (unsigned)s * 32u + fo * 4);
      float d = 0.f;
      d = __builtin_amdgcn_fdot2(ac.h[0], tc.h[0], d, false);
      d = __builtin_amdgcn_fdot2(ac.h[1], tc.h[1], d, false);
      d = __builtin_amdgcn_fdot2(ac.h[2], tc.h[2], d, false);
      d = __builtin_amdgcn_fdot2(ac.h[3], tc.h[3], d, false);
#pragma unroll
      for (int off = 1; off < 8; off <<= 1) d += __shfl_xor(d, off, 64);
      d = d > 0.f ? d : NEG_SLOPE * d;
      float ex = (e < deg) ? expf(d - mx) : 0.f;
#pragma unroll
      for (int off = 8; off < 64; off <<= 1) ex += __shfl_xor(ex, off, 64);
      sum += ex;
    }
    float inv = 1.f / sum;
    for (int i0 = 0; i0 < deg; i0 += 8) {
      int e = i0 + eo;
      int idx = beg + (e < deg ? e : deg - 1);
      int s = edata[idx].x;
      union { uint4 u; half2_t h[4]; } ac;
      ac.u = *reinterpret_cast<const uint4*>(a16u + (unsigned)s * 32u + fo * 4);
      float d = 0.f;
      d = __builtin_amdgcn_fdot2(ac.h[0], tc.h[0], d, false);
      d = __builtin_amdgcn_fdot2(ac.h[1], tc.h[1], d, false);
      d = __builtin_amdgcn_fdot2(ac.h[2], tc.h[2], d, false);
      d = __builtin_amdgcn_fdot2(ac.h[3], tc.h[3], d, false);
#pragma unroll
      for (int off = 1; off < 8; off <<= 1) d += __shfl_xor(d, off, 64);
      d = d > 0.f ? d : NEG_SLOPE * d;
      if (fo == 0 && e < deg) e_soft[edata[idx].y] = expf(d - mx) * inv;
    }
  }
}

extern "C" void kernel_launch(void* const* d_in, const int* in_sizes, int n_in,
                              void* d_out, int out_size, void* d_ws, size_t ws_size,
                              hipStream_t stream) {
  const float* feat = (const float*)d_in[0];
  const float* W    = (const float*)d_in[1];
  const int*   src  = (const int*)d_in[2];
  const int*   dst  = (const int*)d_in[3];
  const int n_nodes = in_sizes[0] / IN_FEATS;
  const int n_edges = in_sizes[2];
  const int nbuck   = (n_nodes + BNODES - 1) >> BSH;   // <= 512

  // Output layout: [h_agg (N*64) | e_soft (E)]
  float* h_agg  = (float*)d_out;
  float* e_soft = (float*)d_out + (size_t)n_nodes * OUT_FEATS;

  // Workspace:
  // [h16 (N*64 bf16) | a16 (N*64 f16) | bcount(513) | bbase(513)
  //  | bcursor(512) | row_ptr(N+1 pad) | tmpe (E int2) | edata (E int2)]
  // t16 aliases tmpe (dead after binB; agg runs after binB and must NOT
  // alias h16, which it reads).
  unsigned short* h16 = (unsigned short*)d_ws;
  unsigned short* a16 = h16 + (size_t)n_nodes * OUT_FEATS;
  int* bcount   = (int*)(a16 + (size_t)n_nodes * OUT_FEATS);
  int* bbase    = bcount + 513;
  int* bcursor  = bbase + 513;
  int* row_ptr  = bcursor + 512;
  size_t rp_pad = ((size_t)n_nodes + 2) & ~(size_t)1;
  int2* tmpe    = (int2*)(row_ptr + rp_pad);
  int2* edata   = tmpe + n_edges;
  unsigned* t16 = (unsigned*)tmpe;          // N*32 uints <= E*2 ints: fits

  const int eb2 = (n_edges + CHUNK - 1) / CHUNK;
  const int wb  = (n_nodes * 64 + 255) / 256;   // wave-per-node grid (softmax)
  const int ab  = (n_nodes * 8 + 255) / 256;    // 8-lane-per-node grid (agg)

  hipMemsetAsync(bcount, 0, (size_t)nbuck * sizeof(int), stream);

  // MFMA gemm: 512 blocks x 4 waves, grid-stride over 16-node tiles
  gemm_h_kernel<<<512, 256, 0, stream>>>(feat, W, h16, n_nodes);

  bhist_kernel<<<eb2, 256, 0, stream>>>(dst, bcount, n_edges, nbuck);
  bscan_kernel<<<1, 512, 0, stream>>>(bcount, bbase, bcursor, nbuck, n_edges);
  bscatter_kernel<<<eb2, 256, 0, stream>>>(src, dst, bcursor, tmpe, n_edges, nbuck);
  binB_kernel<<<nbuck, 256, 0, stream>>>(tmpe, bbase, edata, row_ptr, n_nodes, n_edges);

  agg_kernel<<<ab, 256, 0, stream>>>((const unsigned*)h16, row_ptr, edata,
                                     h_agg, (unsigned*)a16, t16, n_nodes);

  softmax_kernel<<<wb, 256, 0, stream>>>((const unsigned*)a16, (const unsigned*)t16,
                                         row_ptr, edata, e_soft, n_nodes);
}

// Round 17
// 173.336 us; speedup vs baseline: 1.3301x; 1.0400x over previous
//
#include <hip/hip_runtime.h>
#include <math.h>

#define IN_FEATS 128
#define OUT_FEATS 64
#define NEG_SLOPE 0.2f
#define MAXD 256
#define BSH 8                      // bucket = dst >> 8 (256 nodes/bucket)
#define BNODES (1 << BSH)
#define CHUNK 4096                 // edges per block in bucket passes
#define EPT 16                     // edges per thread (CHUNK/256)
#define EID_BITS 21                // n_edges < 2^21
#define LDP 132                    // padded LDS row stride (floats)

typedef _Float16 half2_t __attribute__((ext_vector_type(2)));
typedef short bf16x8 __attribute__((ext_vector_type(8)));   // 8 bf16 = 4 VGPRs
typedef float f32x4 __attribute__((ext_vector_type(4)));    // MFMA acc

// bf16 helpers (h16 stays bf16 for agg's accumulation path)
__device__ __forceinline__ float bf_lo(unsigned u) { return __uint_as_float(u << 16); }
__device__ __forceinline__ float bf_hi(unsigned u) { return __uint_as_float(u & 0xffff0000u); }
__device__ __forceinline__ unsigned short f2bf(float f) {
  unsigned x = __float_as_uint(f);
  x += 0x7fff + ((x >> 16) & 1);          // round to nearest even
  return (unsigned short)(x >> 16);
}
// bit-cast any 4-byte vector (cvt_pkrtz returns __fp16x2, fdot2 takes _Float16x2)
template <typename T>
__device__ __forceinline__ unsigned h2u(T h) {
  union { T h; unsigned u; } c; c.h = h; return c.u;
}

// ---------------------------------------------------------------------------
// K1: h16 = bf16(feat @ W^T) via MFMA 16x16x32 bf16 (R16-proven).
// ---------------------------------------------------------------------------
__global__ __launch_bounds__(256)
void gemm_h_kernel(const float* __restrict__ feat,
                   const float* __restrict__ W,
                   unsigned short* __restrict__ h16, int n_nodes) {
  const int wid    = (blockIdx.x * blockDim.x + threadIdx.x) >> 6;
  const int lane   = threadIdx.x & 63;
  const int nwaves = (gridDim.x * blockDim.x) >> 6;
  const int r16 = lane & 15;          // row (A) / col (B,D)
  const int kb  = lane >> 4;          // k-block 0..3

  bf16x8 wf[4][4];
#pragma unroll
  for (int ot = 0; ot < 4; ++ot) {
#pragma unroll
    for (int kc = 0; kc < 4; ++kc) {
      const float* wp = W + (size_t)(ot * 16 + r16) * IN_FEATS + kc * 32 + kb * 8;
      float4 w0 = *reinterpret_cast<const float4*>(wp);
      float4 w1 = *reinterpret_cast<const float4*>(wp + 4);
      bf16x8 f;
      f[0] = (short)f2bf(w0.x); f[1] = (short)f2bf(w0.y);
      f[2] = (short)f2bf(w0.z); f[3] = (short)f2bf(w0.w);
      f[4] = (short)f2bf(w1.x); f[5] = (short)f2bf(w1.y);
      f[6] = (short)f2bf(w1.z); f[7] = (short)f2bf(w1.w);
      wf[ot][kc] = f;
    }
  }

  const int ntiles = (n_nodes + 15) >> 4;
  for (int t = wid; t < ntiles; t += nwaves) {
    const int n0 = t * 16;
    int row = n0 + r16;
    if (row >= n_nodes) row = n_nodes - 1;   // clamp loads; stores guarded
    const float* fp = feat + (size_t)row * IN_FEATS + kb * 8;

    bf16x8 af[4];
#pragma unroll
    for (int kc = 0; kc < 4; ++kc) {
      float4 a0 = *reinterpret_cast<const float4*>(fp + kc * 32);
      float4 a1 = *reinterpret_cast<const float4*>(fp + kc * 32 + 4);
      bf16x8 f;
      f[0] = (short)f2bf(a0.x); f[1] = (short)f2bf(a0.y);
      f[2] = (short)f2bf(a0.z); f[3] = (short)f2bf(a0.w);
      f[4] = (short)f2bf(a1.x); f[5] = (short)f2bf(a1.y);
      f[6] = (short)f2bf(a1.z); f[7] = (short)f2bf(a1.w);
      af[kc] = f;
    }

    f32x4 acc[4];
#pragma unroll
    for (int ot = 0; ot < 4; ++ot) acc[ot] = (f32x4){0.f, 0.f, 0.f, 0.f};
#pragma unroll
    for (int ot = 0; ot < 4; ++ot) {
#pragma unroll
      for (int kc = 0; kc < 4; ++kc) {
        acc[ot] = __builtin_amdgcn_mfma_f32_16x16x32_bf16(af[kc], wf[ot][kc],
                                                          acc[ot], 0, 0, 0);
      }
    }

#pragma unroll
    for (int ot = 0; ot < 4; ++ot) {
#pragma unroll
      for (int reg = 0; reg < 4; ++reg) {
        int node = n0 + (lane >> 4) * 4 + reg;
        if (node < n_nodes)
          h16[(size_t)node * OUT_FEATS + ot * 16 + r16] = f2bf(acc[ot][reg]);
      }
    }
  }
}

// ---------------------------------------------------------------------------
// Bucket sort pass A1: per-bucket edge counts
// ---------------------------------------------------------------------------
__global__ __launch_bounds__(256)
void bhist_kernel(const int* __restrict__ dst, int* __restrict__ bcount,
                  int n_edges, int nbuck) {
  __shared__ int hist[512];
  const int t = threadIdx.x;
  for (int i = t; i < nbuck; i += 256) hist[i] = 0;
  __syncthreads();
  const int base = blockIdx.x * CHUNK;
#pragma unroll
  for (int i = 0; i < EPT; ++i) {
    int e = base + t + i * 256;
    if (e < n_edges) atomicAdd(&hist[dst[e] >> BSH], 1);
  }
  __syncthreads();
  for (int i = t; i < nbuck; i += 256)
    if (hist[i]) atomicAdd(&bcount[i], hist[i]);
}

// ---------------------------------------------------------------------------
// A2: exclusive scan of bucket counts
// ---------------------------------------------------------------------------
__global__ void bscan_kernel(const int* __restrict__ bcount, int* __restrict__ bbase,
                             int* __restrict__ bcursor, int nbuck, int n_edges) {
  __shared__ int tmp[512];
  const int t = threadIdx.x;
  int v = (t < nbuck) ? bcount[t] : 0;
  tmp[t] = v;
  __syncthreads();
  for (int off = 1; off < 512; off <<= 1) {
    int x = (t >= off) ? tmp[t - off] : 0;
    __syncthreads();
    tmp[t] += x;
    __syncthreads();
  }
  if (t < nbuck) { int excl = tmp[t] - v; bbase[t] = excl; bcursor[t] = excl; }
  if (t == 0) bbase[nbuck] = n_edges;
}

// ---------------------------------------------------------------------------
// A3: scatter edges into bucket regions
// ---------------------------------------------------------------------------
__global__ __launch_bounds__(256)
void bscatter_kernel(const int* __restrict__ src, const int* __restrict__ dst,
                     int* __restrict__ bcursor, int2* __restrict__ tmpe,
                     int n_edges, int nbuck) {
  __shared__ int hist[512];
  __shared__ int basech[512];
  __shared__ int offs[512];
  const int t = threadIdx.x;
  const int base = blockIdx.x * CHUNK;
  for (int i = t; i < nbuck; i += 256) { hist[i] = 0; offs[i] = 0; }
  __syncthreads();
  int s16a[EPT], d16a[EPT];
#pragma unroll
  for (int i = 0; i < EPT; ++i) {
    int e = base + t + i * 256;
    if (e < n_edges) {
      s16a[i] = src[e];
      d16a[i] = dst[e];
      atomicAdd(&hist[d16a[i] >> BSH], 1);
    } else {
      d16a[i] = -1;
    }
  }
  __syncthreads();
  for (int i = t; i < nbuck; i += 256)
    if (hist[i]) basech[i] = atomicAdd(&bcursor[i], hist[i]);
  __syncthreads();
#pragma unroll
  for (int i = 0; i < EPT; ++i) {
    if (d16a[i] >= 0) {
      int e = base + t + i * 256;
      int b = d16a[i] >> BSH;
      int off = atomicAdd(&offs[b], 1);
      int2 v;
      v.x = s16a[i];
      v.y = ((d16a[i] & (BNODES - 1)) << EID_BITS) | e;
      tmpe[basech[b] + off] = v;
    }
  }
}

// ---------------------------------------------------------------------------
// B: one workgroup per bucket -> row_ptr + final CSR edata (src,eid).
// ---------------------------------------------------------------------------
__global__ __launch_bounds__(256)
void binB_kernel(const int2* __restrict__ tmpe, const int* __restrict__ bbase,
                 int2* __restrict__ edata, int* __restrict__ row_ptr,
                 int n_nodes, int n_edges) {
  __shared__ int cnt[BNODES];
  __shared__ int cur[BNODES];
  const int b = blockIdx.x;
  const int t = threadIdx.x;
  const int beg = bbase[b], end = bbase[b + 1];

  cnt[t] = 0;
  __syncthreads();
  for (int i = beg + t; i < end; i += 256)
    atomicAdd(&cnt[(tmpe[i].y >> EID_BITS) & (BNODES - 1)], 1);
  __syncthreads();

  int v = cnt[t];
  cur[t] = v;
  __syncthreads();
  for (int off = 1; off < BNODES; off <<= 1) {
    int x = (t >= off) ? cur[t - off] : 0;
    __syncthreads();
    cur[t] += x;
    __syncthreads();
  }
  int excl = cur[t] - v;
  int node = b * BNODES + t;
  if (node < n_nodes) row_ptr[node] = beg + excl;
  if (b == 0 && t == 0) row_ptr[n_nodes] = n_edges;
  __syncthreads();
  cur[t] = beg + excl;
  __syncthreads();

  for (int i = beg + t; i < end; i += 256) {
    int2 p = tmpe[i];
    int l = (p.y >> EID_BITS) & (BNODES - 1);
    int pos = atomicAdd(&cur[l], 1);
    int2 o;
    o.x = p.x;
    o.y = p.y & ((1 << EID_BITS) - 1);
    edata[pos] = o;
  }
}

// ---------------------------------------------------------------------------
// agg: 8 nodes per wave, 8 lanes per node, 2-deep gather pipeline (R15).
// Epilogue emits a16/t16 (f16) with full lane utilization.
// ---------------------------------------------------------------------------
__global__ void agg_kernel(const unsigned* __restrict__ h16u,  // rows of 32 uints
                           const int* __restrict__ row_ptr,
                           const int2* __restrict__ edata, float* __restrict__ h_agg,
                           unsigned* __restrict__ a16u, unsigned* __restrict__ t16u,
                           int n_nodes) {
  int tid  = blockIdx.x * blockDim.x + threadIdx.x;
  int node = tid >> 3;
  int fo   = tid & 7;
  if (node >= n_nodes) return;
  int beg = row_ptr[node], end = row_ptr[node + 1];
  float acc[8] = {0.f, 0.f, 0.f, 0.f, 0.f, 0.f, 0.f, 0.f};
  if (beg < end) {
    uint4 v = *reinterpret_cast<const uint4*>(
        h16u + (unsigned)edata[beg].x * 32u + fo * 4);
    for (int i = beg + 1; i < end; ++i) {
      uint4 vn = *reinterpret_cast<const uint4*>(
          h16u + (unsigned)edata[i].x * 32u + fo * 4);   // next gather in flight
      acc[0] += bf_lo(v.x); acc[1] += bf_hi(v.x);
      acc[2] += bf_lo(v.y); acc[3] += bf_hi(v.y);
      acc[4] += bf_lo(v.z); acc[5] += bf_hi(v.z);
      acc[6] += bf_lo(v.w); acc[7] += bf_hi(v.w);
      v = vn;
    }
    acc[0] += bf_lo(v.x); acc[1] += bf_hi(v.x);
    acc[2] += bf_lo(v.y); acc[3] += bf_hi(v.y);
    acc[4] += bf_lo(v.z); acc[5] += bf_hi(v.z);
    acc[6] += bf_lo(v.w); acc[7] += bf_hi(v.w);
  }
  float4 a, b;
  a.x = acc[0]; a.y = acc[1]; a.z = acc[2]; a.w = acc[3];
  b.x = acc[4]; b.y = acc[5]; b.z = acc[6]; b.w = acc[7];
  float* out = h_agg + (size_t)node * OUT_FEATS + fo * 8;
  *reinterpret_cast<float4*>(out) = a;
  *reinterpret_cast<float4*>(out + 4) = b;

  uint4 pa;
  pa.x = h2u(__builtin_amdgcn_cvt_pkrtz(acc[0], acc[1]));
  pa.y = h2u(__builtin_amdgcn_cvt_pkrtz(acc[2], acc[3]));
  pa.z = h2u(__builtin_amdgcn_cvt_pkrtz(acc[4], acc[5]));
  pa.w = h2u(__builtin_amdgcn_cvt_pkrtz(acc[6], acc[7]));
  *reinterpret_cast<uint4*>(a16u + (unsigned)node * 32u + fo * 4) = pa;

  uint4 pt;
  pt.x = h2u(__builtin_amdgcn_cvt_pkrtz(tanhf(acc[0]), tanhf(acc[1])));
  pt.y = h2u(__builtin_amdgcn_cvt_pkrtz(tanhf(acc[2]), tanhf(acc[3])));
  pt.z = h2u(__builtin_amdgcn_cvt_pkrtz(tanhf(acc[4]), tanhf(acc[5])));
  pt.w = h2u(__builtin_amdgcn_cvt_pkrtz(tanhf(acc[6]), tanhf(acc[7])));
  *reinterpret_cast<uint4*>(t16u + (unsigned)node * 32u + fo * 4) = pt;
}

// ---------------------------------------------------------------------------
// fused per-node edge softmax over f16 rows.
// deg<=32 fast path: fo = lane&3 (32B/lane), eo = lane>>2 (16 edges/batch),
// TWO batches with unconditional CLAMPED loads (no exec guards -> compiler
// hoists all 4 row-gathers + 2 edata loads back-to-back = 3x MLP), zero LDS.
// Dot reduce = 2 shuffles; wave max/sum = 4 shuffles (fo-duplicated values).
// 32<deg<=256: LDS path (16-edge steps). deg>256: recompute fallback.
// ---------------------------------------------------------------------------
__global__ __launch_bounds__(256)
void softmax_kernel(const unsigned* __restrict__ a16u, const unsigned* __restrict__ t16u,
                    const int* __restrict__ row_ptr, const int2* __restrict__ edata,
                    float* __restrict__ e_soft, int n_nodes) {
  __shared__ float ebuf[4][MAXD];
  int wid  = (blockIdx.x * blockDim.x + threadIdx.x) >> 6;
  int lane = threadIdx.x & 63;
  int lw   = threadIdx.x >> 6;
  int eo = lane >> 2;   // 0..15 edge slot
  int fo = lane & 3;    // 0..3  row quarter (32B)
  if (wid >= n_nodes) return;
  int beg = row_ptr[wid], end = row_ptr[wid + 1];
  int deg = end - beg;
  if (deg == 0) return;

  union U { uint4 u; half2_t h[4]; };
  U tc0, tc1;
  tc0.u = *reinterpret_cast<const uint4*>(t16u + (unsigned)wid * 32u + fo * 8);
  tc1.u = *reinterpret_cast<const uint4*>(t16u + (unsigned)wid * 32u + fo * 8 + 4);

  if (deg <= 32) {
    int eA = eo, eB = 16 + eo;
    int idxA = beg + (eA < deg ? eA : deg - 1);
    int idxB = beg + (eB < deg ? eB : deg - 1);
    int2 edA = edata[idxA];
    int2 edB = edata[idxB];
    U a0A, a1A, a0B, a1B;
    a0A.u = *reinterpret_cast<const uint4*>(a16u + (unsigned)edA.x * 32u + fo * 8);
    a1A.u = *reinterpret_cast<const uint4*>(a16u + (unsigned)edA.x * 32u + fo * 8 + 4);
    a0B.u = *reinterpret_cast<const uint4*>(a16u + (unsigned)edB.x * 32u + fo * 8);
    a1B.u = *reinterpret_cast<const uint4*>(a16u + (unsigned)edB.x * 32u + fo * 8 + 4);

    float dA = 0.f, dB = 0.f;
#pragma unroll
    for (int j = 0; j < 4; ++j) {
      dA = __builtin_amdgcn_fdot2(a0A.h[j], tc0.h[j], dA, false);
      dB = __builtin_amdgcn_fdot2(a0B.h[j], tc0.h[j], dB, false);
    }
#pragma unroll
    for (int j = 0; j < 4; ++j) {
      dA = __builtin_amdgcn_fdot2(a1A.h[j], tc1.h[j], dA, false);
      dB = __builtin_amdgcn_fdot2(a1B.h[j], tc1.h[j], dB, false);
    }
#pragma unroll
    for (int off = 1; off < 4; off <<= 1) {
      dA += __shfl_xor(dA, off, 64);
      dB += __shfl_xor(dB, off, 64);
    }
    dA = dA > 0.f ? dA : NEG_SLOPE * dA;
    dB = dB > 0.f ? dB : NEG_SLOPE * dB;
    float mA = (eA < deg) ? dA : -INFINITY;
    float mB = (eB < deg) ? dB : -INFINITY;
    float mx = fmaxf(mA, mB);
#pragma unroll
    for (int off = 4; off < 64; off <<= 1) mx = fmaxf(mx, __shfl_xor(mx, off, 64));
    float xA = (eA < deg) ? expf(dA - mx) : 0.f;
    float xB = (eB < deg) ? expf(dB - mx) : 0.f;
    float sum = xA + xB;
#pragma unroll
    for (int off = 4; off < 64; off <<= 1) sum += __shfl_xor(sum, off, 64);
    float inv = 1.f / sum;
    if (fo == 0) {
      if (eA < deg) e_soft[edA.y] = xA * inv;
      if (eB < deg) e_soft[edB.y] = xB * inv;
    }
  } else if (deg <= MAXD) {
    for (int i0 = 0; i0 < deg; i0 += 16) {
      int e = i0 + eo;
      int idx = beg + (e < deg ? e : deg - 1);   // clamp: loads unguarded
      int2 ed = edata[idx];
      U a0, a1;
      a0.u = *reinterpret_cast<const uint4*>(a16u + (unsigned)ed.x * 32u + fo * 8);
      a1.u = *reinterpret_cast<const uint4*>(a16u + (unsigned)ed.x * 32u + fo * 8 + 4);
      float d = 0.f;
#pragma unroll
      for (int j = 0; j < 4; ++j) d = __builtin_amdgcn_fdot2(a0.h[j], tc0.h[j], d, false);
#pragma unroll
      for (int j = 0; j < 4; ++j) d = __builtin_amdgcn_fdot2(a1.h[j], tc1.h[j], d, false);
#pragma unroll
      for (int off = 1; off < 4; off <<= 1) d += __shfl_xor(d, off, 64);
      if (fo == 0 && e < deg) {
        d = d > 0.f ? d : NEG_SLOPE * d;
        ebuf[lw][e] = d;
      }
    }
    if (deg <= 64) {
      float sc = (lane < deg) ? ebuf[lw][lane] : -INFINITY;
      float mx = sc;
#pragma unroll
      for (int off = 32; off > 0; off >>= 1) mx = fmaxf(mx, __shfl_xor(mx, off, 64));
      float ex = (lane < deg) ? expf(sc - mx) : 0.f;
      float sum = ex;
#pragma unroll
      for (int off = 32; off > 0; off >>= 1) sum += __shfl_xor(sum, off, 64);
      float inv = 1.f / sum;
      if (lane < deg) e_soft[edata[beg + lane].y] = ex * inv;
    } else {
      float mx = -INFINITY;
      for (int i = lane; i < deg; i += 64) mx = fmaxf(mx, ebuf[lw][i]);
#pragma unroll
      for (int off = 32; off > 0; off >>= 1) mx = fmaxf(mx, __shfl_xor(mx, off, 64));
      float sum = 0.f;
      for (int i = lane; i < deg; i += 64) {
        float ex = expf(ebuf[lw][i] - mx);
        ebuf[lw][i] = ex;
        sum += ex;
      }
#pragma unroll
      for (int off = 32; off > 0; off >>= 1) sum += __shfl_xor(sum, off, 64);
      float inv = 1.f / sum;
      for (int i = lane; i < deg; i += 64) e_soft[edata[beg + i].y] = ebuf[lw][i] * inv;
    }
  } else {
    // recompute fallback (statistically never hit with Poisson(16) degrees)
    float mx = -INFINITY;
    for (int i0 = 0; i0 < deg; i0 += 16) {
      int e = i0 + eo;
      int idx = beg + (e < deg ? e : deg - 1);
      int2 ed = edata[idx];
      U a0, a1;
      a0.u = *reinterpret_cast<const uint4*>(a16u + (unsigned)ed.x * 32u + fo * 8);
      a1.u = *reinterpret_cast<const uint4*>(a16u + (unsigned)ed.x * 32u + fo * 8 + 4);
      float d = 0.f;
#pragma unroll
      for (int j = 0; j < 4; ++j) d = __builtin_amdgcn_fdot2(a0.h[j], tc0.h[j], d, false);
#pragma unroll
      for (int j = 0; j < 4; ++j) d = __builtin_amdgcn_fdot2(a1.h[j], tc1.h[j], d, false);
#pragma unroll
      for (int off = 1; off < 4; off <<= 1) d += __shfl_xor(d, off, 64);
      d = d > 0.f ? d : NEG_SLOPE * d;
      if (e >= deg) d = -INFINITY;
#pragma unroll
      for (int off = 4; off < 64; off <<= 1) d = fmaxf(d, __shfl_xor(d, off, 64));
      mx = fmaxf(mx, d);
    }
    float sum = 0.f;
    for (int i0 = 0; i0 < deg; i0 += 16) {
      int e = i0 + eo;
      int idx = beg + (e < deg ? e : deg - 1);
      int2 ed = edata[idx];
      U a0, a1;
      a0.u = *reinterpret_cast<const uint4*>(a16u + (unsigned)ed.x * 32u + fo * 8);
      a1.u = *reinterpret_cast<const uint4*>(a16u + (unsigned)ed.x * 32u + fo * 8 + 4);
      float d = 0.f;
#pragma unroll
      for (int j = 0; j < 4; ++j) d = __builtin_amdgcn_fdot2(a0.h[j], tc0.h[j], d, false);
#pragma unroll
      for (int j = 0; j < 4; ++j) d = __builtin_amdgcn_fdot2(a1.h[j], tc1.h[j], d, false);
#pragma unroll
      for (int off = 1; off < 4; off <<= 1) d += __shfl_xor(d, off, 64);
      d = d > 0.f ? d : NEG_SLOPE * d;
      float ex = (e < deg) ? expf(d - mx) : 0.f;
#pragma unroll
      for (int off = 4; off < 64; off <<= 1) ex += __shfl_xor(ex, off, 64);
      sum += ex;
    }
    float inv = 1.f / sum;
    for (int i0 = 0; i0 < deg; i0 += 16) {
      int e = i0 + eo;
      int idx = beg + (e < deg ? e : deg - 1);
      int2 ed = edata[idx];
      U a0, a1;
      a0.u = *reinterpret_cast<const uint4*>(a16u + (unsigned)ed.x * 32u + fo * 8);
      a1.u = *reinterpret_cast<const uint4*>(a16u + (unsigned)ed.x * 32u + fo * 8 + 4);
      float d = 0.f;
#pragma unroll
      for (int j = 0; j < 4; ++j) d = __builtin_amdgcn_fdot2(a0.h[j], tc0.h[j], d, false);
#pragma unroll
      for (int j = 0; j < 4; ++j) d = __builtin_amdgcn_fdot2(a1.h[j], tc1.h[j], d, false);
#pragma unroll
      for (int off = 1; off < 4; off <<= 1) d += __shfl_xor(d, off, 64);
      d = d > 0.f ? d : NEG_SLOPE * d;
      if (fo == 0 && e < deg) e_soft[ed.y] = expf(d - mx) * inv;
    }
  }
}

extern "C" void kernel_launch(void* const* d_in, const int* in_sizes, int n_in,
                              void* d_out, int out_size, void* d_ws, size_t ws_size,
                              hipStream_t stream) {
  const float* feat = (const float*)d_in[0];
  const float* W    = (const float*)d_in[1];
  const int*   src  = (const int*)d_in[2];
  const int*   dst  = (const int*)d_in[3];
  const int n_nodes = in_sizes[0] / IN_FEATS;
  const int n_edges = in_sizes[2];
  const int nbuck   = (n_nodes + BNODES - 1) >> BSH;   // <= 512

  // Output layout: [h_agg (N*64) | e_soft (E)]
  float* h_agg  = (float*)d_out;
  float* e_soft = (float*)d_out + (size_t)n_nodes * OUT_FEATS;

  // Workspace:
  // [h16 (N*64 bf16) | a16 (N*64 f16) | bcount(513) | bbase(513)
  //  | bcursor(512) | row_ptr(N+1 pad) | tmpe (E int2) | edata (E int2)]
  // t16 aliases tmpe (dead after binB; agg runs after binB and must NOT
  // alias h16, which it reads).
  unsigned short* h16 = (unsigned short*)d_ws;
  unsigned short* a16 = h16 + (size_t)n_nodes * OUT_FEATS;
  int* bcount   = (int*)(a16 + (size_t)n_nodes * OUT_FEATS);
  int* bbase    = bcount + 513;
  int* bcursor  = bbase + 513;
  int* row_ptr  = bcursor + 512;
  size_t rp_pad = ((size_t)n_nodes + 2) & ~(size_t)1;
  int2* tmpe    = (int2*)(row_ptr + rp_pad);
  int2* edata   = tmpe + n_edges;
  unsigned* t16 = (unsigned*)tmpe;          // N*32 uints <= E*2 ints: fits

  const int eb2 = (n_edges + CHUNK - 1) / CHUNK;
  const int wb  = (n_nodes * 64 + 255) / 256;   // wave-per-node grid (softmax)
  const int ab  = (n_nodes * 8 + 255) / 256;    // 8-lane-per-node grid (agg)

  hipMemsetAsync(bcount, 0, (size_t)nbuck * sizeof(int), stream);

  // MFMA gemm: 512 blocks x 4 waves, grid-stride over 16-node tiles
  gemm_h_kernel<<<512, 256, 0, stream>>>(feat, W, h16, n_nodes);

  bhist_kernel<<<eb2, 256, 0, stream>>>(dst, bcount, n_edges, nbuck);
  bscan_kernel<<<1, 512, 0, stream>>>(bcount, bbase, bcursor, nbuck, n_edges);
  bscatter_kernel<<<eb2, 256, 0, stream>>>(src, dst, bcursor, tmpe, n_edges, nbuck);
  binB_kernel<<<nbuck, 256, 0, stream>>>(tmpe, bbase, edata, row_ptr, n_nodes, n_edges);

  agg_kernel<<<ab, 256, 0, stream>>>((const unsigned*)h16, row_ptr, edata,
                                     h_agg, (unsigned*)a16, t16, n_nodes);

  softmax_kernel<<<wb, 256, 0, stream>>>((const unsigned*)a16, (const unsigned*)t16,
                                         row_ptr, edata, e_soft, n_nodes);
}

// Round 18
// 161.554 us; speedup vs baseline: 1.4271x; 1.0729x over previous
//
#include <hip/hip_runtime.h>
#include <math.h>

#define IN_FEATS 128
#define OUT_FEATS 64
#define NEG_SLOPE 0.2f
#define MAXD 256
#define BSH 8                      // bucket = dst >> 8 (256 nodes/bucket)
#define BNODES (1 << BSH)
#define CHUNK 8192                 // edges per block in bucket passes
#define EID_BITS 21                // n_edges < 2^21

typedef _Float16 half2_t __attribute__((ext_vector_type(2)));
typedef short bf16x8 __attribute__((ext_vector_type(8)));   // 8 bf16 = 4 VGPRs
typedef float f32x4 __attribute__((ext_vector_type(4)));    // MFMA acc

// bf16 helpers (h16 stays bf16 for agg's accumulation path)
__device__ __forceinline__ float bf_lo(unsigned u) { return __uint_as_float(u << 16); }
__device__ __forceinline__ float bf_hi(unsigned u) { return __uint_as_float(u & 0xffff0000u); }
__device__ __forceinline__ unsigned short f2bf(float f) {
  unsigned x = __float_as_uint(f);
  x += 0x7fff + ((x >> 16) & 1);          // round to nearest even
  return (unsigned short)(x >> 16);
}
// bit-cast any 4-byte vector (cvt_pkrtz returns __fp16x2, fdot2 takes _Float16x2)
template <typename T>
__device__ __forceinline__ unsigned h2u(T h) {
  union { T h; unsigned u; } c; c.h = h; return c.u;
}

// ---------------------------------------------------------------------------
// K1: h16 = bf16(feat @ W^T) via MFMA 16x16x32 bf16 (R16-proven).
// ---------------------------------------------------------------------------
__global__ __launch_bounds__(256)
void gemm_h_kernel(const float* __restrict__ feat,
                   const float* __restrict__ W,
                   unsigned short* __restrict__ h16, int n_nodes) {
  const int wid    = (blockIdx.x * blockDim.x + threadIdx.x) >> 6;
  const int lane   = threadIdx.x & 63;
  const int nwaves = (gridDim.x * blockDim.x) >> 6;
  const int r16 = lane & 15;          // row (A) / col (B,D)
  const int kb  = lane >> 4;          // k-block 0..3

  bf16x8 wf[4][4];
#pragma unroll
  for (int ot = 0; ot < 4; ++ot) {
#pragma unroll
    for (int kc = 0; kc < 4; ++kc) {
      const float* wp = W + (size_t)(ot * 16 + r16) * IN_FEATS + kc * 32 + kb * 8;
      float4 w0 = *reinterpret_cast<const float4*>(wp);
      float4 w1 = *reinterpret_cast<const float4*>(wp + 4);
      bf16x8 f;
      f[0] = (short)f2bf(w0.x); f[1] = (short)f2bf(w0.y);
      f[2] = (short)f2bf(w0.z); f[3] = (short)f2bf(w0.w);
      f[4] = (short)f2bf(w1.x); f[5] = (short)f2bf(w1.y);
      f[6] = (short)f2bf(w1.z); f[7] = (short)f2bf(w1.w);
      wf[ot][kc] = f;
    }
  }

  const int ntiles = (n_nodes + 15) >> 4;
  for (int t = wid; t < ntiles; t += nwaves) {
    const int n0 = t * 16;
    int row = n0 + r16;
    if (row >= n_nodes) row = n_nodes - 1;   // clamp loads; stores guarded
    const float* fp = feat + (size_t)row * IN_FEATS + kb * 8;

    bf16x8 af[4];
#pragma unroll
    for (int kc = 0; kc < 4; ++kc) {
      float4 a0 = *reinterpret_cast<const float4*>(fp + kc * 32);
      float4 a1 = *reinterpret_cast<const float4*>(fp + kc * 32 + 4);
      bf16x8 f;
      f[0] = (short)f2bf(a0.x); f[1] = (short)f2bf(a0.y);
      f[2] = (short)f2bf(a0.z); f[3] = (short)f2bf(a0.w);
      f[4] = (short)f2bf(a1.x); f[5] = (short)f2bf(a1.y);
      f[6] = (short)f2bf(a1.z); f[7] = (short)f2bf(a1.w);
      af[kc] = f;
    }

    f32x4 acc[4];
#pragma unroll
    for (int ot = 0; ot < 4; ++ot) acc[ot] = (f32x4){0.f, 0.f, 0.f, 0.f};
#pragma unroll
    for (int ot = 0; ot < 4; ++ot) {
#pragma unroll
      for (int kc = 0; kc < 4; ++kc) {
        acc[ot] = __builtin_amdgcn_mfma_f32_16x16x32_bf16(af[kc], wf[ot][kc],
                                                          acc[ot], 0, 0, 0);
      }
    }

#pragma unroll
    for (int ot = 0; ot < 4; ++ot) {
#pragma unroll
      for (int reg = 0; reg < 4; ++reg) {
        int node = n0 + (lane >> 4) * 4 + reg;
        if (node < n_nodes)
          h16[(size_t)node * OUT_FEATS + ot * 16 + r16] = f2bf(acc[ot][reg]);
      }
    }
  }
}

// ---------------------------------------------------------------------------
// Bucket sort pass A1: per-bucket edge counts. int4 loads (4 edges / 16B),
// 8192 edges per block; scalar tail handled by block 0.
// ---------------------------------------------------------------------------
__global__ __launch_bounds__(256)
void bhist_kernel(const int* __restrict__ dst, int* __restrict__ bcount,
                  int n_edges, int nbuck) {
  __shared__ int hist[512];
  const int t = threadIdx.x;
  for (int i = t; i < nbuck; i += 256) hist[i] = 0;
  __syncthreads();
  const int n4 = n_edges >> 2;
  const int4* dst4 = reinterpret_cast<const int4*>(dst);
  const int base = blockIdx.x * (CHUNK / 4);
#pragma unroll
  for (int i = 0; i < 8; ++i) {
    int idx = base + t + i * 256;
    if (idx < n4) {
      int4 d = dst4[idx];
      atomicAdd(&hist[d.x >> BSH], 1);
      atomicAdd(&hist[d.y >> BSH], 1);
      atomicAdd(&hist[d.z >> BSH], 1);
      atomicAdd(&hist[d.w >> BSH], 1);
    }
  }
  if (blockIdx.x == 0) {
    for (int e = (n4 << 2) + t; e < n_edges; e += 256)
      atomicAdd(&hist[dst[e] >> BSH], 1);
  }
  __syncthreads();
  for (int i = t; i < nbuck; i += 256)
    if (hist[i]) atomicAdd(&bcount[i], hist[i]);
}

// ---------------------------------------------------------------------------
// A2: exclusive scan of bucket counts
// ---------------------------------------------------------------------------
__global__ void bscan_kernel(const int* __restrict__ bcount, int* __restrict__ bbase,
                             int* __restrict__ bcursor, int nbuck, int n_edges) {
  __shared__ int tmp[512];
  const int t = threadIdx.x;
  int v = (t < nbuck) ? bcount[t] : 0;
  tmp[t] = v;
  __syncthreads();
  for (int off = 1; off < 512; off <<= 1) {
    int x = (t >= off) ? tmp[t - off] : 0;
    __syncthreads();
    tmp[t] += x;
    __syncthreads();
  }
  if (t < nbuck) { int excl = tmp[t] - v; bbase[t] = excl; bcursor[t] = excl; }
  if (t == 0) bbase[nbuck] = n_edges;
}

// ---------------------------------------------------------------------------
// A3: scatter edges into bucket regions. int4 loads (4 edges / 16B), 8192
// edges per block -> ~21-edge contiguous runs per (block,bucket).
// ---------------------------------------------------------------------------
__global__ __launch_bounds__(256)
void bscatter_kernel(const int* __restrict__ src, const int* __restrict__ dst,
                     int* __restrict__ bcursor, int2* __restrict__ tmpe,
                     int n_edges, int nbuck) {
  __shared__ int hist[512];
  __shared__ int basech[512];
  __shared__ int offs[512];
  const int t = threadIdx.x;
  const int n4 = n_edges >> 2;
  const int4* src4 = reinterpret_cast<const int4*>(src);
  const int4* dst4 = reinterpret_cast<const int4*>(dst);
  const int base = blockIdx.x * (CHUNK / 4);
  for (int i = t; i < nbuck; i += 256) { hist[i] = 0; offs[i] = 0; }
  __syncthreads();

  int4 sv[8], dv[8];
#pragma unroll
  for (int i = 0; i < 8; ++i) {
    int idx = base + t + i * 256;
    if (idx < n4) {
      sv[i] = src4[idx];
      dv[i] = dst4[idx];
      atomicAdd(&hist[dv[i].x >> BSH], 1);
      atomicAdd(&hist[dv[i].y >> BSH], 1);
      atomicAdd(&hist[dv[i].z >> BSH], 1);
      atomicAdd(&hist[dv[i].w >> BSH], 1);
    } else {
      dv[i].x = -1;
    }
  }
  if (blockIdx.x == 0) {
    for (int e = (n4 << 2) + t; e < n_edges; e += 256)
      atomicAdd(&hist[dst[e] >> BSH], 1);
  }
  __syncthreads();
  for (int i = t; i < nbuck; i += 256)
    if (hist[i]) basech[i] = atomicAdd(&bcursor[i], hist[i]);
  __syncthreads();

#pragma unroll
  for (int i = 0; i < 8; ++i) {
    if (dv[i].x >= 0) {
      int e0 = (base + t + i * 256) << 2;
      int ss[4] = {sv[i].x, sv[i].y, sv[i].z, sv[i].w};
      int dd[4] = {dv[i].x, dv[i].y, dv[i].z, dv[i].w};
#pragma unroll
      for (int j = 0; j < 4; ++j) {
        int b = dd[j] >> BSH;
        int off = atomicAdd(&offs[b], 1);
        int2 v;
        v.x = ss[j];
        v.y = ((dd[j] & (BNODES - 1)) << EID_BITS) | (e0 + j);
        tmpe[basech[b] + off] = v;
      }
    }
  }
  if (blockIdx.x == 0) {
    for (int e = (n4 << 2) + t; e < n_edges; e += 256) {
      int d = dst[e];
      int b = d >> BSH;
      int off = atomicAdd(&offs[b], 1);
      int2 v;
      v.x = src[e];
      v.y = ((d & (BNODES - 1)) << EID_BITS) | e;
      tmpe[basech[b] + off] = v;
    }
  }
}

// ---------------------------------------------------------------------------
// B: one workgroup per bucket -> row_ptr + final CSR edata (src,eid).
// ---------------------------------------------------------------------------
__global__ __launch_bounds__(256)
void binB_kernel(const int2* __restrict__ tmpe, const int* __restrict__ bbase,
                 int2* __restrict__ edata, int* __restrict__ row_ptr,
                 int n_nodes, int n_edges) {
  __shared__ int cnt[BNODES];
  __shared__ int cur[BNODES];
  const int b = blockIdx.x;
  const int t = threadIdx.x;
  const int beg = bbase[b], end = bbase[b + 1];

  cnt[t] = 0;
  __syncthreads();
  for (int i = beg + t; i < end; i += 256)
    atomicAdd(&cnt[(tmpe[i].y >> EID_BITS) & (BNODES - 1)], 1);
  __syncthreads();

  int v = cnt[t];
  cur[t] = v;
  __syncthreads();
  for (int off = 1; off < BNODES; off <<= 1) {
    int x = (t >= off) ? cur[t - off] : 0;
    __syncthreads();
    cur[t] += x;
    __syncthreads();
  }
  int excl = cur[t] - v;
  int node = b * BNODES + t;
  if (node < n_nodes) row_ptr[node] = beg + excl;
  if (b == 0 && t == 0) row_ptr[n_nodes] = n_edges;
  __syncthreads();
  cur[t] = beg + excl;
  __syncthreads();

  for (int i = beg + t; i < end; i += 256) {
    int2 p = tmpe[i];
    int l = (p.y >> EID_BITS) & (BNODES - 1);
    int pos = atomicAdd(&cur[l], 1);
    int2 o;
    o.x = p.x;
    o.y = p.y & ((1 << EID_BITS) - 1);
    edata[pos] = o;
  }
}

// ---------------------------------------------------------------------------
// agg: 8 nodes per wave, 8 lanes per node, 2-deep gather pipeline (R15).
// Epilogue emits a16/t16 (f16) with full lane utilization.
// ---------------------------------------------------------------------------
__global__ void agg_kernel(const unsigned* __restrict__ h16u,  // rows of 32 uints
                           const int* __restrict__ row_ptr,
                           const int2* __restrict__ edata, float* __restrict__ h_agg,
                           unsigned* __restrict__ a16u, unsigned* __restrict__ t16u,
                           int n_nodes) {
  int tid  = blockIdx.x * blockDim.x + threadIdx.x;
  int node = tid >> 3;
  int fo   = tid & 7;
  if (node >= n_nodes) return;
  int beg = row_ptr[node], end = row_ptr[node + 1];
  float acc[8] = {0.f, 0.f, 0.f, 0.f, 0.f, 0.f, 0.f, 0.f};
  if (beg < end) {
    uint4 v = *reinterpret_cast<const uint4*>(
        h16u + (unsigned)edata[beg].x * 32u + fo * 4);
    for (int i = beg + 1; i < end; ++i) {
      uint4 vn = *reinterpret_cast<const uint4*>(
          h16u + (unsigned)edata[i].x * 32u + fo * 4);   // next gather in flight
      acc[0] += bf_lo(v.x); acc[1] += bf_hi(v.x);
      acc[2] += bf_lo(v.y); acc[3] += bf_hi(v.y);
      acc[4] += bf_lo(v.z); acc[5] += bf_hi(v.z);
      acc[6] += bf_lo(v.w); acc[7] += bf_hi(v.w);
      v = vn;
    }
    acc[0] += bf_lo(v.x); acc[1] += bf_hi(v.x);
    acc[2] += bf_lo(v.y); acc[3] += bf_hi(v.y);
    acc[4] += bf_lo(v.z); acc[5] += bf_hi(v.z);
    acc[6] += bf_lo(v.w); acc[7] += bf_hi(v.w);
  }
  float4 a, b;
  a.x = acc[0]; a.y = acc[1]; a.z = acc[2]; a.w = acc[3];
  b.x = acc[4]; b.y = acc[5]; b.z = acc[6]; b.w = acc[7];
  float* out = h_agg + (size_t)node * OUT_FEATS + fo * 8;
  *reinterpret_cast<float4*>(out) = a;
  *reinterpret_cast<float4*>(out + 4) = b;

  uint4 pa;
  pa.x = h2u(__builtin_amdgcn_cvt_pkrtz(acc[0], acc[1]));
  pa.y = h2u(__builtin_amdgcn_cvt_pkrtz(acc[2], acc[3]));
  pa.z = h2u(__builtin_amdgcn_cvt_pkrtz(acc[4], acc[5]));
  pa.w = h2u(__builtin_amdgcn_cvt_pkrtz(acc[6], acc[7]));
  *reinterpret_cast<uint4*>(a16u + (unsigned)node * 32u + fo * 4) = pa;

  uint4 pt;
  pt.x = h2u(__builtin_amdgcn_cvt_pkrtz(tanhf(acc[0]), tanhf(acc[1])));
  pt.y = h2u(__builtin_amdgcn_cvt_pkrtz(tanhf(acc[2]), tanhf(acc[3])));
  pt.z = h2u(__builtin_amdgcn_cvt_pkrtz(tanhf(acc[4]), tanhf(acc[5])));
  pt.w = h2u(__builtin_amdgcn_cvt_pkrtz(tanhf(acc[6]), tanhf(acc[7])));
  *reinterpret_cast<uint4*>(t16u + (unsigned)node * 32u + fo * 4) = pt;
}

// ---------------------------------------------------------------------------
// fused per-node edge softmax over f16 rows (R17-proven).
// deg<=32 fast path: fo = lane&3 (32B/lane), eo = lane>>2, two 16-edge
// batches with unconditional clamped loads, zero LDS.
// ---------------------------------------------------------------------------
__global__ __launch_bounds__(256)
void softmax_kernel(const unsigned* __restrict__ a16u, const unsigned* __restrict__ t16u,
                    const int* __restrict__ row_ptr, const int2* __restrict__ edata,
                    float* __restrict__ e_soft, int n_nodes) {
  __shared__ float ebuf[4][MAXD];
  int wid  = (blockIdx.x * blockDim.x + threadIdx.x) >> 6;
  int lane = threadIdx.x & 63;
  int lw   = threadIdx.x >> 6;
  int eo = lane >> 2;   // 0..15 edge slot
  int fo = lane & 3;    // 0..3  row quarter (32B)
  if (wid >= n_nodes) return;
  int beg = row_ptr[wid], end = row_ptr[wid + 1];
  int deg = end - beg;
  if (deg == 0) return;

  union U { uint4 u; half2_t h[4]; };
  U tc0, tc1;
  tc0.u = *reinterpret_cast<const uint4*>(t16u + (unsigned)wid * 32u + fo * 8);
  tc1.u = *reinterpret_cast<const uint4*>(t16u + (unsigned)wid * 32u + fo * 8 + 4);

  if (deg <= 32) {
    int eA = eo, eB = 16 + eo;
    int idxA = beg + (eA < deg ? eA : deg - 1);
    int idxB = beg + (eB < deg ? eB : deg - 1);
    int2 edA = edata[idxA];
    int2 edB = edata[idxB];
    U a0A, a1A, a0B, a1B;
    a0A.u = *reinterpret_cast<const uint4*>(a16u + (unsigned)edA.x * 32u + fo * 8);
    a1A.u = *reinterpret_cast<const uint4*>(a16u + (unsigned)edA.x * 32u + fo * 8 + 4);
    a0B.u = *reinterpret_cast<const uint4*>(a16u + (unsigned)edB.x * 32u + fo * 8);
    a1B.u = *reinterpret_cast<const uint4*>(a16u + (unsigned)edB.x * 32u + fo * 8 + 4);

    float dA = 0.f, dB = 0.f;
#pragma unroll
    for (int j = 0; j < 4; ++j) {
      dA = __builtin_amdgcn_fdot2(a0A.h[j], tc0.h[j], dA, false);
      dB = __builtin_amdgcn_fdot2(a0B.h[j], tc0.h[j], dB, false);
    }
#pragma unroll
    for (int j = 0; j < 4; ++j) {
      dA = __builtin_amdgcn_fdot2(a1A.h[j], tc1.h[j], dA, false);
      dB = __builtin_amdgcn_fdot2(a1B.h[j], tc1.h[j], dB, false);
    }
#pragma unroll
    for (int off = 1; off < 4; off <<= 1) {
      dA += __shfl_xor(dA, off, 64);
      dB += __shfl_xor(dB, off, 64);
    }
    dA = dA > 0.f ? dA : NEG_SLOPE * dA;
    dB = dB > 0.f ? dB : NEG_SLOPE * dB;
    float mA = (eA < deg) ? dA : -INFINITY;
    float mB = (eB < deg) ? dB : -INFINITY;
    float mx = fmaxf(mA, mB);
#pragma unroll
    for (int off = 4; off < 64; off <<= 1) mx = fmaxf(mx, __shfl_xor(mx, off, 64));
    float xA = (eA < deg) ? expf(dA - mx) : 0.f;
    float xB = (eB < deg) ? expf(dB - mx) : 0.f;
    float sum = xA + xB;
#pragma unroll
    for (int off = 4; off < 64; off <<= 1) sum += __shfl_xor(sum, off, 64);
    float inv = 1.f / sum;
    if (fo == 0) {
      if (eA < deg) e_soft[edA.y] = xA * inv;
      if (eB < deg) e_soft[edB.y] = xB * inv;
    }
  } else if (deg <= MAXD) {
    for (int i0 = 0; i0 < deg; i0 += 16) {
      int e = i0 + eo;
      int idx = beg + (e < deg ? e : deg - 1);   // clamp: loads unguarded
      int2 ed = edata[idx];
      U a0, a1;
      a0.u = *reinterpret_cast<const uint4*>(a16u + (unsigned)ed.x * 32u + fo * 8);
      a1.u = *reinterpret_cast<const uint4*>(a16u + (unsigned)ed.x * 32u + fo * 8 + 4);
      float d = 0.f;
#pragma unroll
      for (int j = 0; j < 4; ++j) d = __builtin_amdgcn_fdot2(a0.h[j], tc0.h[j], d, false);
#pragma unroll
      for (int j = 0; j < 4; ++j) d = __builtin_amdgcn_fdot2(a1.h[j], tc1.h[j], d, false);
#pragma unroll
      for (int off = 1; off < 4; off <<= 1) d += __shfl_xor(d, off, 64);
      if (fo == 0 && e < deg) {
        d = d > 0.f ? d : NEG_SLOPE * d;
        ebuf[lw][e] = d;
      }
    }
    if (deg <= 64) {
      float sc = (lane < deg) ? ebuf[lw][lane] : -INFINITY;
      float mx = sc;
#pragma unroll
      for (int off = 32; off > 0; off >>= 1) mx = fmaxf(mx, __shfl_xor(mx, off, 64));
      float ex = (lane < deg) ? expf(sc - mx) : 0.f;
      float sum = ex;
#pragma unroll
      for (int off = 32; off > 0; off >>= 1) sum += __shfl_xor(sum, off, 64);
      float inv = 1.f / sum;
      if (lane < deg) e_soft[edata[beg + lane].y] = ex * inv;
    } else {
      float mx = -INFINITY;
      for (int i = lane; i < deg; i += 64) mx = fmaxf(mx, ebuf[lw][i]);
#pragma unroll
      for (int off = 32; off > 0; off >>= 1) mx = fmaxf(mx, __shfl_xor(mx, off, 64));
      float sum = 0.f;
      for (int i = lane; i < deg; i += 64) {
        float ex = expf(ebuf[lw][i] - mx);
        ebuf[lw][i] = ex;
        sum += ex;
      }
#pragma unroll
      for (int off = 32; off > 0; off >>= 1) sum += __shfl_xor(sum, off, 64);
      float inv = 1.f / sum;
      for (int i = lane; i < deg; i += 64) e_soft[edata[beg + i].y] = ebuf[lw][i] * inv;
    }
  } else {
    // recompute fallback (statistically never hit with Poisson(16) degrees)
    float mx = -INFINITY;
    for (int i0 = 0; i0 < deg; i0 += 16) {
      int e = i0 + eo;
      int idx = beg + (e < deg ? e : deg - 1);
      int2 ed = edata[idx];
      U a0, a1;
      a0.u = *reinterpret_cast<const uint4*>(a16u + (unsigned)ed.x * 32u + fo * 8);
      a1.u = *reinterpret_cast<const uint4*>(a16u + (unsigned)ed.x * 32u + fo * 8 + 4);
      float d = 0.f;
#pragma unroll
      for (int j = 0; j < 4; ++j) d = __builtin_amdgcn_fdot2(a0.h[j], tc0.h[j], d, false);
#pragma unroll
      for (int j = 0; j < 4; ++j) d = __builtin_amdgcn_fdot2(a1.h[j], tc1.h[j], d, false);
#pragma unroll
      for (int off = 1; off < 4; off <<= 1) d += __shfl_xor(d, off, 64);
      d = d > 0.f ? d : NEG_SLOPE * d;
      if (e >= deg) d = -INFINITY;
#pragma unroll
      for (int off = 4; off < 64; off <<= 1) d = fmaxf(d, __shfl_xor(d, off, 64));
      mx = fmaxf(mx, d);
    }
    float sum = 0.f;
    for (int i0 = 0; i0 < deg; i0 += 16) {
      int e = i0 + eo;
      int idx = beg + (e < deg ? e : deg - 1);
      int2 ed = edata[idx];
      U a0, a1;
      a0.u = *reinterpret_cast<const uint4*>(a16u + (unsigned)ed.x * 32u + fo * 8);
      a1.u = *reinterpret_cast<const uint4*>(a16u + (unsigned)ed.x * 32u + fo * 8 + 4);
      float d = 0.f;
#pragma unroll
      for (int j = 0; j < 4; ++j) d = __builtin_amdgcn_fdot2(a0.h[j], tc0.h[j], d, false);
#pragma unroll
      for (int j = 0; j < 4; ++j) d = __builtin_amdgcn_fdot2(a1.h[j], tc1.h[j], d, false);
#pragma unroll
      for (int off = 1; off < 4; off <<= 1) d += __shfl_xor(d, off, 64);
      d = d > 0.f ? d : NEG_SLOPE * d;
      float ex = (e < deg) ? expf(d - mx) : 0.f;
#pragma unroll
      for (int off = 4; off < 64; off <<= 1) ex += __shfl_xor(ex, off, 64);
      sum += ex;
    }
    float inv = 1.f / sum;
    for (int i0 = 0; i0 < deg; i0 += 16) {
      int e = i0 + eo;
      int idx = beg + (e < deg ? e : deg - 1);
      int2 ed = edata[idx];
      U a0, a1;
      a0.u = *reinterpret_cast<const uint4*>(a16u + (unsigned)ed.x * 32u + fo * 8);
      a1.u = *reinterpret_cast<const uint4*>(a16u + (unsigned)ed.x * 32u + fo * 8 + 4);
      float d = 0.f;
#pragma unroll
      for (int j = 0; j < 4; ++j) d = __builtin_amdgcn_fdot2(a0.h[j], tc0.h[j], d, false);
#pragma unroll
      for (int j = 0; j < 4; ++j) d = __builtin_amdgcn_fdot2(a1.h[j], tc1.h[j], d, false);
#pragma unroll
      for (int off = 1; off < 4; off <<= 1) d += __shfl_xor(d, off, 64);
      d = d > 0.f ? d : NEG_SLOPE * d;
      if (fo == 0 && e < deg) e_soft[ed.y] = expf(d - mx) * inv;
    }
  }
}

extern "C" void kernel_launch(void* const* d_in, const int* in_sizes, int n_in,
                              void* d_out, int out_size, void* d_ws, size_t ws_size,
                              hipStream_t stream) {
  const float* feat = (const float*)d_in[0];
  const float* W    = (const float*)d_in[1];
  const int*   src  = (const int*)d_in[2];
  const int*   dst  = (const int*)d_in[3];
  const int n_nodes = in_sizes[0] / IN_FEATS;
  const int n_edges = in_sizes[2];
  const int nbuck   = (n_nodes + BNODES - 1) >> BSH;   // <= 512

  // Output layout: [h_agg (N*64) | e_soft (E)]
  float* h_agg  = (float*)d_out;
  float* e_soft = (float*)d_out + (size_t)n_nodes * OUT_FEATS;

  // Workspace:
  // [h16 (N*64 bf16) | a16 (N*64 f16) | bcount(513) | bbase(513)
  //  | bcursor(512) | row_ptr(N+1 pad) | tmpe (E int2) | edata (E int2)]
  // t16 aliases tmpe (dead after binB; agg runs after binB and must NOT
  // alias h16, which it reads).
  unsigned short* h16 = (unsigned short*)d_ws;
  unsigned short* a16 = h16 + (size_t)n_nodes * OUT_FEATS;
  int* bcount   = (int*)(a16 + (size_t)n_nodes * OUT_FEATS);
  int* bbase    = bcount + 513;
  int* bcursor  = bbase + 513;
  int* row_ptr  = bcursor + 512;
  size_t rp_pad = ((size_t)n_nodes + 2) & ~(size_t)1;
  int2* tmpe    = (int2*)(row_ptr + rp_pad);
  int2* edata   = tmpe + n_edges;
  unsigned* t16 = (unsigned*)tmpe;          // N*32 uints <= E*2 ints: fits

  const int eb2 = (n_edges + CHUNK - 1) / CHUNK;
  const int wb  = (n_nodes * 64 + 255) / 256;   // wave-per-node grid (softmax)
  const int ab  = (n_nodes * 8 + 255) / 256;    // 8-lane-per-node grid (agg)

  hipMemsetAsync(bcount, 0, (size_t)nbuck * sizeof(int), stream);

  // MFMA gemm: 512 blocks x 4 waves, grid-stride over 16-node tiles
  gemm_h_kernel<<<512, 256, 0, stream>>>(feat, W, h16, n_nodes);

  bhist_kernel<<<eb2, 256, 0, stream>>>(dst, bcount, n_edges, nbuck);
  bscan_kernel<<<1, 512, 0, stream>>>(bcount, bbase, bcursor, nbuck, n_edges);
  bscatter_kernel<<<eb2, 256, 0, stream>>>(src, dst, bcursor, tmpe, n_edges, nbuck);
  binB_kernel<<<nbuck, 256, 0, stream>>>(tmpe, bbase, edata, row_ptr, n_nodes, n_edges);

  agg_kernel<<<ab, 256, 0, stream>>>((const unsigned*)h16, row_ptr, edata,
                                     h_agg, (unsigned*)a16, t16, n_nodes);

  softmax_kernel<<<wb, 256, 0, stream>>>((const unsigned*)a16, (const unsigned*)t16,
                                         row_ptr, edata, e_soft, n_nodes);
}

// Round 19
// 156.966 us; speedup vs baseline: 1.4688x; 1.0292x over previous
//
#include <hip/hip_runtime.h>
#include <math.h>

#define IN_FEATS 128
#define OUT_FEATS 64
#define NEG_SLOPE 0.2f
#define MAXD 256
#define BSH 8                      // bucket = dst >> 8 (256 nodes/bucket)
#define BNODES (1 << BSH)
#define CHUNK 8192                 // edges per block in bucket passes
#define EID_BITS 21                // n_edges < 2^21
#define GEMM_BLOCKS 512

typedef _Float16 half2_t __attribute__((ext_vector_type(2)));
typedef short bf16x8 __attribute__((ext_vector_type(8)));   // 8 bf16 = 4 VGPRs
typedef float f32x4 __attribute__((ext_vector_type(4)));    // MFMA acc

__device__ __forceinline__ float bf_lo(unsigned u) { return __uint_as_float(u << 16); }
__device__ __forceinline__ float bf_hi(unsigned u) { return __uint_as_float(u & 0xffff0000u); }
__device__ __forceinline__ unsigned short f2bf(float f) {
  unsigned x = __float_as_uint(f);
  x += 0x7fff + ((x >> 16) & 1);          // round to nearest even
  return (unsigned short)(x >> 16);
}
template <typename T>
__device__ __forceinline__ unsigned h2u(T h) {
  union { T h; unsigned u; } c; c.h = h; return c.u;
}

// ---------------------------------------------------------------------------
// Fused K1: blocks [0,GEMM_BLOCKS) = MFMA gemm (h16 = bf16(feat @ W^T));
// blocks [GEMM_BLOCKS, ...) = bhist (per-bucket edge counts). The two are
// dataflow-independent; fusing removes serialization on the stream.
// ---------------------------------------------------------------------------
__global__ __launch_bounds__(256)
void gemm_bhist_kernel(const float* __restrict__ feat,
                       const float* __restrict__ W,
                       unsigned short* __restrict__ h16, int n_nodes,
                       const int* __restrict__ dst, int* __restrict__ bcount,
                       int n_edges, int nbuck) {
  __shared__ int hist[512];
  const int t = threadIdx.x;

  if (blockIdx.x >= GEMM_BLOCKS) {
    // ---- bhist part ----
    for (int i = t; i < nbuck; i += 256) hist[i] = 0;
    __syncthreads();
    const int n4 = n_edges >> 2;
    const int4* dst4 = reinterpret_cast<const int4*>(dst);
    const int bb = blockIdx.x - GEMM_BLOCKS;
    const int base = bb * (CHUNK / 4);
#pragma unroll
    for (int i = 0; i < 8; ++i) {
      int idx = base + t + i * 256;
      if (idx < n4) {
        int4 d = dst4[idx];
        atomicAdd(&hist[d.x >> BSH], 1);
        atomicAdd(&hist[d.y >> BSH], 1);
        atomicAdd(&hist[d.z >> BSH], 1);
        atomicAdd(&hist[d.w >> BSH], 1);
      }
    }
    if (bb == 0) {
      for (int e = (n4 << 2) + t; e < n_edges; e += 256)
        atomicAdd(&hist[dst[e] >> BSH], 1);
    }
    __syncthreads();
    for (int i = t; i < nbuck; i += 256)
      if (hist[i]) atomicAdd(&bcount[i], hist[i]);
    return;
  }

  // ---- gemm part (R16-proven MFMA) ----
  const int wid    = (blockIdx.x << 2) + (t >> 6);
  const int lane   = t & 63;
  const int nwaves = GEMM_BLOCKS * 4;
  const int r16 = lane & 15;
  const int kb  = lane >> 4;

  bf16x8 wf[4][4];
#pragma unroll
  for (int ot = 0; ot < 4; ++ot) {
#pragma unroll
    for (int kc = 0; kc < 4; ++kc) {
      const float* wp = W + (size_t)(ot * 16 + r16) * IN_FEATS + kc * 32 + kb * 8;
      float4 w0 = *reinterpret_cast<const float4*>(wp);
      float4 w1 = *reinterpret_cast<const float4*>(wp + 4);
      bf16x8 f;
      f[0] = (short)f2bf(w0.x); f[1] = (short)f2bf(w0.y);
      f[2] = (short)f2bf(w0.z); f[3] = (short)f2bf(w0.w);
      f[4] = (short)f2bf(w1.x); f[5] = (short)f2bf(w1.y);
      f[6] = (short)f2bf(w1.z); f[7] = (short)f2bf(w1.w);
      wf[ot][kc] = f;
    }
  }

  const int ntiles = (n_nodes + 15) >> 4;
  for (int tt = wid; tt < ntiles; tt += nwaves) {
    const int n0 = tt * 16;
    int row = n0 + r16;
    if (row >= n_nodes) row = n_nodes - 1;
    const float* fp = feat + (size_t)row * IN_FEATS + kb * 8;

    bf16x8 af[4];
#pragma unroll
    for (int kc = 0; kc < 4; ++kc) {
      float4 a0 = *reinterpret_cast<const float4*>(fp + kc * 32);
      float4 a1 = *reinterpret_cast<const float4*>(fp + kc * 32 + 4);
      bf16x8 f;
      f[0] = (short)f2bf(a0.x); f[1] = (short)f2bf(a0.y);
      f[2] = (short)f2bf(a0.z); f[3] = (short)f2bf(a0.w);
      f[4] = (short)f2bf(a1.x); f[5] = (short)f2bf(a1.y);
      f[6] = (short)f2bf(a1.z); f[7] = (short)f2bf(a1.w);
      af[kc] = f;
    }

    f32x4 acc[4];
#pragma unroll
    for (int ot = 0; ot < 4; ++ot) acc[ot] = (f32x4){0.f, 0.f, 0.f, 0.f};
#pragma unroll
    for (int ot = 0; ot < 4; ++ot) {
#pragma unroll
      for (int kc = 0; kc < 4; ++kc) {
        acc[ot] = __builtin_amdgcn_mfma_f32_16x16x32_bf16(af[kc], wf[ot][kc],
                                                          acc[ot], 0, 0, 0);
      }
    }

#pragma unroll
    for (int ot = 0; ot < 4; ++ot) {
#pragma unroll
      for (int reg = 0; reg < 4; ++reg) {
        int node = n0 + (lane >> 4) * 4 + reg;
        if (node < n_nodes)
          h16[(size_t)node * OUT_FEATS + ot * 16 + r16] = f2bf(acc[ot][reg]);
      }
    }
  }
}

// ---------------------------------------------------------------------------
// A2: exclusive scan of bucket counts
// ---------------------------------------------------------------------------
__global__ void bscan_kernel(const int* __restrict__ bcount, int* __restrict__ bbase,
                             int* __restrict__ bcursor, int nbuck, int n_edges) {
  __shared__ int tmp[512];
  const int t = threadIdx.x;
  int v = (t < nbuck) ? bcount[t] : 0;
  tmp[t] = v;
  __syncthreads();
  for (int off = 1; off < 512; off <<= 1) {
    int x = (t >= off) ? tmp[t - off] : 0;
    __syncthreads();
    tmp[t] += x;
    __syncthreads();
  }
  if (t < nbuck) { int excl = tmp[t] - v; bbase[t] = excl; bcursor[t] = excl; }
  if (t == 0) bbase[nbuck] = n_edges;
}

// ---------------------------------------------------------------------------
// A3: scatter edges into bucket regions (int4 loads, R18-proven)
// ---------------------------------------------------------------------------
__global__ __launch_bounds__(256)
void bscatter_kernel(const int* __restrict__ src, const int* __restrict__ dst,
                     int* __restrict__ bcursor, int2* __restrict__ tmpe,
                     int n_edges, int nbuck) {
  __shared__ int hist[512];
  __shared__ int basech[512];
  __shared__ int offs[512];
  const int t = threadIdx.x;
  const int n4 = n_edges >> 2;
  const int4* src4 = reinterpret_cast<const int4*>(src);
  const int4* dst4 = reinterpret_cast<const int4*>(dst);
  const int base = blockIdx.x * (CHUNK / 4);
  for (int i = t; i < nbuck; i += 256) { hist[i] = 0; offs[i] = 0; }
  __syncthreads();

  int4 sv[8], dv[8];
#pragma unroll
  for (int i = 0; i < 8; ++i) {
    int idx = base + t + i * 256;
    if (idx < n4) {
      sv[i] = src4[idx];
      dv[i] = dst4[idx];
      atomicAdd(&hist[dv[i].x >> BSH], 1);
      atomicAdd(&hist[dv[i].y >> BSH], 1);
      atomicAdd(&hist[dv[i].z >> BSH], 1);
      atomicAdd(&hist[dv[i].w >> BSH], 1);
    } else {
      dv[i].x = -1;
    }
  }
  if (blockIdx.x == 0) {
    for (int e = (n4 << 2) + t; e < n_edges; e += 256)
      atomicAdd(&hist[dst[e] >> BSH], 1);
  }
  __syncthreads();
  for (int i = t; i < nbuck; i += 256)
    if (hist[i]) basech[i] = atomicAdd(&bcursor[i], hist[i]);
  __syncthreads();

#pragma unroll
  for (int i = 0; i < 8; ++i) {
    if (dv[i].x >= 0) {
      int e0 = (base + t + i * 256) << 2;
      int ss[4] = {sv[i].x, sv[i].y, sv[i].z, sv[i].w};
      int dd[4] = {dv[i].x, dv[i].y, dv[i].z, dv[i].w};
#pragma unroll
      for (int j = 0; j < 4; ++j) {
        int b = dd[j] >> BSH;
        int off = atomicAdd(&offs[b], 1);
        int2 v;
        v.x = ss[j];
        v.y = ((dd[j] & (BNODES - 1)) << EID_BITS) | (e0 + j);
        tmpe[basech[b] + off] = v;
      }
    }
  }
  if (blockIdx.x == 0) {
    for (int e = (n4 << 2) + t; e < n_edges; e += 256) {
      int d = dst[e];
      int b = d >> BSH;
      int off = atomicAdd(&offs[b], 1);
      int2 v;
      v.x = src[e];
      v.y = ((d & (BNODES - 1)) << EID_BITS) | e;
      tmpe[basech[b] + off] = v;
    }
  }
}

// ---------------------------------------------------------------------------
// B: one workgroup per bucket -> row_ptr + final CSR edata (src,eid).
// ---------------------------------------------------------------------------
__global__ __launch_bounds__(256)
void binB_kernel(const int2* __restrict__ tmpe, const int* __restrict__ bbase,
                 int2* __restrict__ edata, int* __restrict__ row_ptr,
                 int n_nodes, int n_edges) {
  __shared__ int cnt[BNODES];
  __shared__ int cur[BNODES];
  const int b = blockIdx.x;
  const int t = threadIdx.x;
  const int beg = bbase[b], end = bbase[b + 1];

  cnt[t] = 0;
  __syncthreads();
  for (int i = beg + t; i < end; i += 256)
    atomicAdd(&cnt[(tmpe[i].y >> EID_BITS) & (BNODES - 1)], 1);
  __syncthreads();

  int v = cnt[t];
  cur[t] = v;
  __syncthreads();
  for (int off = 1; off < BNODES; off <<= 1) {
    int x = (t >= off) ? cur[t - off] : 0;
    __syncthreads();
    cur[t] += x;
    __syncthreads();
  }
  int excl = cur[t] - v;
  int node = b * BNODES + t;
  if (node < n_nodes) row_ptr[node] = beg + excl;
  if (b == 0 && t == 0) row_ptr[n_nodes] = n_edges;
  __syncthreads();
  cur[t] = beg + excl;
  __syncthreads();

  for (int i = beg + t; i < end; i += 256) {
    int2 p = tmpe[i];
    int l = (p.y >> EID_BITS) & (BNODES - 1);
    int pos = atomicAdd(&cur[l], 1);
    int2 o;
    o.x = p.x;
    o.y = p.y & ((1 << EID_BITS) - 1);
    edata[pos] = o;
  }
}

// ---------------------------------------------------------------------------
// agg: 8 nodes per wave, 8 lanes per node, 2-deep gather pipeline (R15).
// Epilogue emits a16/t16 (f16) with full lane utilization.
// ---------------------------------------------------------------------------
__global__ void agg_kernel(const unsigned* __restrict__ h16u,
                           const int* __restrict__ row_ptr,
                           const int2* __restrict__ edata, float* __restrict__ h_agg,
                           unsigned* __restrict__ a16u, unsigned* __restrict__ t16u,
                           int n_nodes) {
  int tid  = blockIdx.x * blockDim.x + threadIdx.x;
  int node = tid >> 3;
  int fo   = tid & 7;
  if (node >= n_nodes) return;
  int beg = row_ptr[node], end = row_ptr[node + 1];
  float acc[8] = {0.f, 0.f, 0.f, 0.f, 0.f, 0.f, 0.f, 0.f};
  if (beg < end) {
    uint4 v = *reinterpret_cast<const uint4*>(
        h16u + (unsigned)edata[beg].x * 32u + fo * 4);
    for (int i = beg + 1; i < end; ++i) {
      uint4 vn = *reinterpret_cast<const uint4*>(
          h16u + (unsigned)edata[i].x * 32u + fo * 4);
      acc[0] += bf_lo(v.x); acc[1] += bf_hi(v.x);
      acc[2] += bf_lo(v.y); acc[3] += bf_hi(v.y);
      acc[4] += bf_lo(v.z); acc[5] += bf_hi(v.z);
      acc[6] += bf_lo(v.w); acc[7] += bf_hi(v.w);
      v = vn;
    }
    acc[0] += bf_lo(v.x); acc[1] += bf_hi(v.x);
    acc[2] += bf_lo(v.y); acc[3] += bf_hi(v.y);
    acc[4] += bf_lo(v.z); acc[5] += bf_hi(v.z);
    acc[6] += bf_lo(v.w); acc[7] += bf_hi(v.w);
  }
  float4 a, b;
  a.x = acc[0]; a.y = acc[1]; a.z = acc[2]; a.w = acc[3];
  b.x = acc[4]; b.y = acc[5]; b.z = acc[6]; b.w = acc[7];
  float* out = h_agg + (size_t)node * OUT_FEATS + fo * 8;
  *reinterpret_cast<float4*>(out) = a;
  *reinterpret_cast<float4*>(out + 4) = b;

  uint4 pa;
  pa.x = h2u(__builtin_amdgcn_cvt_pkrtz(acc[0], acc[1]));
  pa.y = h2u(__builtin_amdgcn_cvt_pkrtz(acc[2], acc[3]));
  pa.z = h2u(__builtin_amdgcn_cvt_pkrtz(acc[4], acc[5]));
  pa.w = h2u(__builtin_amdgcn_cvt_pkrtz(acc[6], acc[7]));
  *reinterpret_cast<uint4*>(a16u + (unsigned)node * 32u + fo * 4) = pa;

  uint4 pt;
  pt.x = h2u(__builtin_amdgcn_cvt_pkrtz(tanhf(acc[0]), tanhf(acc[1])));
  pt.y = h2u(__builtin_amdgcn_cvt_pkrtz(tanhf(acc[2]), tanhf(acc[3])));
  pt.z = h2u(__builtin_amdgcn_cvt_pkrtz(tanhf(acc[4]), tanhf(acc[5])));
  pt.w = h2u(__builtin_amdgcn_cvt_pkrtz(tanhf(acc[6]), tanhf(acc[7])));
  *reinterpret_cast<uint4*>(t16u + (unsigned)node * 32u + fo * 4) = pt;
}

// ---------------------------------------------------------------------------
// per-node softmax worker (R17-proven): handles any deg.
// ---------------------------------------------------------------------------
__device__ __forceinline__
void softmax_one(const unsigned* __restrict__ a16u, const unsigned* __restrict__ t16u,
                 const int2* __restrict__ edata, float* __restrict__ e_soft,
                 float* __restrict__ ebuf_row, int wid, int beg, int deg,
                 int lane, int eo, int fo) {
  union U { uint4 u; half2_t h[4]; };
  U tc0, tc1;
  tc0.u = *reinterpret_cast<const uint4*>(t16u + (unsigned)wid * 32u + fo * 8);
  tc1.u = *reinterpret_cast<const uint4*>(t16u + (unsigned)wid * 32u + fo * 8 + 4);

  if (deg <= 32) {
    int eA = eo, eB = 16 + eo;
    int idxA = beg + (eA < deg ? eA : deg - 1);
    int idxB = beg + (eB < deg ? eB : deg - 1);
    int2 edA = edata[idxA];
    int2 edB = edata[idxB];
    U a0A, a1A, a0B, a1B;
    a0A.u = *reinterpret_cast<const uint4*>(a16u + (unsigned)edA.x * 32u + fo * 8);
    a1A.u = *reinterpret_cast<const uint4*>(a16u + (unsigned)edA.x * 32u + fo * 8 + 4);
    a0B.u = *reinterpret_cast<const uint4*>(a16u + (unsigned)edB.x * 32u + fo * 8);
    a1B.u = *reinterpret_cast<const uint4*>(a16u + (unsigned)edB.x * 32u + fo * 8 + 4);

    float dA = 0.f, dB = 0.f;
#pragma unroll
    for (int j = 0; j < 4; ++j) {
      dA = __builtin_amdgcn_fdot2(a0A.h[j], tc0.h[j], dA, false);
      dB = __builtin_amdgcn_fdot2(a0B.h[j], tc0.h[j], dB, false);
    }
#pragma unroll
    for (int j = 0; j < 4; ++j) {
      dA = __builtin_amdgcn_fdot2(a1A.h[j], tc1.h[j], dA, false);
      dB = __builtin_amdgcn_fdot2(a1B.h[j], tc1.h[j], dB, false);
    }
#pragma unroll
    for (int off = 1; off < 4; off <<= 1) {
      dA += __shfl_xor(dA, off, 64);
      dB += __shfl_xor(dB, off, 64);
    }
    dA = dA > 0.f ? dA : NEG_SLOPE * dA;
    dB = dB > 0.f ? dB : NEG_SLOPE * dB;
    float mA = (eA < deg) ? dA : -INFINITY;
    float mB = (eB < deg) ? dB : -INFINITY;
    float mx = fmaxf(mA, mB);
#pragma unroll
    for (int off = 4; off < 64; off <<= 1) mx = fmaxf(mx, __shfl_xor(mx, off, 64));
    float xA = (eA < deg) ? expf(dA - mx) : 0.f;
    float xB = (eB < deg) ? expf(dB - mx) : 0.f;
    float sum = xA + xB;
#pragma unroll
    for (int off = 4; off < 64; off <<= 1) sum += __shfl_xor(sum, off, 64);
    float inv = 1.f / sum;
    if (fo == 0) {
      if (eA < deg) e_soft[edA.y] = xA * inv;
      if (eB < deg) e_soft[edB.y] = xB * inv;
    }
  } else if (deg <= MAXD) {
    union U2 { uint4 u; half2_t h[4]; };
    for (int i0 = 0; i0 < deg; i0 += 16) {
      int e = i0 + eo;
      int idx = beg + (e < deg ? e : deg - 1);
      int2 ed = edata[idx];
      U2 a0, a1;
      a0.u = *reinterpret_cast<const uint4*>(a16u + (unsigned)ed.x * 32u + fo * 8);
      a1.u = *reinterpret_cast<const uint4*>(a16u + (unsigned)ed.x * 32u + fo * 8 + 4);
      float d = 0.f;
#pragma unroll
      for (int j = 0; j < 4; ++j) d = __builtin_amdgcn_fdot2(a0.h[j], tc0.h[j], d, false);
#pragma unroll
      for (int j = 0; j < 4; ++j) d = __builtin_amdgcn_fdot2(a1.h[j], tc1.h[j], d, false);
#pragma unroll
      for (int off = 1; off < 4; off <<= 1) d += __shfl_xor(d, off, 64);
      if (fo == 0 && e < deg) {
        d = d > 0.f ? d : NEG_SLOPE * d;
        ebuf_row[e] = d;
      }
    }
    if (deg <= 64) {
      float sc = (lane < deg) ? ebuf_row[lane] : -INFINITY;
      float mx = sc;
#pragma unroll
      for (int off = 32; off > 0; off >>= 1) mx = fmaxf(mx, __shfl_xor(mx, off, 64));
      float ex = (lane < deg) ? expf(sc - mx) : 0.f;
      float sum = ex;
#pragma unroll
      for (int off = 32; off > 0; off >>= 1) sum += __shfl_xor(sum, off, 64);
      float inv = 1.f / sum;
      if (lane < deg) e_soft[edata[beg + lane].y] = ex * inv;
    } else {
      float mx = -INFINITY;
      for (int i = lane; i < deg; i += 64) mx = fmaxf(mx, ebuf_row[i]);
#pragma unroll
      for (int off = 32; off > 0; off >>= 1) mx = fmaxf(mx, __shfl_xor(mx, off, 64));
      float sum = 0.f;
      for (int i = lane; i < deg; i += 64) {
        float ex = expf(ebuf_row[i] - mx);
        ebuf_row[i] = ex;
        sum += ex;
      }
#pragma unroll
      for (int off = 32; off > 0; off >>= 1) sum += __shfl_xor(sum, off, 64);
      float inv = 1.f / sum;
      for (int i = lane; i < deg; i += 64) e_soft[edata[beg + i].y] = ebuf_row[i] * inv;
    }
  } else {
    // recompute fallback (deg > 256; statistically never hit)
    union U3 { uint4 u; half2_t h[4]; };
    float mx = -INFINITY;
    for (int i0 = 0; i0 < deg; i0 += 16) {
      int e = i0 + eo;
      int idx = beg + (e < deg ? e : deg - 1);
      int2 ed = edata[idx];
      U3 a0, a1;
      a0.u = *reinterpret_cast<const uint4*>(a16u + (unsigned)ed.x * 32u + fo * 8);
      a1.u = *reinterpret_cast<const uint4*>(a16u + (unsigned)ed.x * 32u + fo * 8 + 4);
      float d = 0.f;
#pragma unroll
      for (int j = 0; j < 4; ++j) d = __builtin_amdgcn_fdot2(a0.h[j], tc0.h[j], d, false);
#pragma unroll
      for (int j = 0; j < 4; ++j) d = __builtin_amdgcn_fdot2(a1.h[j], tc1.h[j], d, false);
#pragma unroll
      for (int off = 1; off < 4; off <<= 1) d += __shfl_xor(d, off, 64);
      d = d > 0.f ? d : NEG_SLOPE * d;
      if (e >= deg) d = -INFINITY;
#pragma unroll
      for (int off = 4; off < 64; off <<= 1) d = fmaxf(d, __shfl_xor(d, off, 64));
      mx = fmaxf(mx, d);
    }
    float sum = 0.f;
    for (int i0 = 0; i0 < deg; i0 += 16) {
      int e = i0 + eo;
      int idx = beg + (e < deg ? e : deg - 1);
      int2 ed = edata[idx];
      U3 a0, a1;
      a0.u = *reinterpret_cast<const uint4*>(a16u + (unsigned)ed.x * 32u + fo * 8);
      a1.u = *reinterpret_cast<const uint4*>(a16u + (unsigned)ed.x * 32u + fo * 8 + 4);
      float d = 0.f;
#pragma unroll
      for (int j = 0; j < 4; ++j) d = __builtin_amdgcn_fdot2(a0.h[j], tc0.h[j], d, false);
#pragma unroll
      for (int j = 0; j < 4; ++j) d = __builtin_amdgcn_fdot2(a1.h[j], tc1.h[j], d, false);
#pragma unroll
      for (int off = 1; off < 4; off <<= 1) d += __shfl_xor(d, off, 64);
      d = d > 0.f ? d : NEG_SLOPE * d;
      float ex = (e < deg) ? expf(d - mx) : 0.f;
#pragma unroll
      for (int off = 4; off < 64; off <<= 1) ex += __shfl_xor(ex, off, 64);
      sum += ex;
    }
    float inv = 1.f / sum;
    for (int i0 = 0; i0 < deg; i0 += 16) {
      int e = i0 + eo;
      int idx = beg + (e < deg ? e : deg - 1);
      int2 ed = edata[idx];
      U3 a0, a1;
      a0.u = *reinterpret_cast<const uint4*>(a16u + (unsigned)ed.x * 32u + fo * 8);
      a1.u = *reinterpret_cast<const uint4*>(a16u + (unsigned)ed.x * 32u + fo * 8 + 4);
      float d = 0.f;
#pragma unroll
      for (int j = 0; j < 4; ++j) d = __builtin_amdgcn_fdot2(a0.h[j], tc0.h[j], d, false);
#pragma unroll
      for (int j = 0; j < 4; ++j) d = __builtin_amdgcn_fdot2(a1.h[j], tc1.h[j], d, false);
#pragma unroll
      for (int off = 1; off < 4; off <<= 1) d += __shfl_xor(d, off, 64);
      d = d > 0.f ? d : NEG_SLOPE * d;
      if (fo == 0 && e < deg) e_soft[ed.y] = expf(d - mx) * inv;
    }
  }
}

// ---------------------------------------------------------------------------
// softmax: wave = TWO adjacent nodes, software-pipelined. Both nodes'
// edata + all 8 row-gathers issue before any compute -> 2x memory-level
// parallelism on the dependent chain (row_ptr -> edata -> a16 -> compute),
// which is the measured bottleneck (326 cyc/wave vs ~1500-cyc chain).
// Fallback to per-node worker for deg>32 / deg==0 / odd tail.
// ---------------------------------------------------------------------------
__global__ __launch_bounds__(256)
void softmax_kernel(const unsigned* __restrict__ a16u, const unsigned* __restrict__ t16u,
                    const int* __restrict__ row_ptr, const int2* __restrict__ edata,
                    float* __restrict__ e_soft, int n_nodes) {
  __shared__ float ebuf[4][MAXD];
  int wv   = (blockIdx.x * blockDim.x + threadIdx.x) >> 6;
  int lane = threadIdx.x & 63;
  int lw   = threadIdx.x >> 6;
  int eo = lane >> 2;   // 0..15 edge slot
  int fo = lane & 3;    // 0..3  row quarter (32B)
  int n0 = wv * 2;
  if (n0 >= n_nodes) return;
  bool has1 = (n0 + 1 < n_nodes);

  int rp0 = row_ptr[n0];
  int rp1 = row_ptr[n0 + 1];
  int rp2 = has1 ? row_ptr[n0 + 2] : rp1;
  int deg0 = rp1 - rp0;
  int deg1 = rp2 - rp1;

  if (deg0 >= 1 && deg0 <= 32 && has1 && deg1 >= 1 && deg1 <= 32) {
    union U { uint4 u; half2_t h[4]; };
    // t16 rows for both nodes
    U tc00, tc01, tc10, tc11;
    tc00.u = *reinterpret_cast<const uint4*>(t16u + (unsigned)n0 * 32u + fo * 8);
    tc01.u = *reinterpret_cast<const uint4*>(t16u + (unsigned)n0 * 32u + fo * 8 + 4);
    tc10.u = *reinterpret_cast<const uint4*>(t16u + (unsigned)(n0 + 1) * 32u + fo * 8);
    tc11.u = *reinterpret_cast<const uint4*>(t16u + (unsigned)(n0 + 1) * 32u + fo * 8 + 4);

    int eA = eo, eB = 16 + eo;
    // node0 edata
    int2 ed0A = edata[rp0 + (eA < deg0 ? eA : deg0 - 1)];
    int2 ed0B = edata[rp0 + (eB < deg0 ? eB : deg0 - 1)];
    // node1 edata
    int2 ed1A = edata[rp1 + (eA < deg1 ? eA : deg1 - 1)];
    int2 ed1B = edata[rp1 + (eB < deg1 ? eB : deg1 - 1)];

    // all 8 row-gathers in flight
    U a00A, a01A, a00B, a01B, a10A, a11A, a10B, a11B;
    a00A.u = *reinterpret_cast<const uint4*>(a16u + (unsigned)ed0A.x * 32u + fo * 8);
    a01A.u = *reinterpret_cast<const uint4*>(a16u + (unsigned)ed0A.x * 32u + fo * 8 + 4);
    a00B.u = *reinterpret_cast<const uint4*>(a16u + (unsigned)ed0B.x * 32u + fo * 8);
    a01B.u = *reinterpret_cast<const uint4*>(a16u + (unsigned)ed0B.x * 32u + fo * 8 + 4);
    a10A.u = *reinterpret_cast<const uint4*>(a16u + (unsigned)ed1A.x * 32u + fo * 8);
    a11A.u = *reinterpret_cast<const uint4*>(a16u + (unsigned)ed1A.x * 32u + fo * 8 + 4);
    a10B.u = *reinterpret_cast<const uint4*>(a16u + (unsigned)ed1B.x * 32u + fo * 8);
    a11B.u = *reinterpret_cast<const uint4*>(a16u + (unsigned)ed1B.x * 32u + fo * 8 + 4);

    float d0A = 0.f, d0B = 0.f, d1A = 0.f, d1B = 0.f;
#pragma unroll
    for (int j = 0; j < 4; ++j) {
      d0A = __builtin_amdgcn_fdot2(a00A.h[j], tc00.h[j], d0A, false);
      d0B = __builtin_amdgcn_fdot2(a00B.h[j], tc00.h[j], d0B, false);
      d1A = __builtin_amdgcn_fdot2(a10A.h[j], tc10.h[j], d1A, false);
      d1B = __builtin_amdgcn_fdot2(a10B.h[j], tc10.h[j], d1B, false);
    }
#pragma unroll
    for (int j = 0; j < 4; ++j) {
      d0A = __builtin_amdgcn_fdot2(a01A.h[j], tc01.h[j], d0A, false);
      d0B = __builtin_amdgcn_fdot2(a01B.h[j], tc01.h[j], d0B, false);
      d1A = __builtin_amdgcn_fdot2(a11A.h[j], tc11.h[j], d1A, false);
      d1B = __builtin_amdgcn_fdot2(a11B.h[j], tc11.h[j], d1B, false);
    }
#pragma unroll
    for (int off = 1; off < 4; off <<= 1) {
      d0A += __shfl_xor(d0A, off, 64);
      d0B += __shfl_xor(d0B, off, 64);
      d1A += __shfl_xor(d1A, off, 64);
      d1B += __shfl_xor(d1B, off, 64);
    }
    d0A = d0A > 0.f ? d0A : NEG_SLOPE * d0A;
    d0B = d0B > 0.f ? d0B : NEG_SLOPE * d0B;
    d1A = d1A > 0.f ? d1A : NEG_SLOPE * d1A;
    d1B = d1B > 0.f ? d1B : NEG_SLOPE * d1B;

    float mx0 = fmaxf((eA < deg0) ? d0A : -INFINITY, (eB < deg0) ? d0B : -INFINITY);
    float mx1 = fmaxf((eA < deg1) ? d1A : -INFINITY, (eB < deg1) ? d1B : -INFINITY);
#pragma unroll
    for (int off = 4; off < 64; off <<= 1) {
      mx0 = fmaxf(mx0, __shfl_xor(mx0, off, 64));
      mx1 = fmaxf(mx1, __shfl_xor(mx1, off, 64));
    }
    float x0A = (eA < deg0) ? expf(d0A - mx0) : 0.f;
    float x0B = (eB < deg0) ? expf(d0B - mx0) : 0.f;
    float x1A = (eA < deg1) ? expf(d1A - mx1) : 0.f;
    float x1B = (eB < deg1) ? expf(d1B - mx1) : 0.f;
    float s0 = x0A + x0B, s1 = x1A + x1B;
#pragma unroll
    for (int off = 4; off < 64; off <<= 1) {
      s0 += __shfl_xor(s0, off, 64);
      s1 += __shfl_xor(s1, off, 64);
    }
    float inv0 = 1.f / s0, inv1 = 1.f / s1;
    if (fo == 0) {
      if (eA < deg0) e_soft[ed0A.y] = x0A * inv0;
      if (eB < deg0) e_soft[ed0B.y] = x0B * inv0;
      if (eA < deg1) e_soft[ed1A.y] = x1A * inv1;
      if (eB < deg1) e_soft[ed1B.y] = x1B * inv1;
    }
  } else {
    if (deg0 > 0)
      softmax_one(a16u, t16u, edata, e_soft, ebuf[lw], n0, rp0, deg0, lane, eo, fo);
    if (has1 && deg1 > 0)
      softmax_one(a16u, t16u, edata, e_soft, ebuf[lw], n0 + 1, rp1, deg1, lane, eo, fo);
  }
}

extern "C" void kernel_launch(void* const* d_in, const int* in_sizes, int n_in,
                              void* d_out, int out_size, void* d_ws, size_t ws_size,
                              hipStream_t stream) {
  const float* feat = (const float*)d_in[0];
  const float* W    = (const float*)d_in[1];
  const int*   src  = (const int*)d_in[2];
  const int*   dst  = (const int*)d_in[3];
  const int n_nodes = in_sizes[0] / IN_FEATS;
  const int n_edges = in_sizes[2];
  const int nbuck   = (n_nodes + BNODES - 1) >> BSH;   // <= 512

  // Output layout: [h_agg (N*64) | e_soft (E)]
  float* h_agg  = (float*)d_out;
  float* e_soft = (float*)d_out + (size_t)n_nodes * OUT_FEATS;

  // Workspace (t16 aliases tmpe, dead after binB):
  unsigned short* h16 = (unsigned short*)d_ws;
  unsigned short* a16 = h16 + (size_t)n_nodes * OUT_FEATS;
  int* bcount   = (int*)(a16 + (size_t)n_nodes * OUT_FEATS);
  int* bbase    = bcount + 513;
  int* bcursor  = bbase + 513;
  int* row_ptr  = bcursor + 512;
  size_t rp_pad = ((size_t)n_nodes + 2) & ~(size_t)1;
  int2* tmpe    = (int2*)(row_ptr + rp_pad);
  int2* edata   = tmpe + n_edges;
  unsigned* t16 = (unsigned*)tmpe;

  const int eb2 = (n_edges + CHUNK - 1) / CHUNK;
  const int ab  = (n_nodes * 8 + 255) / 256;
  const int nwave2 = (n_nodes + 1) / 2;                  // 2 nodes per wave
  const int sb  = (nwave2 * 64 + 255) / 256;

  hipMemsetAsync(bcount, 0, (size_t)nbuck * sizeof(int), stream);

  // fused: gemm (blocks 0..511) || bhist (blocks 512..511+eb2)
  gemm_bhist_kernel<<<GEMM_BLOCKS + eb2, 256, 0, stream>>>(
      feat, W, h16, n_nodes, dst, bcount, n_edges, nbuck);

  bscan_kernel<<<1, 512, 0, stream>>>(bcount, bbase, bcursor, nbuck, n_edges);
  bscatter_kernel<<<eb2, 256, 0, stream>>>(src, dst, bcursor, tmpe, n_edges, nbuck);
  binB_kernel<<<nbuck, 256, 0, stream>>>(tmpe, bbase, edata, row_ptr, n_nodes, n_edges);

  agg_kernel<<<ab, 256, 0, stream>>>((const unsigned*)h16, row_ptr, edata,
                                     h_agg, (unsigned*)a16, t16, n_nodes);

  softmax_kernel<<<sb, 256, 0, stream>>>((const unsigned*)a16, (const unsigned*)t16,
                                         row_ptr, edata, e_soft, n_nodes);
}